// Round 1
// baseline (1895.224 us; speedup 1.0000x reference)
//
#include <hip/hip_runtime.h>
#include <math.h>

#define BATCHN 2
#define SEQ 1024
#define MROWS 2048      // BATCHN*SEQ
#define DMODEL 768
#define DINNER 1536
#define DSTATE 16
#define DCONV 4
#define DTRANK 48       // (768+15)//16
#define DBLW 80         // DTRANK + 2*DSTATE
#define NCHUNK 32
#define CLEN 32         // SEQ / NCHUNK

__device__ __forceinline__ float silu_f(float x) { return x / (1.f + expf(-x)); }
__device__ __forceinline__ float softplus_f(float x) {
    return fmaxf(x, 0.f) + log1pf(expf(-fabsf(x)));
}

// ---------------- LayerNorm: one block per row of 768 ----------------
__global__ __launch_bounds__(256) void ln_kernel(
    const float* __restrict__ x, const float* __restrict__ g,
    const float* __restrict__ b, float* __restrict__ xn)
{
    int row = blockIdx.x;
    const float* xr = x + (size_t)row * DMODEL;
    float v[3], s = 0.f, s2 = 0.f;
#pragma unroll
    for (int i = 0; i < 3; ++i) {
        v[i] = xr[threadIdx.x + i * 256];
        s += v[i]; s2 += v[i] * v[i];
    }
#pragma unroll
    for (int off = 32; off > 0; off >>= 1) {
        s  += __shfl_down(s, off);
        s2 += __shfl_down(s2, off);
    }
    __shared__ float red[2][4];
    int wid = threadIdx.x >> 6, lane = threadIdx.x & 63;
    if (lane == 0) { red[0][wid] = s; red[1][wid] = s2; }
    __syncthreads();
    if (threadIdx.x == 0) {
        float ts = 0.f, ts2 = 0.f;
        for (int w = 0; w < 4; ++w) { ts += red[0][w]; ts2 += red[1][w]; }
        red[0][0] = ts; red[1][0] = ts2;
    }
    __syncthreads();
    float mean = red[0][0] * (1.f / DMODEL);
    float var  = red[1][0] * (1.f / DMODEL) - mean * mean;
    float rstd = rsqrtf(var + 1e-5f);
#pragma unroll
    for (int i = 0; i < 3; ++i) {
        int c = threadIdx.x + i * 256;
        xn[(size_t)row * DMODEL + c] = (v[i] - mean) * rstd * g[c] + b[c];
    }
}

// ---------------- Main fp32 GEMM: M=2048 fixed, 128x128x16 tiles ----------------
// A row-major (2048 x K via lda), B row-major (K x N), C row-major (2048 x N).
// REV: remap A row (b,s) -> (b, SEQ-1-s).  CONCAT: k<768 from A else A2 (lda=768 each).
template <bool REV, bool CONCAT>
__global__ __launch_bounds__(256) void gemm_f32(
    const float* __restrict__ A, const float* __restrict__ A2, int lda, int K,
    const float* __restrict__ B, int N,
    const float* __restrict__ bias, float* __restrict__ C)
{
    __shared__ float As[16][132];
    __shared__ float Bs[16][132];
    int tid = threadIdx.x;
    int bm = blockIdx.y * 128, bn = blockIdx.x * 128;
    int tm = (tid >> 4) * 8, tn = (tid & 15) * 8;
    float acc[8][8];
#pragma unroll
    for (int i = 0; i < 8; ++i)
#pragma unroll
        for (int j = 0; j < 8; ++j) acc[i][j] = 0.f;

    int ar0 = tid >> 2;          // 0..63
    int akc = (tid & 3) * 4;     // 0,4,8,12
    int brk = tid >> 5;          // 0..7
    int bnc = (tid & 31) * 4;    // 0..124

    for (int kb = 0; kb < K; kb += 16) {
#pragma unroll
        for (int i = 0; i < 2; ++i) {
            int r = ar0 + i * 64;
            int grow = bm + r;
            int src;
            if (REV) { int bb = grow >> 10, s = grow & (SEQ - 1); src = (bb << 10) + (SEQ - 1 - s); }
            else src = grow;
            int k = kb + akc;
            const float* ap; int col;
            if (CONCAT) {
                if (k < DMODEL) { ap = A; col = k; }
                else            { ap = A2; col = k - DMODEL; }
            } else { ap = A; col = k; }
            float4 v = *(const float4*)(ap + (size_t)src * lda + col);
            As[akc + 0][r] = v.x; As[akc + 1][r] = v.y;
            As[akc + 2][r] = v.z; As[akc + 3][r] = v.w;
        }
#pragma unroll
        for (int i = 0; i < 2; ++i) {
            int kr = brk + i * 8;
            float4 v = *(const float4*)(B + (size_t)(kb + kr) * N + bn + bnc);
            *(float4*)(&Bs[kr][bnc]) = v;
        }
        __syncthreads();
#pragma unroll
        for (int k = 0; k < 16; ++k) {
            float a[8], bb[8];
            *(float4*)&a[0]  = *(const float4*)&As[k][tm];
            *(float4*)&a[4]  = *(const float4*)&As[k][tm + 4];
            *(float4*)&bb[0] = *(const float4*)&Bs[k][tn];
            *(float4*)&bb[4] = *(const float4*)&Bs[k][tn + 4];
#pragma unroll
            for (int i = 0; i < 8; ++i)
#pragma unroll
                for (int j = 0; j < 8; ++j)
                    acc[i][j] = fmaf(a[i], bb[j], acc[i][j]);
        }
        __syncthreads();
    }
#pragma unroll
    for (int i = 0; i < 8; ++i) {
        int grow = bm + tm + i;
#pragma unroll
        for (int j = 0; j < 8; j += 4) {
            float4 v;
            v.x = acc[i][j]; v.y = acc[i][j + 1]; v.z = acc[i][j + 2]; v.w = acc[i][j + 3];
            if (bias) {
                v.x += bias[bn + tn + j];     v.y += bias[bn + tn + j + 1];
                v.z += bias[bn + tn + j + 2]; v.w += bias[bn + tn + j + 3];
            }
            *(float4*)(C + (size_t)grow * N + bn + tn + j) = v;
        }
    }
}

// ---------------- Naive GEMM for skinny shapes ----------------
__global__ __launch_bounds__(256) void gemm_naive(
    const float* __restrict__ A, int lda,
    const float* __restrict__ B, int ldb,
    const float* __restrict__ bias,
    float* __restrict__ C, int ldc,
    int M, int N, int K, int act)
{
    int idx = blockIdx.x * 256 + threadIdx.x;
    if (idx >= M * N) return;
    int m = idx / N, n = idx % N;
    float s = bias ? bias[n] : 0.f;
    for (int k = 0; k < K; ++k)
        s = fmaf(A[(size_t)m * lda + k], B[(size_t)k * ldb + n], s);
    if (act == 1) s = softplus_f(s);
    C[(size_t)m * ldc + n] = s;
}

// ---------------- Causal depthwise conv (K=4) + SiLU ----------------
__global__ __launch_bounds__(256) void conv_silu(
    const float* __restrict__ xi, int lda,
    const float* __restrict__ w, const float* __restrict__ cb,
    float* __restrict__ xc)
{
    int idx = blockIdx.x * 256 + threadIdx.x;   // over MROWS*DINNER
    int d = idx % DINNER;
    int r = idx / DINNER;
    int s = r & (SEQ - 1);
    float acc = cb[d];
#pragma unroll
    for (int k = 0; k < DCONV; ++k) {
        int off = k - (DCONV - 1);
        float xv = (s + off >= 0) ? xi[(size_t)(r + off) * lda + d] : 0.f;
        acc = fmaf(xv, w[d * DCONV + k], acc);
    }
    xc[idx] = silu_f(acc);
}

// ---------------- Selective scan, chunked (3 kernels) ----------------
// P/Q layout: idx(c,b,n,d) = ((c*BATCHN+b)*DSTATE+n)*DINNER + d
__global__ __launch_bounds__(256) void scan_pass1(
    const float* __restrict__ delta, const float* __restrict__ u_,
    const float* __restrict__ dbl, const float* __restrict__ A_log,
    float* __restrict__ P, float* __restrict__ Q)
{
    int tid = blockIdx.x * 256 + threadIdx.x;   // BATCHN*NCHUNK*DINNER
    int d = tid % DINNER;
    int t2 = tid / DINNER;
    int c = t2 % NCHUNK;
    int b = t2 / NCHUNK;
    float A[DSTATE], h[DSTATE];
#pragma unroll
    for (int n = 0; n < DSTATE; ++n) { A[n] = -expf(A_log[d * DSTATE + n]); h[n] = 0.f; }
    float sumd = 0.f;
    int r0 = b * SEQ + c * CLEN;
    for (int t = 0; t < CLEN; ++t) {
        int r = r0 + t;
        float dl = delta[(size_t)r * DINNER + d];
        float u  = u_[(size_t)r * DINNER + d];
        float du = dl * u;
        sumd += dl;
        const float* Brow = dbl + (size_t)r * DBLW + DTRANK;
#pragma unroll
        for (int n = 0; n < DSTATE; ++n) {
            float a = expf(dl * A[n]);
            h[n] = fmaf(a, h[n], du * Brow[n]);
        }
    }
    size_t base = ((size_t)(c * BATCHN + b) * DSTATE) * DINNER + d;
#pragma unroll
    for (int n = 0; n < DSTATE; ++n) {
        P[base + (size_t)n * DINNER] = expf(sumd * A[n]);
        Q[base + (size_t)n * DINNER] = h[n];
    }
}

__global__ __launch_bounds__(256) void scan_mid(
    const float* __restrict__ P, float* __restrict__ Q)
{
    int tid = blockIdx.x * 256 + threadIdx.x;   // BATCHN*DSTATE*DINNER
    int d = tid % DINNER;
    int rem = tid / DINNER;
    int n = rem % DSTATE;
    int b = rem / DSTATE;
    float H = 0.f;
    for (int c = 0; c < NCHUNK; ++c) {
        size_t idx = ((size_t)((c * BATCHN + b) * DSTATE + n)) * DINNER + d;
        float p = P[idx], q = Q[idx];
        Q[idx] = H;          // state entering chunk c
        H = fmaf(p, H, q);
    }
}

__global__ __launch_bounds__(256) void scan_pass2(
    const float* __restrict__ delta, const float* __restrict__ u_,
    const float* __restrict__ dbl, const float* __restrict__ A_log,
    const float* __restrict__ Hinit, const float* __restrict__ Dp,
    const float* __restrict__ z, int ldz,
    float* __restrict__ ymod)
{
    int tid = blockIdx.x * 256 + threadIdx.x;
    int d = tid % DINNER;
    int t2 = tid / DINNER;
    int c = t2 % NCHUNK;
    int b = t2 / NCHUNK;
    float A[DSTATE], h[DSTATE];
    size_t base = ((size_t)(c * BATCHN + b) * DSTATE) * DINNER + d;
#pragma unroll
    for (int n = 0; n < DSTATE; ++n) {
        A[n] = -expf(A_log[d * DSTATE + n]);
        h[n] = Hinit[base + (size_t)n * DINNER];
    }
    float Dd = Dp[d];
    int r0 = b * SEQ + c * CLEN;
    for (int t = 0; t < CLEN; ++t) {
        int r = r0 + t;
        float dl = delta[(size_t)r * DINNER + d];
        float u  = u_[(size_t)r * DINNER + d];
        float du = dl * u;
        const float* Brow = dbl + (size_t)r * DBLW + DTRANK;
        const float* Crow = Brow + DSTATE;
        float y = 0.f;
#pragma unroll
        for (int n = 0; n < DSTATE; ++n) {
            float a = expf(dl * A[n]);
            h[n] = fmaf(a, h[n], du * Brow[n]);
            y = fmaf(h[n], Crow[n], y);
        }
        float zz = z[(size_t)r * ldz + d];
        float sig = 1.f / (1.f + expf(-zz));
        ymod[(size_t)r * DINNER + d] = (y + u * Dd) * (zz * sig);
    }
}

// ---------------- launch ----------------
extern "C" void kernel_launch(void* const* d_in, const int* in_sizes, int n_in,
                              void* d_out, int out_size, void* d_ws, size_t ws_size,
                              hipStream_t stream)
{
    (void)in_sizes; (void)n_in; (void)out_size; (void)ws_size;
    const float* x    = (const float*)d_in[0];
    const float* ln_g = (const float*)d_in[1];
    const float* ln_b = (const float*)d_in[2];
    const float* W_in[2]   = {(const float*)d_in[3],  (const float*)d_in[12]};
    const float* conv_w[2] = {(const float*)d_in[4],  (const float*)d_in[13]};
    const float* conv_b[2] = {(const float*)d_in[5],  (const float*)d_in[14]};
    const float* W_x[2]    = {(const float*)d_in[6],  (const float*)d_in[15]};
    const float* W_dt[2]   = {(const float*)d_in[7],  (const float*)d_in[16]};
    const float* b_dt[2]   = {(const float*)d_in[8],  (const float*)d_in[17]};
    const float* A_log[2]  = {(const float*)d_in[9],  (const float*)d_in[18]};
    const float* Dp[2]     = {(const float*)d_in[10], (const float*)d_in[19]};
    const float* W_out[2]  = {(const float*)d_in[11], (const float*)d_in[20]};
    const float* W_c = (const float*)d_in[21];
    const float* b_c = (const float*)d_in[22];
    float* out = (float*)d_out;

    float* ws = (float*)d_ws;
    float* xn    = ws; ws += (size_t)MROWS * DMODEL;
    float* out_f = ws; ws += (size_t)MROWS * DMODEL;
    float* out_b = ws; ws += (size_t)MROWS * DMODEL;
    float* xz    = ws; ws += (size_t)MROWS * 2 * DINNER;
    float* xc    = ws; ws += (size_t)MROWS * DINNER;
    float* dbl   = ws; ws += (size_t)MROWS * DBLW;
    float* delta = ws; ws += (size_t)MROWS * DINNER;
    float* P     = ws; ws += (size_t)NCHUNK * BATCHN * DSTATE * DINNER;
    float* Q     = ws; ws += (size_t)NCHUNK * BATCHN * DSTATE * DINNER;
    float* ymod  = ws; ws += (size_t)MROWS * DINNER;

    ln_kernel<<<MROWS, 256, 0, stream>>>(x, ln_g, ln_b, xn);

    for (int dir = 0; dir < 2; ++dir) {
        float* outd = dir ? out_b : out_f;
        dim3 g1(2 * DINNER / 128, MROWS / 128);
        if (dir == 0)
            gemm_f32<false, false><<<g1, 256, 0, stream>>>(xn, nullptr, DMODEL, DMODEL,
                                                           W_in[dir], 2 * DINNER, nullptr, xz);
        else
            gemm_f32<true, false><<<g1, 256, 0, stream>>>(xn, nullptr, DMODEL, DMODEL,
                                                          W_in[dir], 2 * DINNER, nullptr, xz);

        conv_silu<<<(MROWS * DINNER) / 256, 256, 0, stream>>>(xz, 2 * DINNER,
                                                              conv_w[dir], conv_b[dir], xc);

        gemm_naive<<<(MROWS * DBLW + 255) / 256, 256, 0, stream>>>(
            xc, DINNER, W_x[dir], DBLW, nullptr, dbl, DBLW, MROWS, DBLW, DINNER, 0);

        gemm_naive<<<(MROWS * DINNER) / 256, 256, 0, stream>>>(
            dbl, DBLW, W_dt[dir], DINNER, b_dt[dir], delta, DINNER, MROWS, DINNER, DTRANK, 1);

        scan_pass1<<<(BATCHN * NCHUNK * DINNER) / 256, 256, 0, stream>>>(
            delta, xc, dbl, A_log[dir], P, Q);
        scan_mid<<<(BATCHN * DSTATE * DINNER) / 256, 256, 0, stream>>>(P, Q);
        scan_pass2<<<(BATCHN * NCHUNK * DINNER) / 256, 256, 0, stream>>>(
            delta, xc, dbl, A_log[dir], Q, Dp[dir], xz + DINNER, 2 * DINNER, ymod);

        dim3 g2(DMODEL / 128, MROWS / 128);
        if (dir == 0)
            gemm_f32<false, false><<<g2, 256, 0, stream>>>(ymod, nullptr, DINNER, DINNER,
                                                           W_out[dir], DMODEL, nullptr, outd);
        else
            gemm_f32<true, false><<<g2, 256, 0, stream>>>(ymod, nullptr, DINNER, DINNER,
                                                          W_out[dir], DMODEL, nullptr, outd);
    }

    dim3 g3(DMODEL / 128, MROWS / 128);
    gemm_f32<false, true><<<g3, 256, 0, stream>>>(out_f, out_b, DMODEL, 2 * DMODEL,
                                                  W_c, DMODEL, b_c, out);
}

// Round 2
// 1233.866 us; speedup vs baseline: 1.5360x; 1.5360x over previous
//
#include <hip/hip_runtime.h>
#include <math.h>

#define BATCHN 2
#define SEQ 1024
#define MROWS 2048      // BATCHN*SEQ
#define DMODEL 768
#define DINNER 1536
#define DSTATE 16
#define DCONV 4
#define DTRANK 48       // (768+15)//16
#define DBLW 80         // DTRANK + 2*DSTATE
#define NCHUNK 32
#define CLEN 32         // SEQ / NCHUNK

__device__ __forceinline__ float silu_f(float x) { return x / (1.f + expf(-x)); }
__device__ __forceinline__ float softplus_f(float x) {
    return fmaxf(x, 0.f) + log1pf(expf(-fabsf(x)));
}

// ---------------- LayerNorm: one block per row of 768 ----------------
__global__ __launch_bounds__(256) void ln_kernel(
    const float* __restrict__ x, const float* __restrict__ g,
    const float* __restrict__ b, float* __restrict__ xn)
{
    int row = blockIdx.x;
    const float* xr = x + (size_t)row * DMODEL;
    float v[3], s = 0.f, s2 = 0.f;
#pragma unroll
    for (int i = 0; i < 3; ++i) {
        v[i] = xr[threadIdx.x + i * 256];
        s += v[i]; s2 += v[i] * v[i];
    }
#pragma unroll
    for (int off = 32; off > 0; off >>= 1) {
        s  += __shfl_down(s, off);
        s2 += __shfl_down(s2, off);
    }
    __shared__ float red[2][4];
    int wid = threadIdx.x >> 6, lane = threadIdx.x & 63;
    if (lane == 0) { red[0][wid] = s; red[1][wid] = s2; }
    __syncthreads();
    if (threadIdx.x == 0) {
        float ts = 0.f, ts2 = 0.f;
        for (int w = 0; w < 4; ++w) { ts += red[0][w]; ts2 += red[1][w]; }
        red[0][0] = ts; red[1][0] = ts2;
    }
    __syncthreads();
    float mean = red[0][0] * (1.f / DMODEL);
    float var  = red[1][0] * (1.f / DMODEL) - mean * mean;
    float rstd = rsqrtf(var + 1e-5f);
#pragma unroll
    for (int i = 0; i < 3; ++i) {
        int c = threadIdx.x + i * 256;
        xn[(size_t)row * DMODEL + c] = (v[i] - mean) * rstd * g[c] + b[c];
    }
}

// ---------------- Main fp32 GEMM: M=2048 fixed, 128x128x16 tiles ----------------
template <bool REV, bool CONCAT>
__global__ __launch_bounds__(256) void gemm_f32(
    const float* __restrict__ A, const float* __restrict__ A2, int lda, int K,
    const float* __restrict__ B, int N,
    const float* __restrict__ bias, float* __restrict__ C)
{
    __shared__ float As[16][132];
    __shared__ float Bs[16][132];
    int tid = threadIdx.x;
    int bm = blockIdx.y * 128, bn = blockIdx.x * 128;
    int tm = (tid >> 4) * 8, tn = (tid & 15) * 8;
    float acc[8][8];
#pragma unroll
    for (int i = 0; i < 8; ++i)
#pragma unroll
        for (int j = 0; j < 8; ++j) acc[i][j] = 0.f;

    int ar0 = tid >> 2;          // 0..63
    int akc = (tid & 3) * 4;     // 0,4,8,12
    int brk = tid >> 5;          // 0..7
    int bnc = (tid & 31) * 4;    // 0..124

    for (int kb = 0; kb < K; kb += 16) {
#pragma unroll
        for (int i = 0; i < 2; ++i) {
            int r = ar0 + i * 64;
            int grow = bm + r;
            int src;
            if (REV) { int bb = grow >> 10, s = grow & (SEQ - 1); src = (bb << 10) + (SEQ - 1 - s); }
            else src = grow;
            int k = kb + akc;
            const float* ap; int col;
            if (CONCAT) {
                if (k < DMODEL) { ap = A; col = k; }
                else            { ap = A2; col = k - DMODEL; }
            } else { ap = A; col = k; }
            float4 v = *(const float4*)(ap + (size_t)src * lda + col);
            As[akc + 0][r] = v.x; As[akc + 1][r] = v.y;
            As[akc + 2][r] = v.z; As[akc + 3][r] = v.w;
        }
#pragma unroll
        for (int i = 0; i < 2; ++i) {
            int kr = brk + i * 8;
            float4 v = *(const float4*)(B + (size_t)(kb + kr) * N + bn + bnc);
            *(float4*)(&Bs[kr][bnc]) = v;
        }
        __syncthreads();
#pragma unroll
        for (int k = 0; k < 16; ++k) {
            float a[8], bb[8];
            *(float4*)&a[0]  = *(const float4*)&As[k][tm];
            *(float4*)&a[4]  = *(const float4*)&As[k][tm + 4];
            *(float4*)&bb[0] = *(const float4*)&Bs[k][tn];
            *(float4*)&bb[4] = *(const float4*)&Bs[k][tn + 4];
#pragma unroll
            for (int i = 0; i < 8; ++i)
#pragma unroll
                for (int j = 0; j < 8; ++j)
                    acc[i][j] = fmaf(a[i], bb[j], acc[i][j]);
        }
        __syncthreads();
    }
#pragma unroll
    for (int i = 0; i < 8; ++i) {
        int grow = bm + tm + i;
#pragma unroll
        for (int j = 0; j < 8; j += 4) {
            float4 v;
            v.x = acc[i][j]; v.y = acc[i][j + 1]; v.z = acc[i][j + 2]; v.w = acc[i][j + 3];
            if (bias) {
                v.x += bias[bn + tn + j];     v.y += bias[bn + tn + j + 1];
                v.z += bias[bn + tn + j + 2]; v.w += bias[bn + tn + j + 3];
            }
            *(float4*)(C + (size_t)grow * N + bn + tn + j) = v;
        }
    }
}

// ---------------- x-proj GEMM: 2048x80x1536, tiled split-K ----------------
// Grid: (MROWS/32, KSPLIT). Block 256. Each block: 32 rows x 80 cols, K-chunk 384.
#define XP_BM 32
#define XP_BK 32
#define XP_KSPLIT 4
#define XP_KCH (DINNER / XP_KSPLIT)   // 384

__global__ __launch_bounds__(256) void xproj_gemm(
    const float* __restrict__ A,   // xc: 2048 x 1536
    const float* __restrict__ B,   // W_x: 1536 x 80
    float* __restrict__ part)      // KSPLIT x 2048 x 80
{
    __shared__ float As[XP_BK][XP_BM + 1];   // [k][m]
    __shared__ float Bs[XP_BK][DBLW + 1];    // [k][n]
    int tid = threadIdx.x;
    int bm = blockIdx.x * XP_BM;
    int k0 = blockIdx.y * XP_KCH;
    int tm = (tid >> 4) * 2;       // 0..30
    int tn = (tid & 15) * 5;       // 0..75
    float acc[2][5];
#pragma unroll
    for (int i = 0; i < 2; ++i)
#pragma unroll
        for (int j = 0; j < 5; ++j) acc[i][j] = 0.f;

    int ar = tid >> 3;             // 0..31
    int ac = (tid & 7) * 4;        // 0..28

    for (int kb = 0; kb < XP_KCH; kb += XP_BK) {
        float4 va = *(const float4*)(A + (size_t)(bm + ar) * DINNER + k0 + kb + ac);
        As[ac + 0][ar] = va.x; As[ac + 1][ar] = va.y;
        As[ac + 2][ar] = va.z; As[ac + 3][ar] = va.w;
#pragma unroll
        for (int i = 0; i < 10; ++i) {
            int li = tid + i * 256;
            int kk = li / DBLW, nn = li - kk * DBLW;
            Bs[kk][nn] = B[(size_t)(k0 + kb + kk) * DBLW + nn];
        }
        __syncthreads();
#pragma unroll
        for (int k = 0; k < XP_BK; ++k) {
            float a0 = As[k][tm], a1 = As[k][tm + 1];
            float b0 = Bs[k][tn + 0], b1 = Bs[k][tn + 1], b2 = Bs[k][tn + 2];
            float b3 = Bs[k][tn + 3], b4 = Bs[k][tn + 4];
            acc[0][0] = fmaf(a0, b0, acc[0][0]); acc[0][1] = fmaf(a0, b1, acc[0][1]);
            acc[0][2] = fmaf(a0, b2, acc[0][2]); acc[0][3] = fmaf(a0, b3, acc[0][3]);
            acc[0][4] = fmaf(a0, b4, acc[0][4]);
            acc[1][0] = fmaf(a1, b0, acc[1][0]); acc[1][1] = fmaf(a1, b1, acc[1][1]);
            acc[1][2] = fmaf(a1, b2, acc[1][2]); acc[1][3] = fmaf(a1, b3, acc[1][3]);
            acc[1][4] = fmaf(a1, b4, acc[1][4]);
        }
        __syncthreads();
    }
    size_t base = ((size_t)blockIdx.y * MROWS + bm) * DBLW;
#pragma unroll
    for (int i = 0; i < 2; ++i)
#pragma unroll
        for (int j = 0; j < 5; ++j)
            part[base + (size_t)(tm + i) * DBLW + tn + j] = acc[i][j];
}

__global__ __launch_bounds__(256) void xproj_reduce(
    const float* __restrict__ part, float* __restrict__ dbl)
{
    int idx = blockIdx.x * 256 + threadIdx.x;   // over MROWS*DBLW
    float s = 0.f;
#pragma unroll
    for (int ks = 0; ks < XP_KSPLIT; ++ks)
        s += part[(size_t)ks * MROWS * DBLW + idx];
    dbl[idx] = s;
}

// ---------------- Naive GEMM (delta: M=2048,N=1536,K=48 + softplus) ----------------
__global__ __launch_bounds__(256) void gemm_naive(
    const float* __restrict__ A, int lda,
    const float* __restrict__ B, int ldb,
    const float* __restrict__ bias,
    float* __restrict__ C, int ldc,
    int M, int N, int K, int act)
{
    int idx = blockIdx.x * 256 + threadIdx.x;
    if (idx >= M * N) return;
    int m = idx / N, n = idx % N;
    float s = bias ? bias[n] : 0.f;
    for (int k = 0; k < K; ++k)
        s = fmaf(A[(size_t)m * lda + k], B[(size_t)k * ldb + n], s);
    if (act == 1) s = softplus_f(s);
    C[(size_t)m * ldc + n] = s;
}

// ---------------- Causal depthwise conv (K=4) + SiLU ----------------
__global__ __launch_bounds__(256) void conv_silu(
    const float* __restrict__ xi, int lda,
    const float* __restrict__ w, const float* __restrict__ cb,
    float* __restrict__ xc)
{
    int idx = blockIdx.x * 256 + threadIdx.x;   // over MROWS*DINNER
    int d = idx % DINNER;
    int r = idx / DINNER;
    int s = r & (SEQ - 1);
    float acc = cb[d];
#pragma unroll
    for (int k = 0; k < DCONV; ++k) {
        int off = k - (DCONV - 1);
        float xv = (s + off >= 0) ? xi[(size_t)(r + off) * lda + d] : 0.f;
        acc = fmaf(xv, w[d * DCONV + k], acc);
    }
    xc[idx] = silu_f(acc);
}

// ---------------- Selective scan, chunked (3 kernels) ----------------
__global__ __launch_bounds__(256) void scan_pass1(
    const float* __restrict__ delta, const float* __restrict__ u_,
    const float* __restrict__ dbl, const float* __restrict__ A_log,
    float* __restrict__ P, float* __restrict__ Q)
{
    int tid = blockIdx.x * 256 + threadIdx.x;   // BATCHN*NCHUNK*DINNER
    int d = tid % DINNER;
    int t2 = tid / DINNER;
    int c = t2 % NCHUNK;
    int b = t2 / NCHUNK;
    float A[DSTATE], h[DSTATE];
#pragma unroll
    for (int n = 0; n < DSTATE; ++n) { A[n] = -expf(A_log[d * DSTATE + n]); h[n] = 0.f; }
    float sumd = 0.f;
    int r0 = b * SEQ + c * CLEN;
    for (int t = 0; t < CLEN; ++t) {
        int r = r0 + t;
        float dl = delta[(size_t)r * DINNER + d];
        float u  = u_[(size_t)r * DINNER + d];
        float du = dl * u;
        sumd += dl;
        const float* Brow = dbl + (size_t)r * DBLW + DTRANK;
#pragma unroll
        for (int n = 0; n < DSTATE; ++n) {
            float a = expf(dl * A[n]);
            h[n] = fmaf(a, h[n], du * Brow[n]);
        }
    }
    size_t base = ((size_t)(c * BATCHN + b) * DSTATE) * DINNER + d;
#pragma unroll
    for (int n = 0; n < DSTATE; ++n) {
        P[base + (size_t)n * DINNER] = expf(sumd * A[n]);
        Q[base + (size_t)n * DINNER] = h[n];
    }
}

__global__ __launch_bounds__(256) void scan_mid(
    const float* __restrict__ P, float* __restrict__ Q)
{
    int tid = blockIdx.x * 256 + threadIdx.x;   // BATCHN*DSTATE*DINNER
    int d = tid % DINNER;
    int rem = tid / DINNER;
    int n = rem % DSTATE;
    int b = rem / DSTATE;
    float H = 0.f;
    for (int c = 0; c < NCHUNK; ++c) {
        size_t idx = ((size_t)((c * BATCHN + b) * DSTATE + n)) * DINNER + d;
        float p = P[idx], q = Q[idx];
        Q[idx] = H;          // state entering chunk c
        H = fmaf(p, H, q);
    }
}

__global__ __launch_bounds__(256) void scan_pass2(
    const float* __restrict__ delta, const float* __restrict__ u_,
    const float* __restrict__ dbl, const float* __restrict__ A_log,
    const float* __restrict__ Hinit, const float* __restrict__ Dp,
    const float* __restrict__ z, int ldz,
    float* __restrict__ ymod)
{
    int tid = blockIdx.x * 256 + threadIdx.x;
    int d = tid % DINNER;
    int t2 = tid / DINNER;
    int c = t2 % NCHUNK;
    int b = t2 / NCHUNK;
    float A[DSTATE], h[DSTATE];
    size_t base = ((size_t)(c * BATCHN + b) * DSTATE) * DINNER + d;
#pragma unroll
    for (int n = 0; n < DSTATE; ++n) {
        A[n] = -expf(A_log[d * DSTATE + n]);
        h[n] = Hinit[base + (size_t)n * DINNER];
    }
    float Dd = Dp[d];
    int r0 = b * SEQ + c * CLEN;
    for (int t = 0; t < CLEN; ++t) {
        int r = r0 + t;
        float dl = delta[(size_t)r * DINNER + d];
        float u  = u_[(size_t)r * DINNER + d];
        float du = dl * u;
        const float* Brow = dbl + (size_t)r * DBLW + DTRANK;
        const float* Crow = Brow + DSTATE;
        float y = 0.f;
#pragma unroll
        for (int n = 0; n < DSTATE; ++n) {
            float a = expf(dl * A[n]);
            h[n] = fmaf(a, h[n], du * Brow[n]);
            y = fmaf(h[n], Crow[n], y);
        }
        float zz = z[(size_t)r * ldz + d];
        float sig = 1.f / (1.f + expf(-zz));
        ymod[(size_t)r * DINNER + d] = (y + u * Dd) * (zz * sig);
    }
}

// ---------------- launch ----------------
extern "C" void kernel_launch(void* const* d_in, const int* in_sizes, int n_in,
                              void* d_out, int out_size, void* d_ws, size_t ws_size,
                              hipStream_t stream)
{
    (void)in_sizes; (void)n_in; (void)out_size; (void)ws_size;
    const float* x    = (const float*)d_in[0];
    const float* ln_g = (const float*)d_in[1];
    const float* ln_b = (const float*)d_in[2];
    const float* W_in[2]   = {(const float*)d_in[3],  (const float*)d_in[12]};
    const float* conv_w[2] = {(const float*)d_in[4],  (const float*)d_in[13]};
    const float* conv_b[2] = {(const float*)d_in[5],  (const float*)d_in[14]};
    const float* W_x[2]    = {(const float*)d_in[6],  (const float*)d_in[15]};
    const float* W_dt[2]   = {(const float*)d_in[7],  (const float*)d_in[16]};
    const float* b_dt[2]   = {(const float*)d_in[8],  (const float*)d_in[17]};
    const float* A_log[2]  = {(const float*)d_in[9],  (const float*)d_in[18]};
    const float* Dp[2]     = {(const float*)d_in[10], (const float*)d_in[19]};
    const float* W_out[2]  = {(const float*)d_in[11], (const float*)d_in[20]};
    const float* W_c = (const float*)d_in[21];
    const float* b_c = (const float*)d_in[22];
    float* out = (float*)d_out;

    float* ws = (float*)d_ws;
    float* xn    = ws; ws += (size_t)MROWS * DMODEL;
    float* out_f = ws; ws += (size_t)MROWS * DMODEL;
    float* out_b = ws; ws += (size_t)MROWS * DMODEL;
    float* xz    = ws; ws += (size_t)MROWS * 2 * DINNER;
    float* xc    = ws; ws += (size_t)MROWS * DINNER;
    float* dbl   = ws; ws += (size_t)MROWS * DBLW;
    float* delta = ws; ws += (size_t)MROWS * DINNER;
    float* P     = ws; ws += (size_t)NCHUNK * BATCHN * DSTATE * DINNER;
    float* Q     = ws; ws += (size_t)NCHUNK * BATCHN * DSTATE * DINNER;
    float* ymod  = ws; ws += (size_t)MROWS * DINNER;
    float* part  = ws; ws += (size_t)XP_KSPLIT * MROWS * DBLW;

    ln_kernel<<<MROWS, 256, 0, stream>>>(x, ln_g, ln_b, xn);

    for (int dir = 0; dir < 2; ++dir) {
        float* outd = dir ? out_b : out_f;
        dim3 g1(2 * DINNER / 128, MROWS / 128);
        if (dir == 0)
            gemm_f32<false, false><<<g1, 256, 0, stream>>>(xn, nullptr, DMODEL, DMODEL,
                                                           W_in[dir], 2 * DINNER, nullptr, xz);
        else
            gemm_f32<true, false><<<g1, 256, 0, stream>>>(xn, nullptr, DMODEL, DMODEL,
                                                          W_in[dir], 2 * DINNER, nullptr, xz);

        conv_silu<<<(MROWS * DINNER) / 256, 256, 0, stream>>>(xz, 2 * DINNER,
                                                              conv_w[dir], conv_b[dir], xc);

        dim3 gx(MROWS / XP_BM, XP_KSPLIT);
        xproj_gemm<<<gx, 256, 0, stream>>>(xc, W_x[dir], part);
        xproj_reduce<<<(MROWS * DBLW) / 256, 256, 0, stream>>>(part, dbl);

        gemm_naive<<<(MROWS * DINNER) / 256, 256, 0, stream>>>(
            dbl, DBLW, W_dt[dir], DINNER, b_dt[dir], delta, DINNER, MROWS, DINNER, DTRANK, 1);

        scan_pass1<<<(BATCHN * NCHUNK * DINNER) / 256, 256, 0, stream>>>(
            delta, xc, dbl, A_log[dir], P, Q);
        scan_mid<<<(BATCHN * DSTATE * DINNER) / 256, 256, 0, stream>>>(P, Q);
        scan_pass2<<<(BATCHN * NCHUNK * DINNER) / 256, 256, 0, stream>>>(
            delta, xc, dbl, A_log[dir], Q, Dp[dir], xz + DINNER, 2 * DINNER, ymod);

        dim3 g2(DMODEL / 128, MROWS / 128);
        if (dir == 0)
            gemm_f32<false, false><<<g2, 256, 0, stream>>>(ymod, nullptr, DINNER, DINNER,
                                                           W_out[dir], DMODEL, nullptr, outd);
        else
            gemm_f32<true, false><<<g2, 256, 0, stream>>>(ymod, nullptr, DINNER, DINNER,
                                                          W_out[dir], DMODEL, nullptr, outd);
    }

    dim3 g3(DMODEL / 128, MROWS / 128);
    gemm_f32<false, true><<<g3, 256, 0, stream>>>(out_f, out_b, DMODEL, 2 * DMODEL,
                                                  W_c, DMODEL, b_c, out);
}

// Round 4
// 542.683 us; speedup vs baseline: 3.4923x; 2.2736x over previous
//
#include <hip/hip_runtime.h>
#include <math.h>

#define BATCHN 2
#define SEQ 1024
#define MROWS 2048      // BATCHN*SEQ
#define DMODEL 768
#define DINNER 1536
#define DSTATE 16
#define DCONV 4
#define DTRANK 48       // (768+15)//16
#define DBLW 80         // DTRANK + 2*DSTATE
#define NCHUNK 32
#define CLEN 32         // SEQ / NCHUNK

typedef __bf16 bf16x8 __attribute__((ext_vector_type(8)));
typedef float  f32x4  __attribute__((ext_vector_type(4)));

__device__ __forceinline__ float silu_f(float x) { return x / (1.f + expf(-x)); }
__device__ __forceinline__ float softplus_f(float x) {
    return fmaxf(x, 0.f) + log1pf(expf(-fabsf(x)));
}
__device__ __forceinline__ unsigned short f2bf(float f) {
    unsigned int u = __float_as_uint(f);
    u += 0x7fffu + ((u >> 16) & 1u);          // round-to-nearest-even
    return (unsigned short)(u >> 16);
}
__device__ __forceinline__ void gload_lds16(const void* g, void* l) {
    __builtin_amdgcn_global_load_lds((const __attribute__((address_space(1))) void*)g,
                                     (__attribute__((address_space(3))) void*)l, 16, 0, 0);
}

// ---------------- LayerNorm -> bf16 (normal + seq-reversed copies) ----------------
__global__ __launch_bounds__(256) void ln_kernel(
    const float* __restrict__ x, const float* __restrict__ g,
    const float* __restrict__ b,
    unsigned short* __restrict__ xn_bf, unsigned short* __restrict__ xnr_bf)
{
    int row = blockIdx.x;
    const float* xr = x + (size_t)row * DMODEL;
    float v[3], s = 0.f, s2 = 0.f;
#pragma unroll
    for (int i = 0; i < 3; ++i) {
        v[i] = xr[threadIdx.x + i * 256];
        s += v[i]; s2 += v[i] * v[i];
    }
#pragma unroll
    for (int off = 32; off > 0; off >>= 1) {
        s  += __shfl_down(s, off);
        s2 += __shfl_down(s2, off);
    }
    __shared__ float red[2][4];
    int wid = threadIdx.x >> 6, lane = threadIdx.x & 63;
    if (lane == 0) { red[0][wid] = s; red[1][wid] = s2; }
    __syncthreads();
    if (threadIdx.x == 0) {
        float ts = 0.f, ts2 = 0.f;
        for (int w = 0; w < 4; ++w) { ts += red[0][w]; ts2 += red[1][w]; }
        red[0][0] = ts; red[1][0] = ts2;
    }
    __syncthreads();
    float mean = red[0][0] * (1.f / DMODEL);
    float var  = red[1][0] * (1.f / DMODEL) - mean * mean;
    float rstd = rsqrtf(var + 1e-5f);
    int rrow = row ^ (SEQ - 1);              // flip within batch
#pragma unroll
    for (int i = 0; i < 3; ++i) {
        int c = threadIdx.x + i * 256;
        unsigned short h = f2bf((v[i] - mean) * rstd * g[c] + b[c]);
        xn_bf [(size_t)row  * DMODEL + c] = h;
        xnr_bf[(size_t)rrow * DMODEL + c] = h;
    }
}

// ---------------- weight transpose + fp32->bf16: W[K][N] -> Wt[N][K] ----------------
__global__ __launch_bounds__(256) void wt_transpose(
    const float* __restrict__ W, unsigned short* __restrict__ Wt, int K, int N)
{
    __shared__ float t[32][33];
    int n0 = blockIdx.x * 32, k0 = blockIdx.y * 32;
    int tx = threadIdx.x & 31, ty = threadIdx.x >> 5;
#pragma unroll
    for (int i = 0; i < 4; ++i)
        t[ty + i * 8][tx] = W[(size_t)(k0 + ty + i * 8) * N + n0 + tx];
    __syncthreads();
#pragma unroll
    for (int i = 0; i < 4; ++i)
        Wt[(size_t)(n0 + ty + i * 8) * K + k0 + tx] = f2bf(t[tx][ty + i * 8]);
}

// ---------------- bf16 MFMA GEMM ----------------
// A: M x K bf16 row-major (lda). Bt: N x K bf16 row-major (ldb=K). C: M x N.
// Tile BM x 128, BK=32. 4 waves as 2x2; wave tile (BM/2) x 64.
// REVC: C row ^= 1023 (per-batch seq flip). CONCAT: k<768 from A else A2.
// CBF16: C stored as bf16, else fp32.
template <int BM, bool REVC, bool CONCAT, bool CBF16>
__global__ __launch_bounds__(256) void gemm_bf16(
    const unsigned short* __restrict__ A, const unsigned short* __restrict__ A2,
    int lda, int K,
    const unsigned short* __restrict__ Bt, int N,
    const float* __restrict__ bias, void* __restrict__ Cv)
{
    constexpr int MI = BM / 32;
    __shared__ unsigned short lsA[BM * 32];
    __shared__ unsigned short lsB[128 * 32];
    int tid = threadIdx.x;
    int w = tid >> 6, lane = tid & 63;
    int wm = w >> 1, wn = w & 1;
    int bm = blockIdx.y * BM, bn = blockIdx.x * 128;
    int sr = lane >> 2, sc = (lane & 3) * 8;
    int l15 = lane & 15, kq = (lane >> 4) * 8;

    f32x4 acc[MI][4];
#pragma unroll
    for (int mi = 0; mi < MI; ++mi)
#pragma unroll
        for (int ni = 0; ni < 4; ++ni) acc[mi][ni] = (f32x4){0.f, 0.f, 0.f, 0.f};

    for (int kb = 0; kb < K; kb += 32) {
        const unsigned short* ap; int kc;
        if (CONCAT) {
            ap = (kb < DMODEL) ? A : A2;
            kc = (kb < DMODEL) ? kb : kb - DMODEL;
        } else { ap = A; kc = kb; }
#pragma unroll
        for (int r = 0; r < BM / 64; ++r) {
            const void* gp = ap + (size_t)(bm + r * 64 + w * 16 + sr) * lda + kc + sc;
            gload_lds16(gp, (void*)&lsA[(r * 64 + w * 16) * 32]);
        }
#pragma unroll
        for (int r = 0; r < 2; ++r) {
            const void* gp = Bt + (size_t)(bn + r * 64 + w * 16 + sr) * K + kb + sc;
            gload_lds16(gp, (void*)&lsB[(r * 64 + w * 16) * 32]);
        }
        __syncthreads();
        bf16x8 af[MI], bfr[4];
#pragma unroll
        for (int mi = 0; mi < MI; ++mi)
            af[mi] = *(const bf16x8*)&lsA[(wm * (BM / 2) + mi * 16 + l15) * 32 + kq];
#pragma unroll
        for (int ni = 0; ni < 4; ++ni)
            bfr[ni] = *(const bf16x8*)&lsB[(wn * 64 + ni * 16 + l15) * 32 + kq];
#pragma unroll
        for (int mi = 0; mi < MI; ++mi)
#pragma unroll
            for (int ni = 0; ni < 4; ++ni)
                acc[mi][ni] = __builtin_amdgcn_mfma_f32_16x16x32_bf16(
                    af[mi], bfr[ni], acc[mi][ni], 0, 0, 0);
        __syncthreads();
    }

    int r4 = (lane >> 4) * 4;
#pragma unroll
    for (int mi = 0; mi < MI; ++mi) {
#pragma unroll
        for (int ni = 0; ni < 4; ++ni) {
            int col = bn + wn * 64 + ni * 16 + l15;
            float bv = bias ? bias[col] : 0.f;
#pragma unroll
            for (int r = 0; r < 4; ++r) {
                int row = bm + wm * (BM / 2) + mi * 16 + r4 + r;
                if (REVC) row ^= (SEQ - 1);
                float val = acc[mi][ni][r] + bv;
                if (CBF16)
                    ((unsigned short*)Cv)[(size_t)row * N + col] = f2bf(val);
                else
                    ((float*)Cv)[(size_t)row * N + col] = val;
            }
        }
    }
}

// ---------------- x-proj GEMM: 2048x80x1536, tiled split-K ----------------
#define XP_BM 32
#define XP_BK 32
#define XP_KSPLIT 4
#define XP_KCH (DINNER / XP_KSPLIT)   // 384

__global__ __launch_bounds__(256) void xproj_gemm(
    const float* __restrict__ A,   // xc: 2048 x 1536
    const float* __restrict__ B,   // W_x: 1536 x 80
    float* __restrict__ part)      // KSPLIT x 2048 x 80
{
    __shared__ float As[XP_BK][XP_BM + 1];
    __shared__ float Bs[XP_BK][DBLW + 1];
    int tid = threadIdx.x;
    int bm = blockIdx.x * XP_BM;
    int k0 = blockIdx.y * XP_KCH;
    int tm = (tid >> 4) * 2;
    int tn = (tid & 15) * 5;
    float acc[2][5];
#pragma unroll
    for (int i = 0; i < 2; ++i)
#pragma unroll
        for (int j = 0; j < 5; ++j) acc[i][j] = 0.f;

    int ar = tid >> 3;
    int ac = (tid & 7) * 4;

    for (int kb = 0; kb < XP_KCH; kb += XP_BK) {
        float4 va = *(const float4*)(A + (size_t)(bm + ar) * DINNER + k0 + kb + ac);
        As[ac + 0][ar] = va.x; As[ac + 1][ar] = va.y;
        As[ac + 2][ar] = va.z; As[ac + 3][ar] = va.w;
#pragma unroll
        for (int i = 0; i < 10; ++i) {
            int li = tid + i * 256;
            int kk = li / DBLW, nn = li - kk * DBLW;
            Bs[kk][nn] = B[(size_t)(k0 + kb + kk) * DBLW + nn];
        }
        __syncthreads();
#pragma unroll
        for (int k = 0; k < XP_BK; ++k) {
            float a0 = As[k][tm], a1 = As[k][tm + 1];
            float b0 = Bs[k][tn + 0], b1 = Bs[k][tn + 1], b2 = Bs[k][tn + 2];
            float b3 = Bs[k][tn + 3], b4 = Bs[k][tn + 4];
            acc[0][0] = fmaf(a0, b0, acc[0][0]); acc[0][1] = fmaf(a0, b1, acc[0][1]);
            acc[0][2] = fmaf(a0, b2, acc[0][2]); acc[0][3] = fmaf(a0, b3, acc[0][3]);
            acc[0][4] = fmaf(a0, b4, acc[0][4]);
            acc[1][0] = fmaf(a1, b0, acc[1][0]); acc[1][1] = fmaf(a1, b1, acc[1][1]);
            acc[1][2] = fmaf(a1, b2, acc[1][2]); acc[1][3] = fmaf(a1, b3, acc[1][3]);
            acc[1][4] = fmaf(a1, b4, acc[1][4]);
        }
        __syncthreads();
    }
    size_t base = ((size_t)blockIdx.y * MROWS + bm) * DBLW;
#pragma unroll
    for (int i = 0; i < 2; ++i)
#pragma unroll
        for (int j = 0; j < 5; ++j)
            part[base + (size_t)(tm + i) * DBLW + tn + j] = acc[i][j];
}

__global__ __launch_bounds__(256) void xproj_reduce(
    const float* __restrict__ part, float* __restrict__ dbl)
{
    int idx = blockIdx.x * 256 + threadIdx.x;
    float s = 0.f;
#pragma unroll
    for (int ks = 0; ks < XP_KSPLIT; ++ks)
        s += part[(size_t)ks * MROWS * DBLW + idx];
    dbl[idx] = s;
}

// ---------------- Naive GEMM (delta: M=2048,N=1536,K=48 + softplus) ----------------
__global__ __launch_bounds__(256) void gemm_naive(
    const float* __restrict__ A, int lda,
    const float* __restrict__ B, int ldb,
    const float* __restrict__ bias,
    float* __restrict__ C, int ldc,
    int M, int N, int K, int act)
{
    int idx = blockIdx.x * 256 + threadIdx.x;
    if (idx >= M * N) return;
    int m = idx / N, n = idx % N;
    float s = bias ? bias[n] : 0.f;
    for (int k = 0; k < K; ++k)
        s = fmaf(A[(size_t)m * lda + k], B[(size_t)k * ldb + n], s);
    if (act == 1) s = softplus_f(s);
    C[(size_t)m * ldc + n] = s;
}

// ---------------- Causal depthwise conv (K=4) + SiLU ----------------
__global__ __launch_bounds__(256) void conv_silu(
    const float* __restrict__ xi, int lda,
    const float* __restrict__ w, const float* __restrict__ cb,
    float* __restrict__ xc)
{
    int idx = blockIdx.x * 256 + threadIdx.x;
    int d = idx % DINNER;
    int r = idx / DINNER;
    int s = r & (SEQ - 1);
    float acc = cb[d];
#pragma unroll
    for (int k = 0; k < DCONV; ++k) {
        int off = k - (DCONV - 1);
        float xv = (s + off >= 0) ? xi[(size_t)(r + off) * lda + d] : 0.f;
        acc = fmaf(xv, w[d * DCONV + k], acc);
    }
    xc[idx] = silu_f(acc);
}

// ---------------- Selective scan, chunked (3 kernels) ----------------
__global__ __launch_bounds__(256) void scan_pass1(
    const float* __restrict__ delta, const float* __restrict__ u_,
    const float* __restrict__ dbl, const float* __restrict__ A_log,
    float* __restrict__ P, float* __restrict__ Q)
{
    int tid = blockIdx.x * 256 + threadIdx.x;
    int d = tid % DINNER;
    int t2 = tid / DINNER;
    int c = t2 % NCHUNK;
    int b = t2 / NCHUNK;
    float A[DSTATE], h[DSTATE];
#pragma unroll
    for (int n = 0; n < DSTATE; ++n) { A[n] = -expf(A_log[d * DSTATE + n]); h[n] = 0.f; }
    float sumd = 0.f;
    int r0 = b * SEQ + c * CLEN;
    for (int t = 0; t < CLEN; ++t) {
        int r = r0 + t;
        float dl = delta[(size_t)r * DINNER + d];
        float u  = u_[(size_t)r * DINNER + d];
        float du = dl * u;
        sumd += dl;
        const float* Brow = dbl + (size_t)r * DBLW + DTRANK;
#pragma unroll
        for (int n = 0; n < DSTATE; ++n) {
            float a = expf(dl * A[n]);
            h[n] = fmaf(a, h[n], du * Brow[n]);
        }
    }
    size_t base = ((size_t)(c * BATCHN + b) * DSTATE) * DINNER + d;
#pragma unroll
    for (int n = 0; n < DSTATE; ++n) {
        P[base + (size_t)n * DINNER] = expf(sumd * A[n]);
        Q[base + (size_t)n * DINNER] = h[n];
    }
}

__global__ __launch_bounds__(256) void scan_mid(
    const float* __restrict__ P, float* __restrict__ Q)
{
    int tid = blockIdx.x * 256 + threadIdx.x;
    int d = tid % DINNER;
    int rem = tid / DINNER;
    int n = rem % DSTATE;
    int b = rem / DSTATE;
    float H = 0.f;
    for (int c = 0; c < NCHUNK; ++c) {
        size_t idx = ((size_t)((c * BATCHN + b) * DSTATE + n)) * DINNER + d;
        float p = P[idx], q = Q[idx];
        Q[idx] = H;
        H = fmaf(p, H, q);
    }
}

__global__ __launch_bounds__(256) void scan_pass2(
    const float* __restrict__ delta, const float* __restrict__ u_,
    const float* __restrict__ dbl, const float* __restrict__ A_log,
    const float* __restrict__ Hinit, const float* __restrict__ Dp,
    const float* __restrict__ z, int ldz,
    unsigned short* __restrict__ ymod_bf)
{
    int tid = blockIdx.x * 256 + threadIdx.x;
    int d = tid % DINNER;
    int t2 = tid / DINNER;
    int c = t2 % NCHUNK;
    int b = t2 / NCHUNK;
    float A[DSTATE], h[DSTATE];
    size_t base = ((size_t)(c * BATCHN + b) * DSTATE) * DINNER + d;
#pragma unroll
    for (int n = 0; n < DSTATE; ++n) {
        A[n] = -expf(A_log[d * DSTATE + n]);
        h[n] = Hinit[base + (size_t)n * DINNER];
    }
    float Dd = Dp[d];
    int r0 = b * SEQ + c * CLEN;
    for (int t = 0; t < CLEN; ++t) {
        int r = r0 + t;
        float dl = delta[(size_t)r * DINNER + d];
        float u  = u_[(size_t)r * DINNER + d];
        float du = dl * u;
        const float* Brow = dbl + (size_t)r * DBLW + DTRANK;
        const float* Crow = Brow + DSTATE;
        float y = 0.f;
#pragma unroll
        for (int n = 0; n < DSTATE; ++n) {
            float a = expf(dl * A[n]);
            h[n] = fmaf(a, h[n], du * Brow[n]);
            y = fmaf(h[n], Crow[n], y);
        }
        float zz = z[(size_t)r * ldz + d];
        float sig = 1.f / (1.f + expf(-zz));
        ymod_bf[(size_t)r * DINNER + d] = f2bf((y + u * Dd) * (zz * sig));
    }
}

// ---------------- launch ----------------
extern "C" void kernel_launch(void* const* d_in, const int* in_sizes, int n_in,
                              void* d_out, int out_size, void* d_ws, size_t ws_size,
                              hipStream_t stream)
{
    (void)in_sizes; (void)n_in; (void)out_size; (void)ws_size;
    const float* x    = (const float*)d_in[0];
    const float* ln_g = (const float*)d_in[1];
    const float* ln_b = (const float*)d_in[2];
    const float* W_in[2]   = {(const float*)d_in[3],  (const float*)d_in[12]};
    const float* conv_w[2] = {(const float*)d_in[4],  (const float*)d_in[13]};
    const float* conv_b[2] = {(const float*)d_in[5],  (const float*)d_in[14]};
    const float* W_x[2]    = {(const float*)d_in[6],  (const float*)d_in[15]};
    const float* W_dt[2]   = {(const float*)d_in[7],  (const float*)d_in[16]};
    const float* b_dt[2]   = {(const float*)d_in[8],  (const float*)d_in[17]};
    const float* A_log[2]  = {(const float*)d_in[9],  (const float*)d_in[18]};
    const float* Dp[2]     = {(const float*)d_in[10], (const float*)d_in[19]};
    const float* W_out[2]  = {(const float*)d_in[11], (const float*)d_in[20]};
    const float* W_c = (const float*)d_in[21];
    const float* b_c = (const float*)d_in[22];
    float* out = (float*)d_out;

    float* ws = (float*)d_ws;
    float* xz    = ws; ws += (size_t)MROWS * 2 * DINNER;
    float* xc    = ws; ws += (size_t)MROWS * DINNER;
    float* dbl   = ws; ws += (size_t)MROWS * DBLW;
    float* delta = ws; ws += (size_t)MROWS * DINNER;
    float* P     = ws; ws += (size_t)NCHUNK * BATCHN * DSTATE * DINNER;
    float* Q     = ws; ws += (size_t)NCHUNK * BATCHN * DSTATE * DINNER;
    float* part  = ws; ws += (size_t)XP_KSPLIT * MROWS * DBLW;
    unsigned short* us = (unsigned short*)ws;
    unsigned short* xn_bf   = us; us += (size_t)MROWS * DMODEL;
    unsigned short* xnr_bf  = us; us += (size_t)MROWS * DMODEL;
    unsigned short* ymod_bf = us; us += (size_t)MROWS * DINNER;
    unsigned short* outf_bf = us; us += (size_t)MROWS * DMODEL;
    unsigned short* outb_bf = us; us += (size_t)MROWS * DMODEL;
    unsigned short* wt_in   = us; us += (size_t)(2 * DINNER) * DMODEL;   // 3072 x 768
    unsigned short* wt_out  = us; us += (size_t)DMODEL * DINNER;         // 768 x 1536
    unsigned short* wt_c    = us; us += (size_t)DMODEL * (2 * DMODEL);   // 768 x 1536

    ln_kernel<<<MROWS, 256, 0, stream>>>(x, ln_g, ln_b, xn_bf, xnr_bf);
    // W_c is (2*DMODEL=1536) x DMODEL -> wt_c: DMODEL x 1536
    wt_transpose<<<dim3(DMODEL / 32, 2 * DMODEL / 32), 256, 0, stream>>>(
        W_c, wt_c, 2 * DMODEL, DMODEL);

    for (int dir = 0; dir < 2; ++dir) {
        // W_in: (768 x 3072) -> Wt 3072x768
        wt_transpose<<<dim3(2 * DINNER / 32, DMODEL / 32), 256, 0, stream>>>(
            W_in[dir], wt_in, DMODEL, 2 * DINNER);
        gemm_bf16<128, false, false, false><<<dim3(2 * DINNER / 128, MROWS / 128), 256, 0, stream>>>(
            dir ? xnr_bf : xn_bf, nullptr, DMODEL, DMODEL, wt_in, 2 * DINNER, nullptr, xz);

        conv_silu<<<(MROWS * DINNER) / 256, 256, 0, stream>>>(xz, 2 * DINNER,
                                                              conv_w[dir], conv_b[dir], xc);

        dim3 gx(MROWS / XP_BM, XP_KSPLIT);
        xproj_gemm<<<gx, 256, 0, stream>>>(xc, W_x[dir], part);
        xproj_reduce<<<(MROWS * DBLW) / 256, 256, 0, stream>>>(part, dbl);

        gemm_naive<<<(MROWS * DINNER) / 256, 256, 0, stream>>>(
            dbl, DBLW, W_dt[dir], DINNER, b_dt[dir], delta, DINNER, MROWS, DINNER, DTRANK, 1);

        scan_pass1<<<(BATCHN * NCHUNK * DINNER) / 256, 256, 0, stream>>>(
            delta, xc, dbl, A_log[dir], P, Q);
        scan_mid<<<(BATCHN * DSTATE * DINNER) / 256, 256, 0, stream>>>(P, Q);
        scan_pass2<<<(BATCHN * NCHUNK * DINNER) / 256, 256, 0, stream>>>(
            delta, xc, dbl, A_log[dir], Q, Dp[dir], xz + DINNER, 2 * DINNER, ymod_bf);

        // W_out: (1536 x 768) -> Wt 768x1536
        wt_transpose<<<dim3(DMODEL / 32, DINNER / 32), 256, 0, stream>>>(
            W_out[dir], wt_out, DINNER, DMODEL);
        if (dir == 0)
            gemm_bf16<64, false, false, true><<<dim3(DMODEL / 128, MROWS / 64), 256, 0, stream>>>(
                ymod_bf, nullptr, DINNER, DINNER, wt_out, DMODEL, nullptr, outf_bf);
        else
            gemm_bf16<64, true, false, true><<<dim3(DMODEL / 128, MROWS / 64), 256, 0, stream>>>(
                ymod_bf, nullptr, DINNER, DINNER, wt_out, DMODEL, nullptr, outb_bf);
    }

    gemm_bf16<64, false, true, false><<<dim3(DMODEL / 128, MROWS / 64), 256, 0, stream>>>(
        outf_bf, outb_bf, DMODEL, 2 * DMODEL, wt_c, DMODEL, b_c, out);
}

// Round 5
// 469.241 us; speedup vs baseline: 4.0389x; 1.1565x over previous
//
#include <hip/hip_runtime.h>
#include <math.h>

#define BATCHN 2
#define SEQ 1024
#define MROWS 2048      // BATCHN*SEQ
#define DMODEL 768
#define DINNER 1536
#define DSTATE 16
#define DCONV 4
#define DTRANK 48       // (768+15)//16
#define DBLW 80         // DTRANK + 2*DSTATE
#define NCHUNK 32
#define CLEN 32         // SEQ / NCHUNK

typedef __bf16 bf16x8 __attribute__((ext_vector_type(8)));
typedef float  f32x4  __attribute__((ext_vector_type(4)));

__device__ __forceinline__ float silu_f(float x) { return x / (1.f + expf(-x)); }
__device__ __forceinline__ float softplus_f(float x) {
    return fmaxf(x, 0.f) + log1pf(expf(-fabsf(x)));
}
__device__ __forceinline__ unsigned short f2bf(float f) {
    unsigned int u = __float_as_uint(f);
    u += 0x7fffu + ((u >> 16) & 1u);          // round-to-nearest-even
    return (unsigned short)(u >> 16);
}
__device__ __forceinline__ void gload_lds16(const void* g, void* l) {
    __builtin_amdgcn_global_load_lds((const __attribute__((address_space(1))) void*)g,
                                     (__attribute__((address_space(3))) void*)l, 16, 0, 0);
}

// ---------------- LayerNorm -> bf16 (normal + seq-reversed copies) ----------------
__global__ __launch_bounds__(256) void ln_kernel(
    const float* __restrict__ x, const float* __restrict__ g,
    const float* __restrict__ b,
    unsigned short* __restrict__ xn_bf, unsigned short* __restrict__ xnr_bf)
{
    int row = blockIdx.x;
    const float* xr = x + (size_t)row * DMODEL;
    float v[3], s = 0.f, s2 = 0.f;
#pragma unroll
    for (int i = 0; i < 3; ++i) {
        v[i] = xr[threadIdx.x + i * 256];
        s += v[i]; s2 += v[i] * v[i];
    }
#pragma unroll
    for (int off = 32; off > 0; off >>= 1) {
        s  += __shfl_down(s, off);
        s2 += __shfl_down(s2, off);
    }
    __shared__ float red[2][4];
    int wid = threadIdx.x >> 6, lane = threadIdx.x & 63;
    if (lane == 0) { red[0][wid] = s; red[1][wid] = s2; }
    __syncthreads();
    if (threadIdx.x == 0) {
        float ts = 0.f, ts2 = 0.f;
        for (int w = 0; w < 4; ++w) { ts += red[0][w]; ts2 += red[1][w]; }
        red[0][0] = ts; red[1][0] = ts2;
    }
    __syncthreads();
    float mean = red[0][0] * (1.f / DMODEL);
    float var  = red[1][0] * (1.f / DMODEL) - mean * mean;
    float rstd = rsqrtf(var + 1e-5f);
    int rrow = row ^ (SEQ - 1);              // flip within batch
#pragma unroll
    for (int i = 0; i < 3; ++i) {
        int c = threadIdx.x + i * 256;
        unsigned short h = f2bf((v[i] - mean) * rstd * g[c] + b[c]);
        xn_bf [(size_t)row  * DMODEL + c] = h;
        xnr_bf[(size_t)rrow * DMODEL + c] = h;
    }
}

// ---------------- weight transpose + fp32->bf16: W[K][N] -> Wt[N][K] ----------------
__global__ __launch_bounds__(256) void wt_transpose(
    const float* __restrict__ W, unsigned short* __restrict__ Wt, int K, int N)
{
    __shared__ float t[32][33];
    int n0 = blockIdx.x * 32, k0 = blockIdx.y * 32;
    int tx = threadIdx.x & 31, ty = threadIdx.x >> 5;
#pragma unroll
    for (int i = 0; i < 4; ++i)
        t[ty + i * 8][tx] = W[(size_t)(k0 + ty + i * 8) * N + n0 + tx];
    __syncthreads();
#pragma unroll
    for (int i = 0; i < 4; ++i)
        Wt[(size_t)(n0 + ty + i * 8) * K + k0 + tx] = f2bf(t[tx][ty + i * 8]);
}

// ---------------- bf16 MFMA GEMM ----------------
// A: M x K bf16 row-major (lda). Bt: N x K bf16 row-major (ldb=K). C: M x N.
// Tile BM x 128, BK=32. 4 waves as 2x2; wave tile (BM/2) x 64.
// REVC: C row ^= 1023 (per-batch seq flip). CONCAT: k<768 from A else A2.
// CBF16: C stored as bf16, else fp32.
template <int BM, bool REVC, bool CONCAT, bool CBF16>
__global__ __launch_bounds__(256) void gemm_bf16(
    const unsigned short* __restrict__ A, const unsigned short* __restrict__ A2,
    int lda, int K,
    const unsigned short* __restrict__ Bt, int N,
    const float* __restrict__ bias, void* __restrict__ Cv)
{
    constexpr int MI = BM / 32;
    __shared__ unsigned short lsA[BM * 32];
    __shared__ unsigned short lsB[128 * 32];
    int tid = threadIdx.x;
    int w = tid >> 6, lane = tid & 63;
    int wm = w >> 1, wn = w & 1;
    int bm = blockIdx.y * BM, bn = blockIdx.x * 128;
    int sr = lane >> 2, sc = (lane & 3) * 8;
    int l15 = lane & 15, kq = (lane >> 4) * 8;

    f32x4 acc[MI][4];
#pragma unroll
    for (int mi = 0; mi < MI; ++mi)
#pragma unroll
        for (int ni = 0; ni < 4; ++ni) acc[mi][ni] = (f32x4){0.f, 0.f, 0.f, 0.f};

    for (int kb = 0; kb < K; kb += 32) {
        const unsigned short* ap; int kc;
        if (CONCAT) {
            ap = (kb < DMODEL) ? A : A2;
            kc = (kb < DMODEL) ? kb : kb - DMODEL;
        } else { ap = A; kc = kb; }
#pragma unroll
        for (int r = 0; r < BM / 64; ++r) {
            const void* gp = ap + (size_t)(bm + r * 64 + w * 16 + sr) * lda + kc + sc;
            gload_lds16(gp, (void*)&lsA[(r * 64 + w * 16) * 32]);
        }
#pragma unroll
        for (int r = 0; r < 2; ++r) {
            const void* gp = Bt + (size_t)(bn + r * 64 + w * 16 + sr) * K + kb + sc;
            gload_lds16(gp, (void*)&lsB[(r * 64 + w * 16) * 32]);
        }
        __syncthreads();
        bf16x8 af[MI], bfr[4];
#pragma unroll
        for (int mi = 0; mi < MI; ++mi)
            af[mi] = *(const bf16x8*)&lsA[(wm * (BM / 2) + mi * 16 + l15) * 32 + kq];
#pragma unroll
        for (int ni = 0; ni < 4; ++ni)
            bfr[ni] = *(const bf16x8*)&lsB[(wn * 64 + ni * 16 + l15) * 32 + kq];
#pragma unroll
        for (int mi = 0; mi < MI; ++mi)
#pragma unroll
            for (int ni = 0; ni < 4; ++ni)
                acc[mi][ni] = __builtin_amdgcn_mfma_f32_16x16x32_bf16(
                    af[mi], bfr[ni], acc[mi][ni], 0, 0, 0);
        __syncthreads();
    }

    int r4 = (lane >> 4) * 4;
#pragma unroll
    for (int mi = 0; mi < MI; ++mi) {
#pragma unroll
        for (int ni = 0; ni < 4; ++ni) {
            int col = bn + wn * 64 + ni * 16 + l15;
            float bv = bias ? bias[col] : 0.f;
#pragma unroll
            for (int r = 0; r < 4; ++r) {
                int row = bm + wm * (BM / 2) + mi * 16 + r4 + r;
                if (REVC) row ^= (SEQ - 1);
                float val = acc[mi][ni][r] + bv;
                if (CBF16)
                    ((unsigned short*)Cv)[(size_t)row * N + col] = f2bf(val);
                else
                    ((float*)Cv)[(size_t)row * N + col] = val;
            }
        }
    }
}

// ---------------- x-proj GEMM: 2048x80x1536, tiled split-K ----------------
#define XP_BM 32
#define XP_BK 32
#define XP_KSPLIT 4
#define XP_KCH (DINNER / XP_KSPLIT)   // 384

__global__ __launch_bounds__(256) void xproj_gemm(
    const float* __restrict__ A,   // xc: 2048 x 1536
    const float* __restrict__ B,   // W_x: 1536 x 80
    float* __restrict__ part)      // KSPLIT x 2048 x 80
{
    __shared__ float As[XP_BK][XP_BM + 1];
    __shared__ float Bs[XP_BK][DBLW + 1];
    int tid = threadIdx.x;
    int bm = blockIdx.x * XP_BM;
    int k0 = blockIdx.y * XP_KCH;
    int tm = (tid >> 4) * 2;
    int tn = (tid & 15) * 5;
    float acc[2][5];
#pragma unroll
    for (int i = 0; i < 2; ++i)
#pragma unroll
        for (int j = 0; j < 5; ++j) acc[i][j] = 0.f;

    int ar = tid >> 3;
    int ac = (tid & 7) * 4;

    for (int kb = 0; kb < XP_KCH; kb += XP_BK) {
        float4 va = *(const float4*)(A + (size_t)(bm + ar) * DINNER + k0 + kb + ac);
        As[ac + 0][ar] = va.x; As[ac + 1][ar] = va.y;
        As[ac + 2][ar] = va.z; As[ac + 3][ar] = va.w;
#pragma unroll
        for (int i = 0; i < 10; ++i) {
            int li = tid + i * 256;
            int kk = li / DBLW, nn = li - kk * DBLW;
            Bs[kk][nn] = B[(size_t)(k0 + kb + kk) * DBLW + nn];
        }
        __syncthreads();
#pragma unroll
        for (int k = 0; k < XP_BK; ++k) {
            float a0 = As[k][tm], a1 = As[k][tm + 1];
            float b0 = Bs[k][tn + 0], b1 = Bs[k][tn + 1], b2 = Bs[k][tn + 2];
            float b3 = Bs[k][tn + 3], b4 = Bs[k][tn + 4];
            acc[0][0] = fmaf(a0, b0, acc[0][0]); acc[0][1] = fmaf(a0, b1, acc[0][1]);
            acc[0][2] = fmaf(a0, b2, acc[0][2]); acc[0][3] = fmaf(a0, b3, acc[0][3]);
            acc[0][4] = fmaf(a0, b4, acc[0][4]);
            acc[1][0] = fmaf(a1, b0, acc[1][0]); acc[1][1] = fmaf(a1, b1, acc[1][1]);
            acc[1][2] = fmaf(a1, b2, acc[1][2]); acc[1][3] = fmaf(a1, b3, acc[1][3]);
            acc[1][4] = fmaf(a1, b4, acc[1][4]);
        }
        __syncthreads();
    }
    size_t base = ((size_t)blockIdx.y * MROWS + bm) * DBLW;
#pragma unroll
    for (int i = 0; i < 2; ++i)
#pragma unroll
        for (int j = 0; j < 5; ++j)
            part[base + (size_t)(tm + i) * DBLW + tn + j] = acc[i][j];
}

__global__ __launch_bounds__(256) void xproj_reduce(
    const float* __restrict__ part, float* __restrict__ dbl)
{
    int idx = blockIdx.x * 256 + threadIdx.x;
    float s = 0.f;
#pragma unroll
    for (int ks = 0; ks < XP_KSPLIT; ++ks)
        s += part[(size_t)ks * MROWS * DBLW + idx];
    dbl[idx] = s;
}

// ---------------- delta GEMM: 2048 x 1536, K=48, + softplus ----------------
// A = dbl (2048 x 80, cols 0..47), B = W_dt (48 x 1536), bias b_dt.
#define DT_BM 64
#define DT_BN 128
__global__ __launch_bounds__(256) void dt_gemm(
    const float* __restrict__ dbl_, const float* __restrict__ Wdt,
    const float* __restrict__ bdt, float* __restrict__ delta)
{
    __shared__ float As[DTRANK][DT_BM + 1];   // 48 x 65
    __shared__ float Bs[DTRANK][DT_BN + 4];   // 48 x 132
    int tid = threadIdx.x;
    int bm = blockIdx.y * DT_BM, bn = blockIdx.x * DT_BN;
#pragma unroll
    for (int i = 0; i < 12; ++i) {
        int li = tid + i * 256;        // 0..3071
        int r = li / DTRANK, c = li % DTRANK;
        As[c][r] = dbl_[(size_t)(bm + r) * DBLW + c];
    }
#pragma unroll
    for (int i = 0; i < 6; ++i) {
        int fi = tid + i * 256;        // float4 idx 0..1535
        int r = fi >> 5, c4 = (fi & 31) * 4;
        *(float4*)&Bs[r][c4] = *(const float4*)(Wdt + (size_t)r * DINNER + bn + c4);
    }
    __syncthreads();
    int tm = (tid >> 4) * 4, tn = (tid & 15) * 8;
    float acc[4][8] = {};
#pragma unroll
    for (int k = 0; k < DTRANK; ++k) {
        float a[4], b[8];
        *(float4*)a     = *(const float4*)&As[k][tm];
        *(float4*)&b[0] = *(const float4*)&Bs[k][tn];
        *(float4*)&b[4] = *(const float4*)&Bs[k][tn + 4];
#pragma unroll
        for (int i = 0; i < 4; ++i)
#pragma unroll
            for (int j = 0; j < 8; ++j)
                acc[i][j] = fmaf(a[i], b[j], acc[i][j]);
    }
#pragma unroll
    for (int i = 0; i < 4; ++i) {
#pragma unroll
        for (int j = 0; j < 8; ++j)
            acc[i][j] = softplus_f(acc[i][j] + bdt[bn + tn + j]);
        *(float4*)(delta + (size_t)(bm + tm + i) * DINNER + bn + tn)     = *(float4*)&acc[i][0];
        *(float4*)(delta + (size_t)(bm + tm + i) * DINNER + bn + tn + 4) = *(float4*)&acc[i][4];
    }
}

// ---------------- Causal depthwise conv (K=4) + SiLU ----------------
__global__ __launch_bounds__(256) void conv_silu(
    const float* __restrict__ xi, int lda,
    const float* __restrict__ w, const float* __restrict__ cb,
    float* __restrict__ xc)
{
    int idx = blockIdx.x * 256 + threadIdx.x;
    int d = idx % DINNER;
    int r = idx / DINNER;
    int s = r & (SEQ - 1);
    float acc = cb[d];
#pragma unroll
    for (int k = 0; k < DCONV; ++k) {
        int off = k - (DCONV - 1);
        float xv = (s + off >= 0) ? xi[(size_t)(r + off) * lda + d] : 0.f;
        acc = fmaf(xv, w[d * DCONV + k], acc);
    }
    xc[idx] = silu_f(acc);
}

// ---------------- Selective scan, chunked (3 kernels) ----------------
__global__ __launch_bounds__(256) void scan_pass1(
    const float* __restrict__ delta, const float* __restrict__ u_,
    const float* __restrict__ dbl, const float* __restrict__ A_log,
    float* __restrict__ P, float* __restrict__ Q)
{
    int tid = blockIdx.x * 256 + threadIdx.x;
    int d = tid % DINNER;
    int t2 = tid / DINNER;
    int c = t2 % NCHUNK;
    int b = t2 / NCHUNK;
    float A[DSTATE], h[DSTATE];
#pragma unroll
    for (int n = 0; n < DSTATE; ++n) { A[n] = -expf(A_log[d * DSTATE + n]); h[n] = 0.f; }
    float sumd = 0.f;
    int r0 = b * SEQ + c * CLEN;
    for (int t = 0; t < CLEN; ++t) {
        int r = r0 + t;
        float dl = delta[(size_t)r * DINNER + d];
        float u  = u_[(size_t)r * DINNER + d];
        float du = dl * u;
        sumd += dl;
        const float* Brow = dbl + (size_t)r * DBLW + DTRANK;
#pragma unroll
        for (int n = 0; n < DSTATE; ++n) {
            float a = expf(dl * A[n]);
            h[n] = fmaf(a, h[n], du * Brow[n]);
        }
    }
    size_t base = ((size_t)(c * BATCHN + b) * DSTATE) * DINNER + d;
#pragma unroll
    for (int n = 0; n < DSTATE; ++n) {
        P[base + (size_t)n * DINNER] = expf(sumd * A[n]);
        Q[base + (size_t)n * DINNER] = h[n];
    }
}

__global__ __launch_bounds__(256) void scan_mid(
    const float* __restrict__ P, float* __restrict__ Q)
{
    int tid = blockIdx.x * 256 + threadIdx.x;
    int d = tid % DINNER;
    int rem = tid / DINNER;
    int n = rem % DSTATE;
    int b = rem / DSTATE;
    float H = 0.f;
    for (int c = 0; c < NCHUNK; ++c) {
        size_t idx = ((size_t)((c * BATCHN + b) * DSTATE + n)) * DINNER + d;
        float p = P[idx], q = Q[idx];
        Q[idx] = H;
        H = fmaf(p, H, q);
    }
}

__global__ __launch_bounds__(256) void scan_pass2(
    const float* __restrict__ delta, const float* __restrict__ u_,
    const float* __restrict__ dbl, const float* __restrict__ A_log,
    const float* __restrict__ Hinit, const float* __restrict__ Dp,
    const float* __restrict__ z, int ldz,
    unsigned short* __restrict__ ymod_bf)
{
    int tid = blockIdx.x * 256 + threadIdx.x;
    int d = tid % DINNER;
    int t2 = tid / DINNER;
    int c = t2 % NCHUNK;
    int b = t2 / NCHUNK;
    float A[DSTATE], h[DSTATE];
    size_t base = ((size_t)(c * BATCHN + b) * DSTATE) * DINNER + d;
#pragma unroll
    for (int n = 0; n < DSTATE; ++n) {
        A[n] = -expf(A_log[d * DSTATE + n]);
        h[n] = Hinit[base + (size_t)n * DINNER];
    }
    float Dd = Dp[d];
    int r0 = b * SEQ + c * CLEN;
    for (int t = 0; t < CLEN; ++t) {
        int r = r0 + t;
        float dl = delta[(size_t)r * DINNER + d];
        float u  = u_[(size_t)r * DINNER + d];
        float du = dl * u;
        const float* Brow = dbl + (size_t)r * DBLW + DTRANK;
        const float* Crow = Brow + DSTATE;
        float y = 0.f;
#pragma unroll
        for (int n = 0; n < DSTATE; ++n) {
            float a = expf(dl * A[n]);
            h[n] = fmaf(a, h[n], du * Brow[n]);
            y = fmaf(h[n], Crow[n], y);
        }
        float zz = z[(size_t)r * ldz + d];
        float sig = 1.f / (1.f + expf(-zz));
        ymod_bf[(size_t)r * DINNER + d] = f2bf((y + u * Dd) * (zz * sig));
    }
}

// ---------------- launch ----------------
extern "C" void kernel_launch(void* const* d_in, const int* in_sizes, int n_in,
                              void* d_out, int out_size, void* d_ws, size_t ws_size,
                              hipStream_t stream)
{
    (void)in_sizes; (void)n_in; (void)out_size; (void)ws_size;
    const float* x    = (const float*)d_in[0];
    const float* ln_g = (const float*)d_in[1];
    const float* ln_b = (const float*)d_in[2];
    const float* W_in[2]   = {(const float*)d_in[3],  (const float*)d_in[12]};
    const float* conv_w[2] = {(const float*)d_in[4],  (const float*)d_in[13]};
    const float* conv_b[2] = {(const float*)d_in[5],  (const float*)d_in[14]};
    const float* W_x[2]    = {(const float*)d_in[6],  (const float*)d_in[15]};
    const float* W_dt[2]   = {(const float*)d_in[7],  (const float*)d_in[16]};
    const float* b_dt[2]   = {(const float*)d_in[8],  (const float*)d_in[17]};
    const float* A_log[2]  = {(const float*)d_in[9],  (const float*)d_in[18]};
    const float* Dp[2]     = {(const float*)d_in[10], (const float*)d_in[19]};
    const float* W_out[2]  = {(const float*)d_in[11], (const float*)d_in[20]};
    const float* W_c = (const float*)d_in[21];
    const float* b_c = (const float*)d_in[22];
    float* out = (float*)d_out;

    float* ws = (float*)d_ws;
    float* xz    = ws; ws += (size_t)MROWS * 2 * DINNER;
    float* xc    = ws; ws += (size_t)MROWS * DINNER;
    float* dbl   = ws; ws += (size_t)MROWS * DBLW;
    float* delta = ws; ws += (size_t)MROWS * DINNER;
    float* P     = ws; ws += (size_t)NCHUNK * BATCHN * DSTATE * DINNER;
    float* Q     = ws; ws += (size_t)NCHUNK * BATCHN * DSTATE * DINNER;
    float* part  = ws; ws += (size_t)XP_KSPLIT * MROWS * DBLW;
    unsigned short* us = (unsigned short*)ws;
    unsigned short* xn_bf   = us; us += (size_t)MROWS * DMODEL;
    unsigned short* xnr_bf  = us; us += (size_t)MROWS * DMODEL;
    unsigned short* ymod_bf = us; us += (size_t)MROWS * DINNER;
    unsigned short* outf_bf = us; us += (size_t)MROWS * DMODEL;
    unsigned short* outb_bf = us; us += (size_t)MROWS * DMODEL;
    unsigned short* wt_in   = us; us += (size_t)(2 * DINNER) * DMODEL;   // 3072 x 768
    unsigned short* wt_out  = us; us += (size_t)DMODEL * DINNER;         // 768 x 1536
    unsigned short* wt_c    = us; us += (size_t)DMODEL * (2 * DMODEL);   // 768 x 1536

    ln_kernel<<<MROWS, 256, 0, stream>>>(x, ln_g, ln_b, xn_bf, xnr_bf);
    // W_c is (2*DMODEL=1536) x DMODEL -> wt_c: DMODEL x 1536
    wt_transpose<<<dim3(DMODEL / 32, 2 * DMODEL / 32), 256, 0, stream>>>(
        W_c, wt_c, 2 * DMODEL, DMODEL);

    for (int dir = 0; dir < 2; ++dir) {
        // W_in: (768 x 3072) -> Wt 3072x768
        wt_transpose<<<dim3(2 * DINNER / 32, DMODEL / 32), 256, 0, stream>>>(
            W_in[dir], wt_in, DMODEL, 2 * DINNER);
        gemm_bf16<128, false, false, false><<<dim3(2 * DINNER / 128, MROWS / 128), 256, 0, stream>>>(
            dir ? xnr_bf : xn_bf, nullptr, DMODEL, DMODEL, wt_in, 2 * DINNER, nullptr, xz);

        conv_silu<<<(MROWS * DINNER) / 256, 256, 0, stream>>>(xz, 2 * DINNER,
                                                              conv_w[dir], conv_b[dir], xc);

        dim3 gx(MROWS / XP_BM, XP_KSPLIT);
        xproj_gemm<<<gx, 256, 0, stream>>>(xc, W_x[dir], part);
        xproj_reduce<<<(MROWS * DBLW) / 256, 256, 0, stream>>>(part, dbl);

        dt_gemm<<<dim3(DINNER / DT_BN, MROWS / DT_BM), 256, 0, stream>>>(
            dbl, W_dt[dir], b_dt[dir], delta);

        scan_pass1<<<(BATCHN * NCHUNK * DINNER) / 256, 256, 0, stream>>>(
            delta, xc, dbl, A_log[dir], P, Q);
        scan_mid<<<(BATCHN * DSTATE * DINNER) / 256, 256, 0, stream>>>(P, Q);
        scan_pass2<<<(BATCHN * NCHUNK * DINNER) / 256, 256, 0, stream>>>(
            delta, xc, dbl, A_log[dir], Q, Dp[dir], xz + DINNER, 2 * DINNER, ymod_bf);

        // W_out: (1536 x 768) -> Wt 768x1536
        wt_transpose<<<dim3(DMODEL / 32, DINNER / 32), 256, 0, stream>>>(
            W_out[dir], wt_out, DINNER, DMODEL);
        if (dir == 0)
            gemm_bf16<64, false, false, true><<<dim3(DMODEL / 128, MROWS / 64), 256, 0, stream>>>(
                ymod_bf, nullptr, DINNER, DINNER, wt_out, DMODEL, nullptr, outf_bf);
        else
            gemm_bf16<64, true, false, true><<<dim3(DMODEL / 128, MROWS / 64), 256, 0, stream>>>(
                ymod_bf, nullptr, DINNER, DINNER, wt_out, DMODEL, nullptr, outb_bf);
    }

    gemm_bf16<64, false, true, false><<<dim3(DMODEL / 128, MROWS / 64), 256, 0, stream>>>(
        outf_bf, outb_bf, DMODEL, 2 * DMODEL, wt_c, DMODEL, b_c, out);
}

// Round 6
// 372.068 us; speedup vs baseline: 5.0938x; 1.2612x over previous
//
#include <hip/hip_runtime.h>
#include <math.h>

#define BATCHN 2
#define SEQ 1024
#define MROWS 2048      // BATCHN*SEQ
#define DMODEL 768
#define DINNER 1536
#define DSTATE 16
#define DCONV 4
#define DTRANK 48       // (768+15)//16
#define DBLW 80         // DTRANK + 2*DSTATE

typedef __bf16 bf16x8 __attribute__((ext_vector_type(8)));
typedef float  f32x4  __attribute__((ext_vector_type(4)));

__device__ __forceinline__ float silu_f(float x) { return x / (1.f + expf(-x)); }
__device__ __forceinline__ float softplus_f(float x) {
    return fmaxf(x, 0.f) + log1pf(expf(-fabsf(x)));
}
__device__ __forceinline__ unsigned short f2bf(float f) {
    unsigned int u = __float_as_uint(f);
    u += 0x7fffu + ((u >> 16) & 1u);          // round-to-nearest-even
    return (unsigned short)(u >> 16);
}
__device__ __forceinline__ void gload_lds16(const void* g, void* l) {
    __builtin_amdgcn_global_load_lds((const __attribute__((address_space(1))) void*)g,
                                     (__attribute__((address_space(3))) void*)l, 16, 0, 0);
}

// ---------------- LayerNorm -> bf16 (normal + seq-reversed copies) ----------------
__global__ __launch_bounds__(256) void ln_kernel(
    const float* __restrict__ x, const float* __restrict__ g,
    const float* __restrict__ b,
    unsigned short* __restrict__ xn_bf, unsigned short* __restrict__ xnr_bf)
{
    int row = blockIdx.x;
    const float* xr = x + (size_t)row * DMODEL;
    float v[3], s = 0.f, s2 = 0.f;
#pragma unroll
    for (int i = 0; i < 3; ++i) {
        v[i] = xr[threadIdx.x + i * 256];
        s += v[i]; s2 += v[i] * v[i];
    }
#pragma unroll
    for (int off = 32; off > 0; off >>= 1) {
        s  += __shfl_down(s, off);
        s2 += __shfl_down(s2, off);
    }
    __shared__ float red[2][4];
    int wid = threadIdx.x >> 6, lane = threadIdx.x & 63;
    if (lane == 0) { red[0][wid] = s; red[1][wid] = s2; }
    __syncthreads();
    if (threadIdx.x == 0) {
        float ts = 0.f, ts2 = 0.f;
        for (int w = 0; w < 4; ++w) { ts += red[0][w]; ts2 += red[1][w]; }
        red[0][0] = ts; red[1][0] = ts2;
    }
    __syncthreads();
    float mean = red[0][0] * (1.f / DMODEL);
    float var  = red[1][0] * (1.f / DMODEL) - mean * mean;
    float rstd = rsqrtf(var + 1e-5f);
    int rrow = row ^ (SEQ - 1);              // flip within batch
#pragma unroll
    for (int i = 0; i < 3; ++i) {
        int c = threadIdx.x + i * 256;
        unsigned short h = f2bf((v[i] - mean) * rstd * g[c] + b[c]);
        xn_bf [(size_t)row  * DMODEL + c] = h;
        xnr_bf[(size_t)rrow * DMODEL + c] = h;
    }
}

// ---------------- weight transpose + fp32->bf16: W[K][N] -> Wt[N][K] ----------------
__global__ __launch_bounds__(256) void wt_transpose(
    const float* __restrict__ W, unsigned short* __restrict__ Wt, int K, int N)
{
    __shared__ float t[32][33];
    int n0 = blockIdx.x * 32, k0 = blockIdx.y * 32;
    int tx = threadIdx.x & 31, ty = threadIdx.x >> 5;
#pragma unroll
    for (int i = 0; i < 4; ++i)
        t[ty + i * 8][tx] = W[(size_t)(k0 + ty + i * 8) * N + n0 + tx];
    __syncthreads();
#pragma unroll
    for (int i = 0; i < 4; ++i)
        Wt[(size_t)(n0 + ty + i * 8) * K + k0 + tx] = f2bf(t[tx][ty + i * 8]);
}

// ---------------- bf16 MFMA GEMM ----------------
// A: M x K bf16 row-major (lda). Bt: N x K bf16 row-major (ldb=K). C: M x N.
// Tile BM x 128, BK=32. 4 waves as 2x2; wave tile (BM/2) x 64.
// REVC: C row ^= 1023 (per-batch seq flip). CONCAT: k<768 from A else A2.
// CBF16: C stored as bf16, else fp32.
template <int BM, bool REVC, bool CONCAT, bool CBF16>
__global__ __launch_bounds__(256) void gemm_bf16(
    const unsigned short* __restrict__ A, const unsigned short* __restrict__ A2,
    int lda, int K,
    const unsigned short* __restrict__ Bt, int N,
    const float* __restrict__ bias, void* __restrict__ Cv)
{
    constexpr int MI = BM / 32;
    __shared__ unsigned short lsA[BM * 32];
    __shared__ unsigned short lsB[128 * 32];
    int tid = threadIdx.x;
    int w = tid >> 6, lane = tid & 63;
    int wm = w >> 1, wn = w & 1;
    int bm = blockIdx.y * BM, bn = blockIdx.x * 128;
    int sr = lane >> 2, sc = (lane & 3) * 8;
    int l15 = lane & 15, kq = (lane >> 4) * 8;

    f32x4 acc[MI][4];
#pragma unroll
    for (int mi = 0; mi < MI; ++mi)
#pragma unroll
        for (int ni = 0; ni < 4; ++ni) acc[mi][ni] = (f32x4){0.f, 0.f, 0.f, 0.f};

    for (int kb = 0; kb < K; kb += 32) {
        const unsigned short* ap; int kc;
        if (CONCAT) {
            ap = (kb < DMODEL) ? A : A2;
            kc = (kb < DMODEL) ? kb : kb - DMODEL;
        } else { ap = A; kc = kb; }
#pragma unroll
        for (int r = 0; r < BM / 64; ++r) {
            const void* gp = ap + (size_t)(bm + r * 64 + w * 16 + sr) * lda + kc + sc;
            gload_lds16(gp, (void*)&lsA[(r * 64 + w * 16) * 32]);
        }
#pragma unroll
        for (int r = 0; r < 2; ++r) {
            const void* gp = Bt + (size_t)(bn + r * 64 + w * 16 + sr) * K + kb + sc;
            gload_lds16(gp, (void*)&lsB[(r * 64 + w * 16) * 32]);
        }
        __syncthreads();
        bf16x8 af[MI], bfr[4];
#pragma unroll
        for (int mi = 0; mi < MI; ++mi)
            af[mi] = *(const bf16x8*)&lsA[(wm * (BM / 2) + mi * 16 + l15) * 32 + kq];
#pragma unroll
        for (int ni = 0; ni < 4; ++ni)
            bfr[ni] = *(const bf16x8*)&lsB[(wn * 64 + ni * 16 + l15) * 32 + kq];
#pragma unroll
        for (int mi = 0; mi < MI; ++mi)
#pragma unroll
            for (int ni = 0; ni < 4; ++ni)
                acc[mi][ni] = __builtin_amdgcn_mfma_f32_16x16x32_bf16(
                    af[mi], bfr[ni], acc[mi][ni], 0, 0, 0);
        __syncthreads();
    }

    int r4 = (lane >> 4) * 4;
#pragma unroll
    for (int mi = 0; mi < MI; ++mi) {
#pragma unroll
        for (int ni = 0; ni < 4; ++ni) {
            int col = bn + wn * 64 + ni * 16 + l15;
            float bv = bias ? bias[col] : 0.f;
#pragma unroll
            for (int r = 0; r < 4; ++r) {
                int row = bm + wm * (BM / 2) + mi * 16 + r4 + r;
                if (REVC) row ^= (SEQ - 1);
                float val = acc[mi][ni][r] + bv;
                if (CBF16)
                    ((unsigned short*)Cv)[(size_t)row * N + col] = f2bf(val);
                else
                    ((float*)Cv)[(size_t)row * N + col] = val;
            }
        }
    }
}

// ---------------- x-proj GEMM: 2048x80x1536, tiled split-K ----------------
#define XP_BM 32
#define XP_BK 32
#define XP_KSPLIT 4
#define XP_KCH (DINNER / XP_KSPLIT)   // 384

__global__ __launch_bounds__(256) void xproj_gemm(
    const float* __restrict__ A,   // xc: 2048 x 1536
    const float* __restrict__ B,   // W_x: 1536 x 80
    float* __restrict__ part)      // KSPLIT x 2048 x 80
{
    __shared__ float As[XP_BK][XP_BM + 1];
    __shared__ float Bs[XP_BK][DBLW + 1];
    int tid = threadIdx.x;
    int bm = blockIdx.x * XP_BM;
    int k0 = blockIdx.y * XP_KCH;
    int tm = (tid >> 4) * 2;
    int tn = (tid & 15) * 5;
    float acc[2][5];
#pragma unroll
    for (int i = 0; i < 2; ++i)
#pragma unroll
        for (int j = 0; j < 5; ++j) acc[i][j] = 0.f;

    int ar = tid >> 3;
    int ac = (tid & 7) * 4;

    for (int kb = 0; kb < XP_KCH; kb += XP_BK) {
        float4 va = *(const float4*)(A + (size_t)(bm + ar) * DINNER + k0 + kb + ac);
        As[ac + 0][ar] = va.x; As[ac + 1][ar] = va.y;
        As[ac + 2][ar] = va.z; As[ac + 3][ar] = va.w;
#pragma unroll
        for (int i = 0; i < 10; ++i) {
            int li = tid + i * 256;
            int kk = li / DBLW, nn = li - kk * DBLW;
            Bs[kk][nn] = B[(size_t)(k0 + kb + kk) * DBLW + nn];
        }
        __syncthreads();
#pragma unroll
        for (int k = 0; k < XP_BK; ++k) {
            float a0 = As[k][tm], a1 = As[k][tm + 1];
            float b0 = Bs[k][tn + 0], b1 = Bs[k][tn + 1], b2 = Bs[k][tn + 2];
            float b3 = Bs[k][tn + 3], b4 = Bs[k][tn + 4];
            acc[0][0] = fmaf(a0, b0, acc[0][0]); acc[0][1] = fmaf(a0, b1, acc[0][1]);
            acc[0][2] = fmaf(a0, b2, acc[0][2]); acc[0][3] = fmaf(a0, b3, acc[0][3]);
            acc[0][4] = fmaf(a0, b4, acc[0][4]);
            acc[1][0] = fmaf(a1, b0, acc[1][0]); acc[1][1] = fmaf(a1, b1, acc[1][1]);
            acc[1][2] = fmaf(a1, b2, acc[1][2]); acc[1][3] = fmaf(a1, b3, acc[1][3]);
            acc[1][4] = fmaf(a1, b4, acc[1][4]);
        }
        __syncthreads();
    }
    size_t base = ((size_t)blockIdx.y * MROWS + bm) * DBLW;
#pragma unroll
    for (int i = 0; i < 2; ++i)
#pragma unroll
        for (int j = 0; j < 5; ++j)
            part[base + (size_t)(tm + i) * DBLW + tn + j] = acc[i][j];
}

__global__ __launch_bounds__(256) void xproj_reduce(
    const float* __restrict__ part, float* __restrict__ dbl)
{
    int idx = blockIdx.x * 256 + threadIdx.x;
    float s = 0.f;
#pragma unroll
    for (int ks = 0; ks < XP_KSPLIT; ++ks)
        s += part[(size_t)ks * MROWS * DBLW + idx];
    dbl[idx] = s;
}

// ---------------- delta GEMM: 2048 x 1536, K=48, + softplus ----------------
#define DT_BM 64
#define DT_BN 128
__global__ __launch_bounds__(256) void dt_gemm(
    const float* __restrict__ dbl_, const float* __restrict__ Wdt,
    const float* __restrict__ bdt, float* __restrict__ delta)
{
    __shared__ float As[DTRANK][DT_BM + 1];   // 48 x 65
    __shared__ float Bs[DTRANK][DT_BN + 4];   // 48 x 132
    int tid = threadIdx.x;
    int bm = blockIdx.y * DT_BM, bn = blockIdx.x * DT_BN;
#pragma unroll
    for (int i = 0; i < 12; ++i) {
        int li = tid + i * 256;        // 0..3071
        int r = li / DTRANK, c = li % DTRANK;
        As[c][r] = dbl_[(size_t)(bm + r) * DBLW + c];
    }
#pragma unroll
    for (int i = 0; i < 6; ++i) {
        int fi = tid + i * 256;        // float4 idx 0..1535
        int r = fi >> 5, c4 = (fi & 31) * 4;
        *(float4*)&Bs[r][c4] = *(const float4*)(Wdt + (size_t)r * DINNER + bn + c4);
    }
    __syncthreads();
    int tm = (tid >> 4) * 4, tn = (tid & 15) * 8;
    float acc[4][8] = {};
#pragma unroll
    for (int k = 0; k < DTRANK; ++k) {
        float a[4], b[8];
        *(float4*)a     = *(const float4*)&As[k][tm];
        *(float4*)&b[0] = *(const float4*)&Bs[k][tn];
        *(float4*)&b[4] = *(const float4*)&Bs[k][tn + 4];
#pragma unroll
        for (int i = 0; i < 4; ++i)
#pragma unroll
            for (int j = 0; j < 8; ++j)
                acc[i][j] = fmaf(a[i], b[j], acc[i][j]);
    }
#pragma unroll
    for (int i = 0; i < 4; ++i) {
#pragma unroll
        for (int j = 0; j < 8; ++j)
            acc[i][j] = softplus_f(acc[i][j] + bdt[bn + tn + j]);
        *(float4*)(delta + (size_t)(bm + tm + i) * DINNER + bn + tn)     = *(float4*)&acc[i][0];
        *(float4*)(delta + (size_t)(bm + tm + i) * DINNER + bn + tn + 4) = *(float4*)&acc[i][4];
    }
}

// ---------------- Causal depthwise conv (K=4) + SiLU ----------------
__global__ __launch_bounds__(256) void conv_silu(
    const float* __restrict__ xi, int lda,
    const float* __restrict__ w, const float* __restrict__ cb,
    float* __restrict__ xc)
{
    int idx = blockIdx.x * 256 + threadIdx.x;
    int d = idx % DINNER;
    int r = idx / DINNER;
    int s = r & (SEQ - 1);
    float acc = cb[d];
#pragma unroll
    for (int k = 0; k < DCONV; ++k) {
        int off = k - (DCONV - 1);
        float xv = (s + off >= 0) ? xi[(size_t)(r + off) * lda + d] : 0.f;
        acc = fmaf(xv, w[d * DCONV + k], acc);
    }
    xc[idx] = silu_f(acc);
}

// ---------------- Selective scan, chunked (3 kernels), NC chunks ----------------
template <int NC>
__global__ __launch_bounds__(256) void scan_pass1(
    const float* __restrict__ delta, const float* __restrict__ u_,
    const float* __restrict__ dbl, const float* __restrict__ A_log,
    float* __restrict__ P, float* __restrict__ Q)
{
    constexpr int CL = SEQ / NC;
    int tid = blockIdx.x * 256 + threadIdx.x;   // BATCHN*NC*DINNER
    int d = tid % DINNER;
    int t2 = tid / DINNER;
    int c = t2 % NC;
    int b = t2 / NC;
    float A[DSTATE], h[DSTATE];
#pragma unroll
    for (int n = 0; n < DSTATE; ++n) { A[n] = -__expf(A_log[d * DSTATE + n]); h[n] = 0.f; }
    float sumd = 0.f;
    int r0 = b * SEQ + c * CL;
#pragma unroll 2
    for (int t = 0; t < CL; ++t) {
        int r = r0 + t;
        float dl = delta[(size_t)r * DINNER + d];
        float u  = u_[(size_t)r * DINNER + d];
        float du = dl * u;
        sumd += dl;
        const float* Brow = dbl + (size_t)r * DBLW + DTRANK;
#pragma unroll
        for (int n = 0; n < DSTATE; ++n) {
            float a = __expf(dl * A[n]);
            h[n] = fmaf(a, h[n], du * Brow[n]);
        }
    }
    size_t base = ((size_t)(c * BATCHN + b) * DSTATE) * DINNER + d;
#pragma unroll
    for (int n = 0; n < DSTATE; ++n) {
        P[base + (size_t)n * DINNER] = __expf(sumd * A[n]);
        Q[base + (size_t)n * DINNER] = h[n];
    }
}

template <int NC>
__global__ __launch_bounds__(256) void scan_mid(
    const float* __restrict__ P, float* __restrict__ Q)
{
    int tid = blockIdx.x * 256 + threadIdx.x;   // BATCHN*DSTATE*DINNER
    int d = tid % DINNER;
    int rem = tid / DINNER;
    int n = rem % DSTATE;
    int b = rem / DSTATE;
    float H = 0.f;
    for (int c = 0; c < NC; ++c) {
        size_t idx = ((size_t)((c * BATCHN + b) * DSTATE + n)) * DINNER + d;
        float p = P[idx], q = Q[idx];
        Q[idx] = H;          // state entering chunk c
        H = fmaf(p, H, q);
    }
}

template <int NC>
__global__ __launch_bounds__(256) void scan_pass2(
    const float* __restrict__ delta, const float* __restrict__ u_,
    const float* __restrict__ dbl, const float* __restrict__ A_log,
    const float* __restrict__ Hinit, const float* __restrict__ Dp,
    const float* __restrict__ z, int ldz,
    unsigned short* __restrict__ ymod_bf)
{
    constexpr int CL = SEQ / NC;
    int tid = blockIdx.x * 256 + threadIdx.x;
    int d = tid % DINNER;
    int t2 = tid / DINNER;
    int c = t2 % NC;
    int b = t2 / NC;
    float A[DSTATE], h[DSTATE];
    size_t base = ((size_t)(c * BATCHN + b) * DSTATE) * DINNER + d;
#pragma unroll
    for (int n = 0; n < DSTATE; ++n) {
        A[n] = -__expf(A_log[d * DSTATE + n]);
        h[n] = Hinit[base + (size_t)n * DINNER];
    }
    float Dd = Dp[d];
    int r0 = b * SEQ + c * CL;
#pragma unroll 2
    for (int t = 0; t < CL; ++t) {
        int r = r0 + t;
        float dl = delta[(size_t)r * DINNER + d];
        float u  = u_[(size_t)r * DINNER + d];
        float du = dl * u;
        const float* Brow = dbl + (size_t)r * DBLW + DTRANK;
        const float* Crow = Brow + DSTATE;
        float y = 0.f;
#pragma unroll
        for (int n = 0; n < DSTATE; ++n) {
            float a = __expf(dl * A[n]);
            h[n] = fmaf(a, h[n], du * Brow[n]);
            y = fmaf(h[n], Crow[n], y);
        }
        float zz = z[(size_t)r * ldz + d];
        float sig = 1.f / (1.f + __expf(-zz));
        ymod_bf[(size_t)r * DINNER + d] = f2bf((y + u * Dd) * (zz * sig));
    }
}

// ---------------- launch ----------------
extern "C" void kernel_launch(void* const* d_in, const int* in_sizes, int n_in,
                              void* d_out, int out_size, void* d_ws, size_t ws_size,
                              hipStream_t stream)
{
    (void)in_sizes; (void)n_in; (void)out_size;
    const float* x    = (const float*)d_in[0];
    const float* ln_g = (const float*)d_in[1];
    const float* ln_b = (const float*)d_in[2];
    const float* W_in[2]   = {(const float*)d_in[3],  (const float*)d_in[12]};
    const float* conv_w[2] = {(const float*)d_in[4],  (const float*)d_in[13]};
    const float* conv_b[2] = {(const float*)d_in[5],  (const float*)d_in[14]};
    const float* W_x[2]    = {(const float*)d_in[6],  (const float*)d_in[15]};
    const float* W_dt[2]   = {(const float*)d_in[7],  (const float*)d_in[16]};
    const float* b_dt[2]   = {(const float*)d_in[8],  (const float*)d_in[17]};
    const float* A_log[2]  = {(const float*)d_in[9],  (const float*)d_in[18]};
    const float* Dp[2]     = {(const float*)d_in[10], (const float*)d_in[19]};
    const float* W_out[2]  = {(const float*)d_in[11], (const float*)d_in[20]};
    const float* W_c = (const float*)d_in[21];
    const float* b_c = (const float*)d_in[22];
    float* out = (float*)d_out;

    float* ws = (float*)d_ws;
    float* xz    = ws; ws += (size_t)MROWS * 2 * DINNER;
    float* xc    = ws; ws += (size_t)MROWS * DINNER;
    float* dbl   = ws; ws += (size_t)MROWS * DBLW;
    float* delta = ws; ws += (size_t)MROWS * DINNER;
    float* part  = ws; ws += (size_t)XP_KSPLIT * MROWS * DBLW;

    // P/Q sized for up to NC=64; fall back to NC=32 if workspace is tight.
    size_t fixed_floats = (size_t)MROWS * 2 * DINNER + (size_t)MROWS * DINNER +
                          (size_t)MROWS * DBLW + (size_t)MROWS * DINNER +
                          (size_t)XP_KSPLIT * MROWS * DBLW;
    size_t shorts_cnt = (size_t)MROWS * DMODEL * 5 + (size_t)MROWS * DINNER +
                        (size_t)(2 * DINNER) * DMODEL + (size_t)DMODEL * DINNER +
                        (size_t)DMODEL * (2 * DMODEL);
    size_t pq64 = 2ULL * 64 * BATCHN * DSTATE * DINNER;
    bool big = ws_size >= (fixed_floats + pq64) * 4 + shorts_cnt * 2;
    size_t pq_floats = big ? pq64 : pq64 / 2;

    float* P = ws; ws += pq_floats / 2;
    float* Q = ws; ws += pq_floats / 2;
    unsigned short* us = (unsigned short*)ws;
    unsigned short* xn_bf   = us; us += (size_t)MROWS * DMODEL;
    unsigned short* xnr_bf  = us; us += (size_t)MROWS * DMODEL;
    unsigned short* ymod_bf = us; us += (size_t)MROWS * DINNER;
    unsigned short* outf_bf = us; us += (size_t)MROWS * DMODEL;
    unsigned short* outb_bf = us; us += (size_t)MROWS * DMODEL;
    unsigned short* wt_in   = us; us += (size_t)(2 * DINNER) * DMODEL;   // 3072 x 768
    unsigned short* wt_out  = us; us += (size_t)DMODEL * DINNER;         // 768 x 1536
    unsigned short* wt_c    = us; us += (size_t)DMODEL * (2 * DMODEL);   // 768 x 1536

    ln_kernel<<<MROWS, 256, 0, stream>>>(x, ln_g, ln_b, xn_bf, xnr_bf);
    // W_c is (2*DMODEL=1536) x DMODEL -> wt_c: DMODEL x 1536
    wt_transpose<<<dim3(DMODEL / 32, 2 * DMODEL / 32), 256, 0, stream>>>(
        W_c, wt_c, 2 * DMODEL, DMODEL);

    for (int dir = 0; dir < 2; ++dir) {
        // W_in: (768 x 3072) -> Wt 3072x768
        wt_transpose<<<dim3(2 * DINNER / 32, DMODEL / 32), 256, 0, stream>>>(
            W_in[dir], wt_in, DMODEL, 2 * DINNER);
        gemm_bf16<128, false, false, false><<<dim3(2 * DINNER / 128, MROWS / 128), 256, 0, stream>>>(
            dir ? xnr_bf : xn_bf, nullptr, DMODEL, DMODEL, wt_in, 2 * DINNER, nullptr, xz);

        conv_silu<<<(MROWS * DINNER) / 256, 256, 0, stream>>>(xz, 2 * DINNER,
                                                              conv_w[dir], conv_b[dir], xc);

        dim3 gx(MROWS / XP_BM, XP_KSPLIT);
        xproj_gemm<<<gx, 256, 0, stream>>>(xc, W_x[dir], part);
        xproj_reduce<<<(MROWS * DBLW) / 256, 256, 0, stream>>>(part, dbl);

        dt_gemm<<<dim3(DINNER / DT_BN, MROWS / DT_BM), 256, 0, stream>>>(
            dbl, W_dt[dir], b_dt[dir], delta);

        if (big) {
            scan_pass1<64><<<(BATCHN * 64 * DINNER) / 256, 256, 0, stream>>>(
                delta, xc, dbl, A_log[dir], P, Q);
            scan_mid<64><<<(BATCHN * DSTATE * DINNER) / 256, 256, 0, stream>>>(P, Q);
            scan_pass2<64><<<(BATCHN * 64 * DINNER) / 256, 256, 0, stream>>>(
                delta, xc, dbl, A_log[dir], Q, Dp[dir], xz + DINNER, 2 * DINNER, ymod_bf);
        } else {
            scan_pass1<32><<<(BATCHN * 32 * DINNER) / 256, 256, 0, stream>>>(
                delta, xc, dbl, A_log[dir], P, Q);
            scan_mid<32><<<(BATCHN * DSTATE * DINNER) / 256, 256, 0, stream>>>(P, Q);
            scan_pass2<32><<<(BATCHN * 32 * DINNER) / 256, 256, 0, stream>>>(
                delta, xc, dbl, A_log[dir], Q, Dp[dir], xz + DINNER, 2 * DINNER, ymod_bf);
        }

        // W_out: (1536 x 768) -> Wt 768x1536
        wt_transpose<<<dim3(DMODEL / 32, DINNER / 32), 256, 0, stream>>>(
            W_out[dir], wt_out, DINNER, DMODEL);
        if (dir == 0)
            gemm_bf16<64, false, false, true><<<dim3(DMODEL / 128, MROWS / 64), 256, 0, stream>>>(
                ymod_bf, nullptr, DINNER, DINNER, wt_out, DMODEL, nullptr, outf_bf);
        else
            gemm_bf16<64, true, false, true><<<dim3(DMODEL / 128, MROWS / 64), 256, 0, stream>>>(
                ymod_bf, nullptr, DINNER, DINNER, wt_out, DMODEL, nullptr, outb_bf);
    }

    gemm_bf16<64, false, true, false><<<dim3(DMODEL / 128, MROWS / 64), 256, 0, stream>>>(
        outf_bf, outb_bf, DMODEL, 2 * DMODEL, wt_c, DMODEL, b_c, out);
}

// Round 7
// 317.173 us; speedup vs baseline: 5.9754x; 1.1731x over previous
//
#include <hip/hip_runtime.h>
#include <math.h>

#define BATCHN 2
#define SEQ 1024
#define MROWS 2048      // BATCHN*SEQ
#define DMODEL 768
#define DINNER 1536
#define DSTATE 16
#define DCONV 4
#define DTRANK 48       // (768+15)//16
#define DBLW 80         // DTRANK + 2*DSTATE

typedef __bf16 bf16x8 __attribute__((ext_vector_type(8)));
typedef float  f32x4  __attribute__((ext_vector_type(4)));

__device__ __forceinline__ float silu_f(float x) { return x / (1.f + __expf(-x)); }
__device__ __forceinline__ float softplus_f(float x) {
    return fmaxf(x, 0.f) + log1pf(__expf(-fabsf(x)));
}
__device__ __forceinline__ unsigned short f2bf(float f) {
    unsigned int u = __float_as_uint(f);
    u += 0x7fffu + ((u >> 16) & 1u);          // round-to-nearest-even
    return (unsigned short)(u >> 16);
}
__device__ __forceinline__ float bf2f(unsigned short h) {
    return __uint_as_float(((unsigned int)h) << 16);
}
__device__ __forceinline__ void gload_lds16(const void* g, void* l) {
    __builtin_amdgcn_global_load_lds((const __attribute__((address_space(1))) void*)g,
                                     (__attribute__((address_space(3))) void*)l, 16, 0, 0);
}

// ---------------- LayerNorm -> bf16 (normal + seq-reversed copies) ----------------
__global__ __launch_bounds__(256) void ln_kernel(
    const float* __restrict__ x, const float* __restrict__ g,
    const float* __restrict__ b,
    unsigned short* __restrict__ xn_bf, unsigned short* __restrict__ xnr_bf)
{
    int row = blockIdx.x;
    const float* xr = x + (size_t)row * DMODEL;
    float v[3], s = 0.f, s2 = 0.f;
#pragma unroll
    for (int i = 0; i < 3; ++i) {
        v[i] = xr[threadIdx.x + i * 256];
        s += v[i]; s2 += v[i] * v[i];
    }
#pragma unroll
    for (int off = 32; off > 0; off >>= 1) {
        s  += __shfl_down(s, off);
        s2 += __shfl_down(s2, off);
    }
    __shared__ float red[2][4];
    int wid = threadIdx.x >> 6, lane = threadIdx.x & 63;
    if (lane == 0) { red[0][wid] = s; red[1][wid] = s2; }
    __syncthreads();
    if (threadIdx.x == 0) {
        float ts = 0.f, ts2 = 0.f;
        for (int w = 0; w < 4; ++w) { ts += red[0][w]; ts2 += red[1][w]; }
        red[0][0] = ts; red[1][0] = ts2;
    }
    __syncthreads();
    float mean = red[0][0] * (1.f / DMODEL);
    float var  = red[1][0] * (1.f / DMODEL) - mean * mean;
    float rstd = rsqrtf(var + 1e-5f);
    int rrow = row ^ (SEQ - 1);              // flip within batch
#pragma unroll
    for (int i = 0; i < 3; ++i) {
        int c = threadIdx.x + i * 256;
        unsigned short h = f2bf((v[i] - mean) * rstd * g[c] + b[c]);
        xn_bf [(size_t)row  * DMODEL + c] = h;
        xnr_bf[(size_t)rrow * DMODEL + c] = h;
    }
}

// ------- weight transpose + fp32->bf16: W[K][N] -> Wt[N][K], dir via grid.z -------
__global__ __launch_bounds__(256) void wt_transpose(
    const float* __restrict__ W0, const float* __restrict__ W1,
    unsigned short* __restrict__ Wt, int K, int N)
{
    const float* W = blockIdx.z ? W1 : W0;
    unsigned short* Wtz = Wt + (size_t)blockIdx.z * K * N;
    __shared__ float t[32][33];
    int n0 = blockIdx.x * 32, k0 = blockIdx.y * 32;
    int tx = threadIdx.x & 31, ty = threadIdx.x >> 5;
#pragma unroll
    for (int i = 0; i < 4; ++i)
        t[ty + i * 8][tx] = W[(size_t)(k0 + ty + i * 8) * N + n0 + tx];
    __syncthreads();
#pragma unroll
    for (int i = 0; i < 4; ++i)
        Wtz[(size_t)(n0 + ty + i * 8) * K + k0 + tx] = f2bf(t[tx][ty + i * 8]);
}

// ---------------- bf16 MFMA GEMM (dir via grid.z) ----------------
// Non-CONCAT: A = (z? A1 : A0) + z*aStr ; Bt += z*btStr ; C = z? C1 : C0 ; rev = z? revMask : 0.
// CONCAT (z==0): k<768 from A0 else A1 (both lda).
template <int BM, bool CONCAT, bool CBF16>
__global__ __launch_bounds__(256) void gemm_bf16(
    const unsigned short* __restrict__ A0, const unsigned short* __restrict__ A1,
    int lda, size_t aStr, int K,
    const unsigned short* __restrict__ Bt, size_t btStr, int N,
    const float* __restrict__ bias, void* __restrict__ C0, void* __restrict__ C1,
    int revMask)
{
    constexpr int MI = BM / 32;
    __shared__ unsigned short lsA[BM * 32];
    __shared__ unsigned short lsB[128 * 32];
    int z = blockIdx.z;
    const unsigned short* A = (z ? A1 : A0) + (size_t)z * aStr;
    const unsigned short* Bz = Bt + (size_t)z * btStr;
    void* Cv = z ? C1 : C0;
    int revm = z ? revMask : 0;

    int tid = threadIdx.x;
    int w = tid >> 6, lane = tid & 63;
    int wm = w >> 1, wn = w & 1;
    int bm = blockIdx.y * BM, bn = blockIdx.x * 128;
    int sr = lane >> 2, sc = (lane & 3) * 8;
    int l15 = lane & 15, kq = (lane >> 4) * 8;

    f32x4 acc[MI][4];
#pragma unroll
    for (int mi = 0; mi < MI; ++mi)
#pragma unroll
        for (int ni = 0; ni < 4; ++ni) acc[mi][ni] = (f32x4){0.f, 0.f, 0.f, 0.f};

    for (int kb = 0; kb < K; kb += 32) {
        const unsigned short* ap; int kc;
        if (CONCAT) {
            ap = (kb < DMODEL) ? A0 : A1;
            kc = (kb < DMODEL) ? kb : kb - DMODEL;
        } else { ap = A; kc = kb; }
#pragma unroll
        for (int r = 0; r < BM / 64; ++r) {
            const void* gp = ap + (size_t)(bm + r * 64 + w * 16 + sr) * lda + kc + sc;
            gload_lds16(gp, (void*)&lsA[(r * 64 + w * 16) * 32]);
        }
#pragma unroll
        for (int r = 0; r < 2; ++r) {
            const void* gp = Bz + (size_t)(bn + r * 64 + w * 16 + sr) * K + kb + sc;
            gload_lds16(gp, (void*)&lsB[(r * 64 + w * 16) * 32]);
        }
        __syncthreads();
        bf16x8 af[MI], bfr[4];
#pragma unroll
        for (int mi = 0; mi < MI; ++mi)
            af[mi] = *(const bf16x8*)&lsA[(wm * (BM / 2) + mi * 16 + l15) * 32 + kq];
#pragma unroll
        for (int ni = 0; ni < 4; ++ni)
            bfr[ni] = *(const bf16x8*)&lsB[(wn * 64 + ni * 16 + l15) * 32 + kq];
#pragma unroll
        for (int mi = 0; mi < MI; ++mi)
#pragma unroll
            for (int ni = 0; ni < 4; ++ni)
                acc[mi][ni] = __builtin_amdgcn_mfma_f32_16x16x32_bf16(
                    af[mi], bfr[ni], acc[mi][ni], 0, 0, 0);
        __syncthreads();
    }

    int r4 = (lane >> 4) * 4;
#pragma unroll
    for (int mi = 0; mi < MI; ++mi) {
#pragma unroll
        for (int ni = 0; ni < 4; ++ni) {
            int col = bn + wn * 64 + ni * 16 + l15;
            float bv = bias ? bias[col] : 0.f;
#pragma unroll
            for (int r = 0; r < 4; ++r) {
                int row = (bm + wm * (BM / 2) + mi * 16 + r4 + r) ^ revm;
                float val = acc[mi][ni][r] + bv;
                if (CBF16)
                    ((unsigned short*)Cv)[(size_t)row * N + col] = f2bf(val);
                else
                    ((float*)Cv)[(size_t)row * N + col] = val;
            }
        }
    }
}

// ------- Causal depthwise conv (K=4) + SiLU, bf16 in/out, both dirs, 4-wide -------
__global__ __launch_bounds__(256) void conv_silu(
    const unsigned short* __restrict__ xz,
    const float* __restrict__ w0, const float* __restrict__ w1,
    const float* __restrict__ cb0, const float* __restrict__ cb1,
    unsigned short* __restrict__ xc)
{
    int idx = blockIdx.x * 256 + threadIdx.x;       // over 2*MROWS*DINNER/4
    int d4 = (idx % (DINNER / 4)) * 4;
    int rem = idx / (DINNER / 4);
    int r = rem % MROWS;
    int dir = rem / MROWS;
    int s = r & (SEQ - 1);
    const float* w  = dir ? w1 : w0;
    const float* cb = dir ? cb1 : cb0;
    const unsigned short* xi = xz + (size_t)dir * MROWS * 2 * DINNER;
    float acc[4];
#pragma unroll
    for (int j = 0; j < 4; ++j) acc[j] = cb[d4 + j];
#pragma unroll
    for (int k = 0; k < DCONV; ++k) {
        int off = k - (DCONV - 1);
        if (s + off >= 0) {
            ushort4 v = *(const ushort4*)(xi + (size_t)(r + off) * (2 * DINNER) + d4);
            acc[0] = fmaf(bf2f(v.x), w[(d4 + 0) * DCONV + k], acc[0]);
            acc[1] = fmaf(bf2f(v.y), w[(d4 + 1) * DCONV + k], acc[1]);
            acc[2] = fmaf(bf2f(v.z), w[(d4 + 2) * DCONV + k], acc[2]);
            acc[3] = fmaf(bf2f(v.w), w[(d4 + 3) * DCONV + k], acc[3]);
        }
    }
    ushort4 o;
    o.x = f2bf(silu_f(acc[0])); o.y = f2bf(silu_f(acc[1]));
    o.z = f2bf(silu_f(acc[2])); o.w = f2bf(silu_f(acc[3]));
    *(ushort4*)(xc + (size_t)dir * MROWS * DINNER + (size_t)r * DINNER + d4) = o;
}

// ---------------- x-proj GEMM: 2048x80x1536, split-K, both dirs ----------------
#define XP_BM 32
#define XP_BK 32
#define XP_KSPLIT 4
#define XP_KCH (DINNER / XP_KSPLIT)   // 384

__global__ __launch_bounds__(256) void xproj_gemm(
    const unsigned short* __restrict__ xc,
    const float* __restrict__ Wx0, const float* __restrict__ Wx1,
    float* __restrict__ part)      // [dir][KSPLIT][2048][80]
{
    __shared__ float As[XP_BK][XP_BM + 1];
    __shared__ float Bs[XP_BK][DBLW + 1];
    int dir = blockIdx.z;
    const unsigned short* A = xc + (size_t)dir * MROWS * DINNER;
    const float* B = dir ? Wx1 : Wx0;
    int tid = threadIdx.x;
    int bm = blockIdx.x * XP_BM;
    int k0 = blockIdx.y * XP_KCH;
    int tm = (tid >> 4) * 2;
    int tn = (tid & 15) * 5;
    float acc[2][5];
#pragma unroll
    for (int i = 0; i < 2; ++i)
#pragma unroll
        for (int j = 0; j < 5; ++j) acc[i][j] = 0.f;

    int ar = tid >> 3;
    int ac = (tid & 7) * 4;

    for (int kb = 0; kb < XP_KCH; kb += XP_BK) {
        ushort4 va = *(const ushort4*)(A + (size_t)(bm + ar) * DINNER + k0 + kb + ac);
        As[ac + 0][ar] = bf2f(va.x); As[ac + 1][ar] = bf2f(va.y);
        As[ac + 2][ar] = bf2f(va.z); As[ac + 3][ar] = bf2f(va.w);
#pragma unroll
        for (int i = 0; i < 10; ++i) {
            int li = tid + i * 256;
            int kk = li / DBLW, nn = li - kk * DBLW;
            Bs[kk][nn] = B[(size_t)(k0 + kb + kk) * DBLW + nn];
        }
        __syncthreads();
#pragma unroll
        for (int k = 0; k < XP_BK; ++k) {
            float a0 = As[k][tm], a1 = As[k][tm + 1];
            float b0 = Bs[k][tn + 0], b1 = Bs[k][tn + 1], b2 = Bs[k][tn + 2];
            float b3 = Bs[k][tn + 3], b4 = Bs[k][tn + 4];
            acc[0][0] = fmaf(a0, b0, acc[0][0]); acc[0][1] = fmaf(a0, b1, acc[0][1]);
            acc[0][2] = fmaf(a0, b2, acc[0][2]); acc[0][3] = fmaf(a0, b3, acc[0][3]);
            acc[0][4] = fmaf(a0, b4, acc[0][4]);
            acc[1][0] = fmaf(a1, b0, acc[1][0]); acc[1][1] = fmaf(a1, b1, acc[1][1]);
            acc[1][2] = fmaf(a1, b2, acc[1][2]); acc[1][3] = fmaf(a1, b3, acc[1][3]);
            acc[1][4] = fmaf(a1, b4, acc[1][4]);
        }
        __syncthreads();
    }
    size_t base = ((size_t)dir * XP_KSPLIT + blockIdx.y) * MROWS * DBLW + (size_t)bm * DBLW;
#pragma unroll
    for (int i = 0; i < 2; ++i)
#pragma unroll
        for (int j = 0; j < 5; ++j)
            part[base + (size_t)(tm + i) * DBLW + tn + j] = acc[i][j];
}

__global__ __launch_bounds__(256) void xproj_reduce(
    const float* __restrict__ part, float* __restrict__ dbl)
{
    int idx = blockIdx.x * 256 + threadIdx.x;       // over 2*MROWS*DBLW
    int dir = idx / (MROWS * DBLW);
    int rem = idx % (MROWS * DBLW);
    float s = 0.f;
#pragma unroll
    for (int ks = 0; ks < XP_KSPLIT; ++ks)
        s += part[((size_t)dir * XP_KSPLIT + ks) * MROWS * DBLW + rem];
    dbl[idx] = s;
}

// -------- Selective scan, chunked, dt-fused, both dirs. grid(NC, 6, 4) --------
template <int NC>
__global__ __launch_bounds__(256) void scan_pass1(
    const unsigned short* __restrict__ xc, const float* __restrict__ dbl,
    const float* __restrict__ Wdt0, const float* __restrict__ Wdt1,
    const float* __restrict__ bdt0, const float* __restrict__ bdt1,
    const float* __restrict__ Alog0, const float* __restrict__ Alog1,
    float* __restrict__ sumdO, float* __restrict__ Q)
{
    constexpr int CL = SEQ / NC;
    __shared__ float sdbl[CL][DBLW];
    int c = blockIdx.x;
    int d = blockIdx.y * 256 + threadIdx.x;
    int b = blockIdx.z & 1, dir = blockIdx.z >> 1;
    const float* Wdt  = dir ? Wdt1 : Wdt0;
    const float* Alog = dir ? Alog1 : Alog0;
    const unsigned short* u_ = xc + (size_t)dir * MROWS * DINNER;
    const float* dblz = dbl + (size_t)dir * MROWS * DBLW;
    int r0 = b * SEQ + c * CL;
    for (int i = threadIdx.x; i < CL * DBLW; i += 256)
        sdbl[i / DBLW][i % DBLW] = dblz[(size_t)(r0 + i / DBLW) * DBLW + i % DBLW];
    float wcol[DTRANK];
#pragma unroll
    for (int k = 0; k < DTRANK; ++k) wcol[k] = Wdt[(size_t)k * DINNER + d];
    float bd = (dir ? bdt1 : bdt0)[d];
    float A[DSTATE], h[DSTATE];
#pragma unroll
    for (int n = 0; n < DSTATE; ++n) { A[n] = -__expf(Alog[d * DSTATE + n]); h[n] = 0.f; }
    __syncthreads();
    float sd = 0.f;
    for (int t = 0; t < CL; ++t) {
        float acc = bd;
#pragma unroll
        for (int k = 0; k < DTRANK; ++k) acc = fmaf(sdbl[t][k], wcol[k], acc);
        float dl = softplus_f(acc);
        float u = bf2f(u_[(size_t)(r0 + t) * DINNER + d]);
        float du = dl * u;
        sd += dl;
#pragma unroll
        for (int n = 0; n < DSTATE; ++n) {
            float a = __expf(dl * A[n]);
            h[n] = fmaf(a, h[n], du * sdbl[t][DTRANK + n]);
        }
    }
    size_t sOff = (size_t)dir * NC * BATCHN * DINNER + (size_t)(c * BATCHN + b) * DINNER + d;
    sumdO[sOff] = sd;
    size_t qB = (size_t)dir * NC * BATCHN * DSTATE * DINNER +
                ((size_t)(c * BATCHN + b) * DSTATE) * DINNER + d;
#pragma unroll
    for (int n = 0; n < DSTATE; ++n) Q[qB + (size_t)n * DINNER] = h[n];
}

template <int NC>
__global__ __launch_bounds__(256) void scan_mid(
    const float* __restrict__ sumd, float* __restrict__ Q,
    const float* __restrict__ Alog0, const float* __restrict__ Alog1)
{
    int idx = blockIdx.x * 256 + threadIdx.x;   // 2*2*16*1536
    int d = idx % DINNER;
    int n = (idx / DINNER) % DSTATE;
    int b = (idx / (DINNER * DSTATE)) % BATCHN;
    int dir = idx / (DINNER * DSTATE * BATCHN);
    float A = -__expf((dir ? Alog1 : Alog0)[d * DSTATE + n]);
    size_t sBase = (size_t)dir * NC * BATCHN * DINNER;
    size_t qBase = (size_t)dir * NC * BATCHN * DSTATE * DINNER;
    float H = 0.f;
    for (int c = 0; c < NC; ++c) {
        size_t si = sBase + (size_t)(c * BATCHN + b) * DINNER + d;
        size_t qi = qBase + ((size_t)(c * BATCHN + b) * DSTATE + n) * DINNER + d;
        float p = __expf(sumd[si] * A);
        float q = Q[qi];
        Q[qi] = H;              // state entering chunk c
        H = fmaf(p, H, q);
    }
}

template <int NC>
__global__ __launch_bounds__(256) void scan_pass2(
    const unsigned short* __restrict__ xc, const float* __restrict__ dbl,
    const unsigned short* __restrict__ xz,
    const float* __restrict__ Wdt0, const float* __restrict__ Wdt1,
    const float* __restrict__ bdt0, const float* __restrict__ bdt1,
    const float* __restrict__ Alog0, const float* __restrict__ Alog1,
    const float* __restrict__ Dp0, const float* __restrict__ Dp1,
    const float* __restrict__ Q,
    unsigned short* __restrict__ ymod)
{
    constexpr int CL = SEQ / NC;
    __shared__ float sdbl[CL][DBLW];
    int c = blockIdx.x;
    int d = blockIdx.y * 256 + threadIdx.x;
    int b = blockIdx.z & 1, dir = blockIdx.z >> 1;
    const float* Wdt  = dir ? Wdt1 : Wdt0;
    const float* Alog = dir ? Alog1 : Alog0;
    const unsigned short* u_ = xc + (size_t)dir * MROWS * DINNER;
    const unsigned short* z_ = xz + (size_t)dir * MROWS * 2 * DINNER;
    const float* dblz = dbl + (size_t)dir * MROWS * DBLW;
    int r0 = b * SEQ + c * CL;
    for (int i = threadIdx.x; i < CL * DBLW; i += 256)
        sdbl[i / DBLW][i % DBLW] = dblz[(size_t)(r0 + i / DBLW) * DBLW + i % DBLW];
    float wcol[DTRANK];
#pragma unroll
    for (int k = 0; k < DTRANK; ++k) wcol[k] = Wdt[(size_t)k * DINNER + d];
    float bd = (dir ? bdt1 : bdt0)[d];
    float Dd = (dir ? Dp1 : Dp0)[d];
    float A[DSTATE], h[DSTATE];
    size_t qB = (size_t)dir * NC * BATCHN * DSTATE * DINNER +
                ((size_t)(c * BATCHN + b) * DSTATE) * DINNER + d;
#pragma unroll
    for (int n = 0; n < DSTATE; ++n) {
        A[n] = -__expf(Alog[d * DSTATE + n]);
        h[n] = Q[qB + (size_t)n * DINNER];
    }
    __syncthreads();
    unsigned short* yo = ymod + (size_t)dir * MROWS * DINNER;
    for (int t = 0; t < CL; ++t) {
        float acc = bd;
#pragma unroll
        for (int k = 0; k < DTRANK; ++k) acc = fmaf(sdbl[t][k], wcol[k], acc);
        float dl = softplus_f(acc);
        float u = bf2f(u_[(size_t)(r0 + t) * DINNER + d]);
        float du = dl * u;
        float y = 0.f;
#pragma unroll
        for (int n = 0; n < DSTATE; ++n) {
            float a = __expf(dl * A[n]);
            h[n] = fmaf(a, h[n], du * sdbl[t][DTRANK + n]);
            y = fmaf(h[n], sdbl[t][DTRANK + DSTATE + n], y);
        }
        float zz = bf2f(z_[(size_t)(r0 + t) * (2 * DINNER) + DINNER + d]);
        float sig = 1.f / (1.f + __expf(-zz));
        yo[(size_t)(r0 + t) * DINNER + d] = f2bf((y + u * Dd) * (zz * sig));
    }
}

// ---------------- launch ----------------
extern "C" void kernel_launch(void* const* d_in, const int* in_sizes, int n_in,
                              void* d_out, int out_size, void* d_ws, size_t ws_size,
                              hipStream_t stream)
{
    (void)in_sizes; (void)n_in; (void)out_size;
    const float* x    = (const float*)d_in[0];
    const float* ln_g = (const float*)d_in[1];
    const float* ln_b = (const float*)d_in[2];
    const float* W_in[2]   = {(const float*)d_in[3],  (const float*)d_in[12]};
    const float* conv_w[2] = {(const float*)d_in[4],  (const float*)d_in[13]};
    const float* conv_b[2] = {(const float*)d_in[5],  (const float*)d_in[14]};
    const float* W_x[2]    = {(const float*)d_in[6],  (const float*)d_in[15]};
    const float* W_dt[2]   = {(const float*)d_in[7],  (const float*)d_in[16]};
    const float* b_dt[2]   = {(const float*)d_in[8],  (const float*)d_in[17]};
    const float* A_log[2]  = {(const float*)d_in[9],  (const float*)d_in[18]};
    const float* Dp[2]     = {(const float*)d_in[10], (const float*)d_in[19]};
    const float* W_out[2]  = {(const float*)d_in[11], (const float*)d_in[20]};
    const float* W_c = (const float*)d_in[21];
    const float* b_c = (const float*)d_in[22];
    float* out = (float*)d_out;

    // ---- workspace ----
    float* fp = (float*)d_ws;
    float* dbl  = fp; fp += (size_t)2 * MROWS * DBLW;
    float* part = fp; fp += (size_t)2 * XP_KSPLIT * MROWS * DBLW;

    size_t fbase = (size_t)2 * MROWS * DBLW + (size_t)2 * XP_KSPLIT * MROWS * DBLW;
    size_t shortsTot = (size_t)2 * MROWS * 2 * DINNER   // xz
                     + (size_t)2 * MROWS * DINNER       // xc
                     + (size_t)2 * MROWS * DMODEL       // xn + xnr
                     + (size_t)2 * MROWS * DINNER       // ymod
                     + (size_t)2 * MROWS * DMODEL       // outf + outb
                     + (size_t)2 * 2 * DINNER * DMODEL  // wt_in
                     + (size_t)2 * DMODEL * DINNER      // wt_out
                     + (size_t)DMODEL * 2 * DMODEL;     // wt_c
    size_t perNC = (size_t)BATCHN * 2 * DINNER * (1 + DSTATE);  // sumd + Q floats per chunk
    bool big = ws_size >= (fbase + 64 * perNC) * 4 + shortsTot * 2;
    int NC = big ? 64 : 32;

    float* sumd = fp; fp += (size_t)NC * BATCHN * 2 * DINNER;
    float* Q    = fp; fp += (size_t)NC * BATCHN * 2 * DSTATE * DINNER;
    unsigned short* us = (unsigned short*)fp;
    unsigned short* xz_bf   = us; us += (size_t)2 * MROWS * 2 * DINNER;
    unsigned short* xc_bf   = us; us += (size_t)2 * MROWS * DINNER;
    unsigned short* xn_bf   = us; us += (size_t)MROWS * DMODEL;
    unsigned short* xnr_bf  = us; us += (size_t)MROWS * DMODEL;
    unsigned short* ymod_bf = us; us += (size_t)2 * MROWS * DINNER;
    unsigned short* outf_bf = us; us += (size_t)MROWS * DMODEL;
    unsigned short* outb_bf = us; us += (size_t)MROWS * DMODEL;
    unsigned short* wt_in   = us; us += (size_t)2 * (2 * DINNER) * DMODEL;
    unsigned short* wt_out  = us; us += (size_t)2 * DMODEL * DINNER;
    unsigned short* wt_c    = us; us += (size_t)DMODEL * (2 * DMODEL);

    // 1. LN
    ln_kernel<<<MROWS, 256, 0, stream>>>(x, ln_g, ln_b, xn_bf, xnr_bf);
    // 2-3. weight transposes
    wt_transpose<<<dim3(DMODEL / 32, 2 * DMODEL / 32, 1), 256, 0, stream>>>(
        W_c, W_c, wt_c, 2 * DMODEL, DMODEL);
    wt_transpose<<<dim3(2 * DINNER / 32, DMODEL / 32, 2), 256, 0, stream>>>(
        W_in[0], W_in[1], wt_in, DMODEL, 2 * DINNER);
    // 4. W_in GEMM both dirs -> xz bf16
    gemm_bf16<128, false, true><<<dim3(2 * DINNER / 128, MROWS / 128, 2), 256, 0, stream>>>(
        xn_bf, xnr_bf, DMODEL, 0, DMODEL,
        wt_in, (size_t)(2 * DINNER) * DMODEL, 2 * DINNER,
        nullptr, xz_bf, xz_bf + (size_t)MROWS * 2 * DINNER, 0);
    // 5. conv+silu both dirs
    conv_silu<<<(2 * MROWS * DINNER / 4) / 256, 256, 0, stream>>>(
        xz_bf, conv_w[0], conv_w[1], conv_b[0], conv_b[1], xc_bf);
    // 6-7. x-proj both dirs
    xproj_gemm<<<dim3(MROWS / XP_BM, XP_KSPLIT, 2), 256, 0, stream>>>(
        xc_bf, W_x[0], W_x[1], part);
    xproj_reduce<<<(2 * MROWS * DBLW) / 256, 256, 0, stream>>>(part, dbl);
    // 8-10. scan
    if (big) {
        scan_pass1<64><<<dim3(64, DINNER / 256, BATCHN * 2), 256, 0, stream>>>(
            xc_bf, dbl, W_dt[0], W_dt[1], b_dt[0], b_dt[1], A_log[0], A_log[1], sumd, Q);
        scan_mid<64><<<(2 * BATCHN * DSTATE * DINNER) / 256, 256, 0, stream>>>(
            sumd, Q, A_log[0], A_log[1]);
        scan_pass2<64><<<dim3(64, DINNER / 256, BATCHN * 2), 256, 0, stream>>>(
            xc_bf, dbl, xz_bf, W_dt[0], W_dt[1], b_dt[0], b_dt[1],
            A_log[0], A_log[1], Dp[0], Dp[1], Q, ymod_bf);
    } else {
        scan_pass1<32><<<dim3(32, DINNER / 256, BATCHN * 2), 256, 0, stream>>>(
            xc_bf, dbl, W_dt[0], W_dt[1], b_dt[0], b_dt[1], A_log[0], A_log[1], sumd, Q);
        scan_mid<32><<<(2 * BATCHN * DSTATE * DINNER) / 256, 256, 0, stream>>>(
            sumd, Q, A_log[0], A_log[1]);
        scan_pass2<32><<<dim3(32, DINNER / 256, BATCHN * 2), 256, 0, stream>>>(
            xc_bf, dbl, xz_bf, W_dt[0], W_dt[1], b_dt[0], b_dt[1],
            A_log[0], A_log[1], Dp[0], Dp[1], Q, ymod_bf);
    }
    // 11-12. W_out GEMM both dirs (bwd writes seq-reversed)
    wt_transpose<<<dim3(DMODEL / 32, DINNER / 32, 2), 256, 0, stream>>>(
        W_out[0], W_out[1], wt_out, DINNER, DMODEL);
    gemm_bf16<64, false, true><<<dim3(DMODEL / 128, MROWS / 64, 2), 256, 0, stream>>>(
        ymod_bf, ymod_bf, DINNER, (size_t)MROWS * DINNER, DINNER,
        wt_out, (size_t)DMODEL * DINNER, DMODEL,
        nullptr, outf_bf, outb_bf, SEQ - 1);
    // 13. final concat GEMM
    gemm_bf16<64, true, false><<<dim3(DMODEL / 128, MROWS / 64, 1), 256, 0, stream>>>(
        outf_bf, outb_bf, DMODEL, 0, 2 * DMODEL,
        wt_c, 0, DMODEL,
        b_c, out, nullptr, 0);
}

// Round 8
// 293.951 us; speedup vs baseline: 6.4474x; 1.0790x over previous
//
#include <hip/hip_runtime.h>
#include <math.h>

#define BATCHN 2
#define SEQ 1024
#define MROWS 2048      // BATCHN*SEQ
#define DMODEL 768
#define DINNER 1536
#define DSTATE 16
#define DCONV 4
#define DTRANK 48       // (768+15)//16
#define DBLW 80         // DTRANK + 2*DSTATE

typedef __bf16 bf16x8 __attribute__((ext_vector_type(8)));
typedef float  f32x4  __attribute__((ext_vector_type(4)));

__device__ __forceinline__ float silu_f(float x) { return x / (1.f + __expf(-x)); }
__device__ __forceinline__ float softplus_f(float x) {
    return fmaxf(x, 0.f) + log1pf(__expf(-fabsf(x)));
}
__device__ __forceinline__ unsigned short f2bf(float f) {
    unsigned int u = __float_as_uint(f);
    u += 0x7fffu + ((u >> 16) & 1u);          // round-to-nearest-even
    return (unsigned short)(u >> 16);
}
__device__ __forceinline__ float bf2f(unsigned short h) {
    return __uint_as_float(((unsigned int)h) << 16);
}
__device__ __forceinline__ void gload_lds16(const void* g, void* l) {
    __builtin_amdgcn_global_load_lds((const __attribute__((address_space(1))) void*)g,
                                     (__attribute__((address_space(3))) void*)l, 16, 0, 0);
}

// ---------------- LayerNorm -> bf16 (normal + seq-reversed copies) ----------------
__global__ __launch_bounds__(256) void ln_kernel(
    const float* __restrict__ x, const float* __restrict__ g,
    const float* __restrict__ b,
    unsigned short* __restrict__ xn_bf, unsigned short* __restrict__ xnr_bf)
{
    int row = blockIdx.x;
    const float* xr = x + (size_t)row * DMODEL;
    float v[3], s = 0.f, s2 = 0.f;
#pragma unroll
    for (int i = 0; i < 3; ++i) {
        v[i] = xr[threadIdx.x + i * 256];
        s += v[i]; s2 += v[i] * v[i];
    }
#pragma unroll
    for (int off = 32; off > 0; off >>= 1) {
        s  += __shfl_down(s, off);
        s2 += __shfl_down(s2, off);
    }
    __shared__ float red[2][4];
    int wid = threadIdx.x >> 6, lane = threadIdx.x & 63;
    if (lane == 0) { red[0][wid] = s; red[1][wid] = s2; }
    __syncthreads();
    if (threadIdx.x == 0) {
        float ts = 0.f, ts2 = 0.f;
        for (int w = 0; w < 4; ++w) { ts += red[0][w]; ts2 += red[1][w]; }
        red[0][0] = ts; red[1][0] = ts2;
    }
    __syncthreads();
    float mean = red[0][0] * (1.f / DMODEL);
    float var  = red[1][0] * (1.f / DMODEL) - mean * mean;
    float rstd = rsqrtf(var + 1e-5f);
    int rrow = row ^ (SEQ - 1);              // flip within batch
#pragma unroll
    for (int i = 0; i < 3; ++i) {
        int c = threadIdx.x + i * 256;
        unsigned short h = f2bf((v[i] - mean) * rstd * g[c] + b[c]);
        xn_bf [(size_t)row  * DMODEL + c] = h;
        xnr_bf[(size_t)rrow * DMODEL + c] = h;
    }
}

// ------- weight transpose + fp32->bf16: W[K][N] -> Wt[N][K], dir via grid.z -------
__global__ __launch_bounds__(256) void wt_transpose(
    const float* __restrict__ W0, const float* __restrict__ W1,
    unsigned short* __restrict__ Wt, int K, int N)
{
    const float* W = blockIdx.z ? W1 : W0;
    unsigned short* Wtz = Wt + (size_t)blockIdx.z * K * N;
    __shared__ float t[32][33];
    int n0 = blockIdx.x * 32, k0 = blockIdx.y * 32;
    int tx = threadIdx.x & 31, ty = threadIdx.x >> 5;
#pragma unroll
    for (int i = 0; i < 4; ++i)
        t[ty + i * 8][tx] = W[(size_t)(k0 + ty + i * 8) * N + n0 + tx];
    __syncthreads();
#pragma unroll
    for (int i = 0; i < 4; ++i)
        Wtz[(size_t)(n0 + ty + i * 8) * K + k0 + tx] = f2bf(t[tx][ty + i * 8]);
}

// ---------------- bf16 MFMA GEMM (dir via grid.z) ----------------
template <int BM, bool CONCAT, bool CBF16>
__global__ __launch_bounds__(256) void gemm_bf16(
    const unsigned short* __restrict__ A0, const unsigned short* __restrict__ A1,
    int lda, size_t aStr, int K,
    const unsigned short* __restrict__ Bt, size_t btStr, int N,
    const float* __restrict__ bias, void* __restrict__ C0, void* __restrict__ C1,
    int revMask)
{
    constexpr int MI = BM / 32;
    __shared__ unsigned short lsA[BM * 32];
    __shared__ unsigned short lsB[128 * 32];
    int z = blockIdx.z;
    const unsigned short* A = (z ? A1 : A0) + (size_t)z * aStr;
    const unsigned short* Bz = Bt + (size_t)z * btStr;
    void* Cv = z ? C1 : C0;
    int revm = z ? revMask : 0;

    int tid = threadIdx.x;
    int w = tid >> 6, lane = tid & 63;
    int wm = w >> 1, wn = w & 1;
    int bm = blockIdx.y * BM, bn = blockIdx.x * 128;
    int sr = lane >> 2, sc = (lane & 3) * 8;
    int l15 = lane & 15, kq = (lane >> 4) * 8;

    f32x4 acc[MI][4];
#pragma unroll
    for (int mi = 0; mi < MI; ++mi)
#pragma unroll
        for (int ni = 0; ni < 4; ++ni) acc[mi][ni] = (f32x4){0.f, 0.f, 0.f, 0.f};

    for (int kb = 0; kb < K; kb += 32) {
        const unsigned short* ap; int kc;
        if (CONCAT) {
            ap = (kb < DMODEL) ? A0 : A1;
            kc = (kb < DMODEL) ? kb : kb - DMODEL;
        } else { ap = A; kc = kb; }
#pragma unroll
        for (int r = 0; r < BM / 64; ++r) {
            const void* gp = ap + (size_t)(bm + r * 64 + w * 16 + sr) * lda + kc + sc;
            gload_lds16(gp, (void*)&lsA[(r * 64 + w * 16) * 32]);
        }
#pragma unroll
        for (int r = 0; r < 2; ++r) {
            const void* gp = Bz + (size_t)(bn + r * 64 + w * 16 + sr) * K + kb + sc;
            gload_lds16(gp, (void*)&lsB[(r * 64 + w * 16) * 32]);
        }
        __syncthreads();
        bf16x8 af[MI], bfr[4];
#pragma unroll
        for (int mi = 0; mi < MI; ++mi)
            af[mi] = *(const bf16x8*)&lsA[(wm * (BM / 2) + mi * 16 + l15) * 32 + kq];
#pragma unroll
        for (int ni = 0; ni < 4; ++ni)
            bfr[ni] = *(const bf16x8*)&lsB[(wn * 64 + ni * 16 + l15) * 32 + kq];
#pragma unroll
        for (int mi = 0; mi < MI; ++mi)
#pragma unroll
            for (int ni = 0; ni < 4; ++ni)
                acc[mi][ni] = __builtin_amdgcn_mfma_f32_16x16x32_bf16(
                    af[mi], bfr[ni], acc[mi][ni], 0, 0, 0);
        __syncthreads();
    }

    int r4 = (lane >> 4) * 4;
#pragma unroll
    for (int mi = 0; mi < MI; ++mi) {
#pragma unroll
        for (int ni = 0; ni < 4; ++ni) {
            int col = bn + wn * 64 + ni * 16 + l15;
            float bv = bias ? bias[col] : 0.f;
#pragma unroll
            for (int r = 0; r < 4; ++r) {
                int row = (bm + wm * (BM / 2) + mi * 16 + r4 + r) ^ revm;
                float val = acc[mi][ni][r] + bv;
                if (CBF16)
                    ((unsigned short*)Cv)[(size_t)row * N + col] = f2bf(val);
                else
                    ((float*)Cv)[(size_t)row * N + col] = val;
            }
        }
    }
}

// ------- Causal depthwise conv (K=4) + SiLU, bf16 in/out, both dirs, 4-wide -------
__global__ __launch_bounds__(256) void conv_silu(
    const unsigned short* __restrict__ xz,
    const float* __restrict__ w0, const float* __restrict__ w1,
    const float* __restrict__ cb0, const float* __restrict__ cb1,
    unsigned short* __restrict__ xc)
{
    int idx = blockIdx.x * 256 + threadIdx.x;       // over 2*MROWS*DINNER/4
    int d4 = (idx % (DINNER / 4)) * 4;
    int rem = idx / (DINNER / 4);
    int r = rem % MROWS;
    int dir = rem / MROWS;
    int s = r & (SEQ - 1);
    const float* w  = dir ? w1 : w0;
    const float* cb = dir ? cb1 : cb0;
    const unsigned short* xi = xz + (size_t)dir * MROWS * 2 * DINNER;
    float acc[4];
#pragma unroll
    for (int j = 0; j < 4; ++j) acc[j] = cb[d4 + j];
#pragma unroll
    for (int k = 0; k < DCONV; ++k) {
        int off = k - (DCONV - 1);
        if (s + off >= 0) {
            ushort4 v = *(const ushort4*)(xi + (size_t)(r + off) * (2 * DINNER) + d4);
            acc[0] = fmaf(bf2f(v.x), w[(d4 + 0) * DCONV + k], acc[0]);
            acc[1] = fmaf(bf2f(v.y), w[(d4 + 1) * DCONV + k], acc[1]);
            acc[2] = fmaf(bf2f(v.z), w[(d4 + 2) * DCONV + k], acc[2]);
            acc[3] = fmaf(bf2f(v.w), w[(d4 + 3) * DCONV + k], acc[3]);
        }
    }
    ushort4 o;
    o.x = f2bf(silu_f(acc[0])); o.y = f2bf(silu_f(acc[1]));
    o.z = f2bf(silu_f(acc[2])); o.w = f2bf(silu_f(acc[3]));
    *(ushort4*)(xc + (size_t)dir * MROWS * DINNER + (size_t)r * DINNER + d4) = o;
}

// ---------------- x-proj GEMM: 2048x80x1536, split-K, both dirs ----------------
#define XP_BM 32
#define XP_BK 32
#define XP_KSPLIT 4
#define XP_KCH (DINNER / XP_KSPLIT)   // 384

__global__ __launch_bounds__(256) void xproj_gemm(
    const unsigned short* __restrict__ xc,
    const float* __restrict__ Wx0, const float* __restrict__ Wx1,
    float* __restrict__ part)      // [dir][KSPLIT][2048][80]
{
    __shared__ float As[XP_BK][XP_BM + 1];
    __shared__ float Bs[XP_BK][DBLW + 1];
    int dir = blockIdx.z;
    const unsigned short* A = xc + (size_t)dir * MROWS * DINNER;
    const float* B = dir ? Wx1 : Wx0;
    int tid = threadIdx.x;
    int bm = blockIdx.x * XP_BM;
    int k0 = blockIdx.y * XP_KCH;
    int tm = (tid >> 4) * 2;
    int tn = (tid & 15) * 5;
    float acc[2][5];
#pragma unroll
    for (int i = 0; i < 2; ++i)
#pragma unroll
        for (int j = 0; j < 5; ++j) acc[i][j] = 0.f;

    int ar = tid >> 3;
    int ac = (tid & 7) * 4;

    for (int kb = 0; kb < XP_KCH; kb += XP_BK) {
        ushort4 va = *(const ushort4*)(A + (size_t)(bm + ar) * DINNER + k0 + kb + ac);
        As[ac + 0][ar] = bf2f(va.x); As[ac + 1][ar] = bf2f(va.y);
        As[ac + 2][ar] = bf2f(va.z); As[ac + 3][ar] = bf2f(va.w);
#pragma unroll
        for (int i = 0; i < 10; ++i) {
            int li = tid + i * 256;
            int kk = li / DBLW, nn = li - kk * DBLW;
            Bs[kk][nn] = B[(size_t)(k0 + kb + kk) * DBLW + nn];
        }
        __syncthreads();
#pragma unroll
        for (int k = 0; k < XP_BK; ++k) {
            float a0 = As[k][tm], a1 = As[k][tm + 1];
            float b0 = Bs[k][tn + 0], b1 = Bs[k][tn + 1], b2 = Bs[k][tn + 2];
            float b3 = Bs[k][tn + 3], b4 = Bs[k][tn + 4];
            acc[0][0] = fmaf(a0, b0, acc[0][0]); acc[0][1] = fmaf(a0, b1, acc[0][1]);
            acc[0][2] = fmaf(a0, b2, acc[0][2]); acc[0][3] = fmaf(a0, b3, acc[0][3]);
            acc[0][4] = fmaf(a0, b4, acc[0][4]);
            acc[1][0] = fmaf(a1, b0, acc[1][0]); acc[1][1] = fmaf(a1, b1, acc[1][1]);
            acc[1][2] = fmaf(a1, b2, acc[1][2]); acc[1][3] = fmaf(a1, b3, acc[1][3]);
            acc[1][4] = fmaf(a1, b4, acc[1][4]);
        }
        __syncthreads();
    }
    size_t base = ((size_t)dir * XP_KSPLIT + blockIdx.y) * MROWS * DBLW + (size_t)bm * DBLW;
#pragma unroll
    for (int i = 0; i < 2; ++i)
#pragma unroll
        for (int j = 0; j < 5; ++j)
            part[base + (size_t)(tm + i) * DBLW + tn + j] = acc[i][j];
}

__global__ __launch_bounds__(256) void xproj_reduce(
    const float* __restrict__ part, float* __restrict__ dbl)
{
    int idx = blockIdx.x * 256 + threadIdx.x;       // over 2*MROWS*DBLW
    int dir = idx / (MROWS * DBLW);
    int rem = idx % (MROWS * DBLW);
    float s = 0.f;
#pragma unroll
    for (int ks = 0; ks < XP_KSPLIT; ++ks)
        s += part[((size_t)dir * XP_KSPLIT + ks) * MROWS * DBLW + rem];
    dbl[idx] = s;
}

// -------- delta GEMM: [dir] 2048 x 1536, K=48, + softplus; fp32 or bf16 out --------
#define DT_BM 64
#define DT_BN 128
template <bool OBF16>
__global__ __launch_bounds__(256) void dt_gemm(
    const float* __restrict__ dbl_, const float* __restrict__ Wdt0,
    const float* __restrict__ Wdt1, const float* __restrict__ bdt0,
    const float* __restrict__ bdt1, void* __restrict__ deltaO)
{
    int dir = blockIdx.z;
    const float* Ad  = dbl_ + (size_t)dir * MROWS * DBLW;
    const float* Wdt = dir ? Wdt1 : Wdt0;
    const float* bdt = dir ? bdt1 : bdt0;
    __shared__ float As[DTRANK][DT_BM + 1];   // 48 x 65
    __shared__ float Bs[DTRANK][DT_BN + 4];   // 48 x 132
    int tid = threadIdx.x;
    int bm = blockIdx.y * DT_BM, bn = blockIdx.x * DT_BN;
#pragma unroll
    for (int i = 0; i < 12; ++i) {
        int li = tid + i * 256;        // 0..3071
        int r = li / DTRANK, c = li % DTRANK;
        As[c][r] = Ad[(size_t)(bm + r) * DBLW + c];
    }
#pragma unroll
    for (int i = 0; i < 6; ++i) {
        int fi = tid + i * 256;        // float4 idx 0..1535
        int r = fi >> 5, c4 = (fi & 31) * 4;
        *(float4*)&Bs[r][c4] = *(const float4*)(Wdt + (size_t)r * DINNER + bn + c4);
    }
    __syncthreads();
    int tm = (tid >> 4) * 4, tn = (tid & 15) * 8;
    float acc[4][8] = {};
#pragma unroll
    for (int k = 0; k < DTRANK; ++k) {
        float a[4], b[8];
        *(float4*)a     = *(const float4*)&As[k][tm];
        *(float4*)&b[0] = *(const float4*)&Bs[k][tn];
        *(float4*)&b[4] = *(const float4*)&Bs[k][tn + 4];
#pragma unroll
        for (int i = 0; i < 4; ++i)
#pragma unroll
            for (int j = 0; j < 8; ++j)
                acc[i][j] = fmaf(a[i], b[j], acc[i][j]);
    }
#pragma unroll
    for (int i = 0; i < 4; ++i) {
#pragma unroll
        for (int j = 0; j < 8; ++j)
            acc[i][j] = softplus_f(acc[i][j] + bdt[bn + tn + j]);
        size_t rowOff = (size_t)dir * MROWS * DINNER + (size_t)(bm + tm + i) * DINNER + bn + tn;
        if (OBF16) {
            ushort4 o0, o1;
            o0.x = f2bf(acc[i][0]); o0.y = f2bf(acc[i][1]);
            o0.z = f2bf(acc[i][2]); o0.w = f2bf(acc[i][3]);
            o1.x = f2bf(acc[i][4]); o1.y = f2bf(acc[i][5]);
            o1.z = f2bf(acc[i][6]); o1.w = f2bf(acc[i][7]);
            *(ushort4*)((unsigned short*)deltaO + rowOff)     = o0;
            *(ushort4*)((unsigned short*)deltaO + rowOff + 4) = o1;
        } else {
            *(float4*)((float*)deltaO + rowOff)     = *(float4*)&acc[i][0];
            *(float4*)((float*)deltaO + rowOff + 4) = *(float4*)&acc[i][4];
        }
    }
}

// -------- Selective scan, chunked, both dirs. grid(NC, DINNER/256, 4) --------
template <int NC, bool DBF16>
__global__ __launch_bounds__(256) void scan_pass1(
    const unsigned short* __restrict__ xc, const float* __restrict__ dbl,
    const void* __restrict__ deltaI,
    const float* __restrict__ Alog0, const float* __restrict__ Alog1,
    float* __restrict__ sumdO, float* __restrict__ Q)
{
    constexpr int CL = SEQ / NC;
    __shared__ float sbc[CL][32];
    int c = blockIdx.x;
    int d = blockIdx.y * 256 + threadIdx.x;
    int b = blockIdx.z & 1, dir = blockIdx.z >> 1;
    const float* Alog = dir ? Alog1 : Alog0;
    const unsigned short* u_ = xc + (size_t)dir * MROWS * DINNER;
    const float* dblz = dbl + (size_t)dir * MROWS * DBLW;
    size_t dOff = (size_t)dir * MROWS * DINNER;
    int r0 = b * SEQ + c * CL;
    for (int i = threadIdx.x; i < CL * 32; i += 256)
        sbc[i >> 5][i & 31] = dblz[(size_t)(r0 + (i >> 5)) * DBLW + DTRANK + (i & 31)];
    float A[DSTATE], h[DSTATE];
#pragma unroll
    for (int n = 0; n < DSTATE; ++n) { A[n] = -__expf(Alog[d * DSTATE + n]); h[n] = 0.f; }
    __syncthreads();
    float sd = 0.f;
#pragma unroll 2
    for (int t = 0; t < CL; ++t) {
        size_t ri = dOff + (size_t)(r0 + t) * DINNER + d;
        float dl = DBF16 ? bf2f(((const unsigned short*)deltaI)[ri])
                         : ((const float*)deltaI)[ri];
        float u = bf2f(u_[(size_t)(r0 + t) * DINNER + d]);
        float du = dl * u;
        sd += dl;
#pragma unroll
        for (int n = 0; n < DSTATE; ++n) {
            float a = __expf(dl * A[n]);
            h[n] = fmaf(a, h[n], du * sbc[t][n]);
        }
    }
    size_t sOff = (size_t)dir * NC * BATCHN * DINNER + (size_t)(c * BATCHN + b) * DINNER + d;
    sumdO[sOff] = sd;
    size_t qB = (size_t)dir * NC * BATCHN * DSTATE * DINNER +
                ((size_t)(c * BATCHN + b) * DSTATE) * DINNER + d;
#pragma unroll
    for (int n = 0; n < DSTATE; ++n) Q[qB + (size_t)n * DINNER] = h[n];
}

template <int NC>
__global__ __launch_bounds__(256) void scan_mid(
    const float* __restrict__ sumd, float* __restrict__ Q,
    const float* __restrict__ Alog0, const float* __restrict__ Alog1)
{
    int idx = blockIdx.x * 256 + threadIdx.x;   // 2*2*16*1536
    int d = idx % DINNER;
    int n = (idx / DINNER) % DSTATE;
    int b = (idx / (DINNER * DSTATE)) % BATCHN;
    int dir = idx / (DINNER * DSTATE * BATCHN);
    float A = -__expf((dir ? Alog1 : Alog0)[d * DSTATE + n]);
    size_t sBase = (size_t)dir * NC * BATCHN * DINNER;
    size_t qBase = (size_t)dir * NC * BATCHN * DSTATE * DINNER;
    float H = 0.f;
    for (int c = 0; c < NC; ++c) {
        size_t si = sBase + (size_t)(c * BATCHN + b) * DINNER + d;
        size_t qi = qBase + ((size_t)(c * BATCHN + b) * DSTATE + n) * DINNER + d;
        float p = __expf(sumd[si] * A);
        float q = Q[qi];
        Q[qi] = H;              // state entering chunk c
        H = fmaf(p, H, q);
    }
}

template <int NC, bool DBF16>
__global__ __launch_bounds__(256) void scan_pass2(
    const unsigned short* __restrict__ xc, const float* __restrict__ dbl,
    const unsigned short* __restrict__ xz, const void* __restrict__ deltaI,
    const float* __restrict__ Alog0, const float* __restrict__ Alog1,
    const float* __restrict__ Dp0, const float* __restrict__ Dp1,
    const float* __restrict__ Q,
    unsigned short* __restrict__ ymod)
{
    constexpr int CL = SEQ / NC;
    __shared__ float sbc[CL][32];
    int c = blockIdx.x;
    int d = blockIdx.y * 256 + threadIdx.x;
    int b = blockIdx.z & 1, dir = blockIdx.z >> 1;
    const float* Alog = dir ? Alog1 : Alog0;
    const unsigned short* u_ = xc + (size_t)dir * MROWS * DINNER;
    const unsigned short* z_ = xz + (size_t)dir * MROWS * 2 * DINNER;
    const float* dblz = dbl + (size_t)dir * MROWS * DBLW;
    size_t dOff = (size_t)dir * MROWS * DINNER;
    int r0 = b * SEQ + c * CL;
    for (int i = threadIdx.x; i < CL * 32; i += 256)
        sbc[i >> 5][i & 31] = dblz[(size_t)(r0 + (i >> 5)) * DBLW + DTRANK + (i & 31)];
    float Dd = (dir ? Dp1 : Dp0)[d];
    float A[DSTATE], h[DSTATE];
    size_t qB = (size_t)dir * NC * BATCHN * DSTATE * DINNER +
                ((size_t)(c * BATCHN + b) * DSTATE) * DINNER + d;
#pragma unroll
    for (int n = 0; n < DSTATE; ++n) {
        A[n] = -__expf(Alog[d * DSTATE + n]);
        h[n] = Q[qB + (size_t)n * DINNER];
    }
    __syncthreads();
    unsigned short* yo = ymod + (size_t)dir * MROWS * DINNER;
#pragma unroll 2
    for (int t = 0; t < CL; ++t) {
        size_t ri = dOff + (size_t)(r0 + t) * DINNER + d;
        float dl = DBF16 ? bf2f(((const unsigned short*)deltaI)[ri])
                         : ((const float*)deltaI)[ri];
        float u = bf2f(u_[(size_t)(r0 + t) * DINNER + d]);
        float du = dl * u;
        float y = 0.f;
#pragma unroll
        for (int n = 0; n < DSTATE; ++n) {
            float a = __expf(dl * A[n]);
            h[n] = fmaf(a, h[n], du * sbc[t][n]);
            y = fmaf(h[n], sbc[t][DSTATE + n], y);
        }
        float zz = bf2f(z_[(size_t)(r0 + t) * (2 * DINNER) + DINNER + d]);
        float sig = 1.f / (1.f + __expf(-zz));
        yo[(size_t)(r0 + t) * DINNER + d] = f2bf((y + u * Dd) * (zz * sig));
    }
}

// ---------------- launch ----------------
extern "C" void kernel_launch(void* const* d_in, const int* in_sizes, int n_in,
                              void* d_out, int out_size, void* d_ws, size_t ws_size,
                              hipStream_t stream)
{
    (void)in_sizes; (void)n_in; (void)out_size;
    const float* x    = (const float*)d_in[0];
    const float* ln_g = (const float*)d_in[1];
    const float* ln_b = (const float*)d_in[2];
    const float* W_in[2]   = {(const float*)d_in[3],  (const float*)d_in[12]};
    const float* conv_w[2] = {(const float*)d_in[4],  (const float*)d_in[13]};
    const float* conv_b[2] = {(const float*)d_in[5],  (const float*)d_in[14]};
    const float* W_x[2]    = {(const float*)d_in[6],  (const float*)d_in[15]};
    const float* W_dt[2]   = {(const float*)d_in[7],  (const float*)d_in[16]};
    const float* b_dt[2]   = {(const float*)d_in[8],  (const float*)d_in[17]};
    const float* A_log[2]  = {(const float*)d_in[9],  (const float*)d_in[18]};
    const float* Dp[2]     = {(const float*)d_in[10], (const float*)d_in[19]};
    const float* W_out[2]  = {(const float*)d_in[11], (const float*)d_in[20]};
    const float* W_c = (const float*)d_in[21];
    const float* b_c = (const float*)d_in[22];
    float* out = (float*)d_out;

    constexpr int NC = 64;
    // ---- workspace (floats first, then bf16 shorts) ----
    float* fp = (float*)d_ws;
    float* dbl  = fp; fp += (size_t)2 * MROWS * DBLW;
    float* part = fp; fp += (size_t)2 * XP_KSPLIT * MROWS * DBLW;
    float* sumd = fp; fp += (size_t)NC * BATCHN * 2 * DINNER;
    float* Q    = fp; fp += (size_t)NC * BATCHN * 2 * DSTATE * DINNER;

    size_t floatsBase = (size_t)2 * MROWS * DBLW + (size_t)2 * XP_KSPLIT * MROWS * DBLW +
                        (size_t)NC * BATCHN * 2 * DINNER +
                        (size_t)NC * BATCHN * 2 * DSTATE * DINNER;
    size_t shortsTot = (size_t)2 * MROWS * 2 * DINNER + (size_t)2 * MROWS * DINNER +
                       (size_t)2 * MROWS * DMODEL + (size_t)2 * MROWS * DINNER +
                       (size_t)2 * MROWS * DMODEL + (size_t)2 * (2 * DINNER) * DMODEL +
                       (size_t)2 * DMODEL * DINNER + (size_t)DMODEL * (2 * DMODEL);
    size_t deltaElems = (size_t)2 * MROWS * DINNER;
    // Tier A: fp32 delta appended to float region.
    bool tierA = ws_size >= (floatsBase + deltaElems) * 4 + shortsTot * 2;
    float* delta_f = nullptr;
    if (tierA) { delta_f = fp; fp += deltaElems; }

    unsigned short* us = (unsigned short*)fp;
    unsigned short* xz_bf   = us; us += (size_t)2 * MROWS * 2 * DINNER;
    unsigned short* xc_bf   = us; us += (size_t)2 * MROWS * DINNER;
    unsigned short* xn_bf   = us; us += (size_t)MROWS * DMODEL;
    unsigned short* xnr_bf  = us; us += (size_t)MROWS * DMODEL;
    unsigned short* ymod_bf = us; us += (size_t)2 * MROWS * DINNER;
    unsigned short* outf_bf = us; us += (size_t)MROWS * DMODEL;
    unsigned short* outb_bf = us; us += (size_t)MROWS * DMODEL;
    unsigned short* wt_in   = us; us += (size_t)2 * (2 * DINNER) * DMODEL;
    unsigned short* wt_out  = us; us += (size_t)2 * DMODEL * DINNER;
    unsigned short* wt_c    = us; us += (size_t)DMODEL * (2 * DMODEL);
    // Tier B: bf16 delta aliased over wt_in (+wt_out tail) — dead after W_in GEMM;
    // wt_out is (re)written by its transpose only AFTER the scans complete.
    unsigned short* delta_h = wt_in;

    // 1. LN
    ln_kernel<<<MROWS, 256, 0, stream>>>(x, ln_g, ln_b, xn_bf, xnr_bf);
    // 2-3. weight transposes
    wt_transpose<<<dim3(DMODEL / 32, 2 * DMODEL / 32, 1), 256, 0, stream>>>(
        W_c, W_c, wt_c, 2 * DMODEL, DMODEL);
    wt_transpose<<<dim3(2 * DINNER / 32, DMODEL / 32, 2), 256, 0, stream>>>(
        W_in[0], W_in[1], wt_in, DMODEL, 2 * DINNER);
    // 4. W_in GEMM both dirs -> xz bf16
    gemm_bf16<128, false, true><<<dim3(2 * DINNER / 128, MROWS / 128, 2), 256, 0, stream>>>(
        xn_bf, xnr_bf, DMODEL, 0, DMODEL,
        wt_in, (size_t)(2 * DINNER) * DMODEL, 2 * DINNER,
        nullptr, xz_bf, xz_bf + (size_t)MROWS * 2 * DINNER, 0);
    // 5. conv+silu both dirs
    conv_silu<<<(2 * MROWS * DINNER / 4) / 256, 256, 0, stream>>>(
        xz_bf, conv_w[0], conv_w[1], conv_b[0], conv_b[1], xc_bf);
    // 6-7. x-proj both dirs
    xproj_gemm<<<dim3(MROWS / XP_BM, XP_KSPLIT, 2), 256, 0, stream>>>(
        xc_bf, W_x[0], W_x[1], part);
    xproj_reduce<<<(2 * MROWS * DBLW) / 256, 256, 0, stream>>>(part, dbl);
    // 8. delta GEMM both dirs
    dim3 gdt(DINNER / DT_BN, MROWS / DT_BM, 2);
    if (tierA)
        dt_gemm<false><<<gdt, 256, 0, stream>>>(dbl, W_dt[0], W_dt[1], b_dt[0], b_dt[1], delta_f);
    else
        dt_gemm<true><<<gdt, 256, 0, stream>>>(dbl, W_dt[0], W_dt[1], b_dt[0], b_dt[1], delta_h);
    // 9-11. scan
    dim3 gsc(NC, DINNER / 256, BATCHN * 2);
    if (tierA) {
        scan_pass1<NC, false><<<gsc, 256, 0, stream>>>(
            xc_bf, dbl, delta_f, A_log[0], A_log[1], sumd, Q);
        scan_mid<NC><<<(2 * BATCHN * DSTATE * DINNER) / 256, 256, 0, stream>>>(
            sumd, Q, A_log[0], A_log[1]);
        scan_pass2<NC, false><<<gsc, 256, 0, stream>>>(
            xc_bf, dbl, xz_bf, delta_f, A_log[0], A_log[1], Dp[0], Dp[1], Q, ymod_bf);
    } else {
        scan_pass1<NC, true><<<gsc, 256, 0, stream>>>(
            xc_bf, dbl, delta_h, A_log[0], A_log[1], sumd, Q);
        scan_mid<NC><<<(2 * BATCHN * DSTATE * DINNER) / 256, 256, 0, stream>>>(
            sumd, Q, A_log[0], A_log[1]);
        scan_pass2<NC, true><<<gsc, 256, 0, stream>>>(
            xc_bf, dbl, xz_bf, delta_h, A_log[0], A_log[1], Dp[0], Dp[1], Q, ymod_bf);
    }
    // 12-13. W_out GEMM both dirs (bwd writes seq-reversed)
    wt_transpose<<<dim3(DMODEL / 32, DINNER / 32, 2), 256, 0, stream>>>(
        W_out[0], W_out[1], wt_out, DINNER, DMODEL);
    gemm_bf16<64, false, true><<<dim3(DMODEL / 128, MROWS / 64, 2), 256, 0, stream>>>(
        ymod_bf, ymod_bf, DINNER, (size_t)MROWS * DINNER, DINNER,
        wt_out, (size_t)DMODEL * DINNER, DMODEL,
        nullptr, outf_bf, outb_bf, SEQ - 1);
    // 14. final concat GEMM
    gemm_bf16<64, true, false><<<dim3(DMODEL / 128, MROWS / 64, 1), 256, 0, stream>>>(
        outf_bf, outb_bf, DMODEL, 0, 2 * DMODEL,
        wt_c, 0, DMODEL,
        b_c, out, nullptr, 0);
}

// Round 9
// 252.924 us; speedup vs baseline: 7.4933x; 1.1622x over previous
//
#include <hip/hip_runtime.h>
#include <math.h>

#define BATCHN 2
#define SEQ 1024
#define MROWS 2048      // BATCHN*SEQ
#define DMODEL 768
#define DINNER 1536
#define DSTATE 16
#define DCONV 4
#define DTRANK 48       // (768+15)//16
#define DBLW 80         // DTRANK + 2*DSTATE

typedef __bf16 bf16x8 __attribute__((ext_vector_type(8)));
typedef float  f32x4  __attribute__((ext_vector_type(4)));

__device__ __forceinline__ float silu_f(float x) { return x / (1.f + __expf(-x)); }
__device__ __forceinline__ float softplus_f(float x) {
    return fmaxf(x, 0.f) + log1pf(__expf(-fabsf(x)));
}
__device__ __forceinline__ unsigned short f2bf(float f) {
    unsigned int u = __float_as_uint(f);
    u += 0x7fffu + ((u >> 16) & 1u);          // round-to-nearest-even
    return (unsigned short)(u >> 16);
}
__device__ __forceinline__ float bf2f(unsigned short h) {
    return __uint_as_float(((unsigned int)h) << 16);
}
__device__ __forceinline__ void gload_lds16(const void* g, void* l) {
    __builtin_amdgcn_global_load_lds((const __attribute__((address_space(1))) void*)g,
                                     (__attribute__((address_space(3))) void*)l, 16, 0, 0);
}

// ---------------- LayerNorm -> bf16 (normal + seq-reversed copies) ----------------
__global__ __launch_bounds__(256) void ln_kernel(
    const float* __restrict__ x, const float* __restrict__ g,
    const float* __restrict__ b,
    unsigned short* __restrict__ xn_bf, unsigned short* __restrict__ xnr_bf)
{
    int row = blockIdx.x;
    const float* xr = x + (size_t)row * DMODEL;
    float v[3], s = 0.f, s2 = 0.f;
#pragma unroll
    for (int i = 0; i < 3; ++i) {
        v[i] = xr[threadIdx.x + i * 256];
        s += v[i]; s2 += v[i] * v[i];
    }
#pragma unroll
    for (int off = 32; off > 0; off >>= 1) {
        s  += __shfl_down(s, off);
        s2 += __shfl_down(s2, off);
    }
    __shared__ float red[2][4];
    int wid = threadIdx.x >> 6, lane = threadIdx.x & 63;
    if (lane == 0) { red[0][wid] = s; red[1][wid] = s2; }
    __syncthreads();
    if (threadIdx.x == 0) {
        float ts = 0.f, ts2 = 0.f;
        for (int w = 0; w < 4; ++w) { ts += red[0][w]; ts2 += red[1][w]; }
        red[0][0] = ts; red[1][0] = ts2;
    }
    __syncthreads();
    float mean = red[0][0] * (1.f / DMODEL);
    float var  = red[1][0] * (1.f / DMODEL) - mean * mean;
    float rstd = rsqrtf(var + 1e-5f);
    int rrow = row ^ (SEQ - 1);              // flip within batch
#pragma unroll
    for (int i = 0; i < 3; ++i) {
        int c = threadIdx.x + i * 256;
        unsigned short h = f2bf((v[i] - mean) * rstd * g[c] + b[c]);
        xn_bf [(size_t)row  * DMODEL + c] = h;
        xnr_bf[(size_t)rrow * DMODEL + c] = h;
    }
}

// ------- weight transpose + fp32->bf16: W[K][N] -> Wt[N][K], dir via grid.z -------
__global__ __launch_bounds__(256) void wt_transpose(
    const float* __restrict__ W0, const float* __restrict__ W1,
    unsigned short* __restrict__ Wt, int K, int N)
{
    const float* W = blockIdx.z ? W1 : W0;
    unsigned short* Wtz = Wt + (size_t)blockIdx.z * K * N;
    __shared__ float t[32][33];
    int n0 = blockIdx.x * 32, k0 = blockIdx.y * 32;
    int tx = threadIdx.x & 31, ty = threadIdx.x >> 5;
#pragma unroll
    for (int i = 0; i < 4; ++i)
        t[ty + i * 8][tx] = W[(size_t)(k0 + ty + i * 8) * N + n0 + tx];
    __syncthreads();
#pragma unroll
    for (int i = 0; i < 4; ++i)
        Wtz[(size_t)(n0 + ty + i * 8) * K + k0 + tx] = f2bf(t[tx][ty + i * 8]);
}

// ---------------- bf16 MFMA GEMM (dir via grid.z) ----------------
template <int BM, bool CONCAT, bool CBF16>
__global__ __launch_bounds__(256) void gemm_bf16(
    const unsigned short* __restrict__ A0, const unsigned short* __restrict__ A1,
    int lda, size_t aStr, int K,
    const unsigned short* __restrict__ Bt, size_t btStr, int N,
    const float* __restrict__ bias, void* __restrict__ C0, void* __restrict__ C1,
    int revMask)
{
    constexpr int MI = BM / 32;
    __shared__ unsigned short lsA[BM * 32];
    __shared__ unsigned short lsB[128 * 32];
    int z = blockIdx.z;
    const unsigned short* A = (z ? A1 : A0) + (size_t)z * aStr;
    const unsigned short* Bz = Bt + (size_t)z * btStr;
    void* Cv = z ? C1 : C0;
    int revm = z ? revMask : 0;

    int tid = threadIdx.x;
    int w = tid >> 6, lane = tid & 63;
    int wm = w >> 1, wn = w & 1;
    int bm = blockIdx.y * BM, bn = blockIdx.x * 128;
    int sr = lane >> 2, sc = (lane & 3) * 8;
    int l15 = lane & 15, kq = (lane >> 4) * 8;

    f32x4 acc[MI][4];
#pragma unroll
    for (int mi = 0; mi < MI; ++mi)
#pragma unroll
        for (int ni = 0; ni < 4; ++ni) acc[mi][ni] = (f32x4){0.f, 0.f, 0.f, 0.f};

    for (int kb = 0; kb < K; kb += 32) {
        const unsigned short* ap; int kc;
        if (CONCAT) {
            ap = (kb < DMODEL) ? A0 : A1;
            kc = (kb < DMODEL) ? kb : kb - DMODEL;
        } else { ap = A; kc = kb; }
#pragma unroll
        for (int r = 0; r < BM / 64; ++r) {
            const void* gp = ap + (size_t)(bm + r * 64 + w * 16 + sr) * lda + kc + sc;
            gload_lds16(gp, (void*)&lsA[(r * 64 + w * 16) * 32]);
        }
#pragma unroll
        for (int r = 0; r < 2; ++r) {
            const void* gp = Bz + (size_t)(bn + r * 64 + w * 16 + sr) * K + kb + sc;
            gload_lds16(gp, (void*)&lsB[(r * 64 + w * 16) * 32]);
        }
        __syncthreads();
        bf16x8 af[MI], bfr[4];
#pragma unroll
        for (int mi = 0; mi < MI; ++mi)
            af[mi] = *(const bf16x8*)&lsA[(wm * (BM / 2) + mi * 16 + l15) * 32 + kq];
#pragma unroll
        for (int ni = 0; ni < 4; ++ni)
            bfr[ni] = *(const bf16x8*)&lsB[(wn * 64 + ni * 16 + l15) * 32 + kq];
#pragma unroll
        for (int mi = 0; mi < MI; ++mi)
#pragma unroll
            for (int ni = 0; ni < 4; ++ni)
                acc[mi][ni] = __builtin_amdgcn_mfma_f32_16x16x32_bf16(
                    af[mi], bfr[ni], acc[mi][ni], 0, 0, 0);
        __syncthreads();
    }

    int r4 = (lane >> 4) * 4;
#pragma unroll
    for (int mi = 0; mi < MI; ++mi) {
#pragma unroll
        for (int ni = 0; ni < 4; ++ni) {
            int col = bn + wn * 64 + ni * 16 + l15;
            float bv = bias ? bias[col] : 0.f;
#pragma unroll
            for (int r = 0; r < 4; ++r) {
                int row = (bm + wm * (BM / 2) + mi * 16 + r4 + r) ^ revm;
                float val = acc[mi][ni][r] + bv;
                if (CBF16)
                    ((unsigned short*)Cv)[(size_t)row * N + col] = f2bf(val);
                else
                    ((float*)Cv)[(size_t)row * N + col] = val;
            }
        }
    }
}

// --- Causal dwconv (K=4) + SiLU: column-sliding-window, 1 thread per d-column ---
// grid: (dir*BATCHN*NCHK + b*NCHK + chunk, DINNER/256). RC rows per block.
#define CV_RC 16
__global__ __launch_bounds__(256) void conv_silu(
    const unsigned short* __restrict__ xz,
    const float* __restrict__ w0, const float* __restrict__ w1,
    const float* __restrict__ cb0, const float* __restrict__ cb1,
    unsigned short* __restrict__ xc)
{
    constexpr int NCHK = SEQ / CV_RC;
    int bx = blockIdx.x;
    int ch = bx % NCHK;
    int b  = (bx / NCHK) % BATCHN;
    int dir = bx / (NCHK * BATCHN);
    int d = blockIdx.y * 256 + threadIdx.x;
    const unsigned short* xi = xz + (size_t)dir * MROWS * 2 * DINNER;
    unsigned short* yo = xc + (size_t)dir * MROWS * DINNER;
    float4 w = *(const float4*)((dir ? w1 : w0) + (size_t)d * DCONV);
    float cb = (dir ? cb1 : cb0)[d];
    int s0 = ch * CV_RC;
    int rbase = b * SEQ;
    // history x[s0-3..s0-1] (zeros before seq start)
    float xm3 = (s0 >= 3) ? bf2f(xi[(size_t)(rbase + s0 - 3) * 2 * DINNER + d]) : 0.f;
    float xm2 = (s0 >= 2) ? bf2f(xi[(size_t)(rbase + s0 - 2) * 2 * DINNER + d]) : 0.f;
    float xm1 = (s0 >= 1) ? bf2f(xi[(size_t)(rbase + s0 - 1) * 2 * DINNER + d]) : 0.f;
#pragma unroll
    for (int t = 0; t < CV_RC; ++t) {
        int r = rbase + s0 + t;
        float cur = bf2f(xi[(size_t)r * 2 * DINNER + d]);
        float acc = cb;
        acc = fmaf(xm3, w.x, acc);
        acc = fmaf(xm2, w.y, acc);
        acc = fmaf(xm1, w.z, acc);
        acc = fmaf(cur, w.w, acc);
        yo[(size_t)r * DINNER + d] = f2bf(silu_f(acc));
        xm3 = xm2; xm2 = xm1; xm1 = cur;
    }
}

// ---------------- x-proj GEMM: 2048x80x1536, split-K, both dirs ----------------
#define XP_BM 32
#define XP_BK 32
#define XP_KSPLIT 4
#define XP_KCH (DINNER / XP_KSPLIT)   // 384

__global__ __launch_bounds__(256) void xproj_gemm(
    const unsigned short* __restrict__ xc,
    const float* __restrict__ Wx0, const float* __restrict__ Wx1,
    float* __restrict__ part)      // [dir][KSPLIT][2048][80]
{
    __shared__ float As[XP_BK][XP_BM + 1];
    __shared__ float Bs[XP_BK][DBLW + 1];
    int dir = blockIdx.z;
    const unsigned short* A = xc + (size_t)dir * MROWS * DINNER;
    const float* B = dir ? Wx1 : Wx0;
    int tid = threadIdx.x;
    int bm = blockIdx.x * XP_BM;
    int k0 = blockIdx.y * XP_KCH;
    int tm = (tid >> 4) * 2;
    int tn = (tid & 15) * 5;
    float acc[2][5];
#pragma unroll
    for (int i = 0; i < 2; ++i)
#pragma unroll
        for (int j = 0; j < 5; ++j) acc[i][j] = 0.f;

    int ar = tid >> 3;
    int ac = (tid & 7) * 4;

    for (int kb = 0; kb < XP_KCH; kb += XP_BK) {
        ushort4 va = *(const ushort4*)(A + (size_t)(bm + ar) * DINNER + k0 + kb + ac);
        As[ac + 0][ar] = bf2f(va.x); As[ac + 1][ar] = bf2f(va.y);
        As[ac + 2][ar] = bf2f(va.z); As[ac + 3][ar] = bf2f(va.w);
#pragma unroll
        for (int i = 0; i < 10; ++i) {
            int li = tid + i * 256;
            int kk = li / DBLW, nn = li - kk * DBLW;
            Bs[kk][nn] = B[(size_t)(k0 + kb + kk) * DBLW + nn];
        }
        __syncthreads();
#pragma unroll
        for (int k = 0; k < XP_BK; ++k) {
            float a0 = As[k][tm], a1 = As[k][tm + 1];
            float b0 = Bs[k][tn + 0], b1 = Bs[k][tn + 1], b2 = Bs[k][tn + 2];
            float b3 = Bs[k][tn + 3], b4 = Bs[k][tn + 4];
            acc[0][0] = fmaf(a0, b0, acc[0][0]); acc[0][1] = fmaf(a0, b1, acc[0][1]);
            acc[0][2] = fmaf(a0, b2, acc[0][2]); acc[0][3] = fmaf(a0, b3, acc[0][3]);
            acc[0][4] = fmaf(a0, b4, acc[0][4]);
            acc[1][0] = fmaf(a1, b0, acc[1][0]); acc[1][1] = fmaf(a1, b1, acc[1][1]);
            acc[1][2] = fmaf(a1, b2, acc[1][2]); acc[1][3] = fmaf(a1, b3, acc[1][3]);
            acc[1][4] = fmaf(a1, b4, acc[1][4]);
        }
        __syncthreads();
    }
    size_t base = ((size_t)dir * XP_KSPLIT + blockIdx.y) * MROWS * DBLW + (size_t)bm * DBLW;
#pragma unroll
    for (int i = 0; i < 2; ++i)
#pragma unroll
        for (int j = 0; j < 5; ++j)
            part[base + (size_t)(tm + i) * DBLW + tn + j] = acc[i][j];
}

__global__ __launch_bounds__(256) void xproj_reduce(
    const float* __restrict__ part, float* __restrict__ dbl)
{
    int idx = blockIdx.x * 256 + threadIdx.x;       // over 2*MROWS*DBLW
    int dir = idx / (MROWS * DBLW);
    int rem = idx % (MROWS * DBLW);
    float s = 0.f;
#pragma unroll
    for (int ks = 0; ks < XP_KSPLIT; ++ks)
        s += part[((size_t)dir * XP_KSPLIT + ks) * MROWS * DBLW + rem];
    dbl[idx] = s;
}

// -------- delta GEMM: [dir] 2048 x 1536, K=48, + softplus; fp32 or bf16 out --------
#define DT_BM 64
#define DT_BN 128
template <bool OBF16>
__global__ __launch_bounds__(256) void dt_gemm(
    const float* __restrict__ dbl_, const float* __restrict__ Wdt0,
    const float* __restrict__ Wdt1, const float* __restrict__ bdt0,
    const float* __restrict__ bdt1, void* __restrict__ deltaO)
{
    int dir = blockIdx.z;
    const float* Ad  = dbl_ + (size_t)dir * MROWS * DBLW;
    const float* Wdt = dir ? Wdt1 : Wdt0;
    const float* bdt = dir ? bdt1 : bdt0;
    __shared__ float As[DTRANK][DT_BM + 1];   // 48 x 65
    __shared__ float Bs[DTRANK][DT_BN + 4];   // 48 x 132
    int tid = threadIdx.x;
    int bm = blockIdx.y * DT_BM, bn = blockIdx.x * DT_BN;
#pragma unroll
    for (int i = 0; i < 12; ++i) {
        int li = tid + i * 256;        // 0..3071
        int r = li / DTRANK, c = li % DTRANK;
        As[c][r] = Ad[(size_t)(bm + r) * DBLW + c];
    }
#pragma unroll
    for (int i = 0; i < 6; ++i) {
        int fi = tid + i * 256;        // float4 idx 0..1535
        int r = fi >> 5, c4 = (fi & 31) * 4;
        *(float4*)&Bs[r][c4] = *(const float4*)(Wdt + (size_t)r * DINNER + bn + c4);
    }
    __syncthreads();
    int tm = (tid >> 4) * 4, tn = (tid & 15) * 8;
    float acc[4][8] = {};
#pragma unroll
    for (int k = 0; k < DTRANK; ++k) {
        float a[4], b[8];
        *(float4*)a     = *(const float4*)&As[k][tm];
        *(float4*)&b[0] = *(const float4*)&Bs[k][tn];
        *(float4*)&b[4] = *(const float4*)&Bs[k][tn + 4];
#pragma unroll
        for (int i = 0; i < 4; ++i)
#pragma unroll
            for (int j = 0; j < 8; ++j)
                acc[i][j] = fmaf(a[i], b[j], acc[i][j]);
    }
#pragma unroll
    for (int i = 0; i < 4; ++i) {
#pragma unroll
        for (int j = 0; j < 8; ++j)
            acc[i][j] = softplus_f(acc[i][j] + bdt[bn + tn + j]);
        size_t rowOff = (size_t)dir * MROWS * DINNER + (size_t)(bm + tm + i) * DINNER + bn + tn;
        if (OBF16) {
            ushort4 o0, o1;
            o0.x = f2bf(acc[i][0]); o0.y = f2bf(acc[i][1]);
            o0.z = f2bf(acc[i][2]); o0.w = f2bf(acc[i][3]);
            o1.x = f2bf(acc[i][4]); o1.y = f2bf(acc[i][5]);
            o1.z = f2bf(acc[i][6]); o1.w = f2bf(acc[i][7]);
            *(ushort4*)((unsigned short*)deltaO + rowOff)     = o0;
            *(ushort4*)((unsigned short*)deltaO + rowOff + 4) = o1;
        } else {
            *(float4*)((float*)deltaO + rowOff)     = *(float4*)&acc[i][0];
            *(float4*)((float*)deltaO + rowOff + 4) = *(float4*)&acc[i][4];
        }
    }
}

// -------- Selective scan, chunked, both dirs. grid(NC, DINNER/256, 4) --------
template <int NC, bool DBF16>
__global__ __launch_bounds__(256) void scan_pass1(
    const unsigned short* __restrict__ xc, const float* __restrict__ dbl,
    const void* __restrict__ deltaI,
    const float* __restrict__ Alog0, const float* __restrict__ Alog1,
    float* __restrict__ sumdO, float* __restrict__ Q)
{
    constexpr int CL = SEQ / NC;
    __shared__ float sbc[CL][32];
    int c = blockIdx.x;
    int d = blockIdx.y * 256 + threadIdx.x;
    int b = blockIdx.z & 1, dir = blockIdx.z >> 1;
    const float* Alog = dir ? Alog1 : Alog0;
    const unsigned short* u_ = xc + (size_t)dir * MROWS * DINNER;
    const float* dblz = dbl + (size_t)dir * MROWS * DBLW;
    size_t dOff = (size_t)dir * MROWS * DINNER;
    int r0 = b * SEQ + c * CL;
    for (int i = threadIdx.x; i < CL * 32; i += 256)
        sbc[i >> 5][i & 31] = dblz[(size_t)(r0 + (i >> 5)) * DBLW + DTRANK + (i & 31)];
    float A[DSTATE], h[DSTATE];
#pragma unroll
    for (int n = 0; n < DSTATE; ++n) { A[n] = -__expf(Alog[d * DSTATE + n]); h[n] = 0.f; }
    __syncthreads();
    float sd = 0.f;
#pragma unroll 2
    for (int t = 0; t < CL; ++t) {
        size_t ri = dOff + (size_t)(r0 + t) * DINNER + d;
        float dl = DBF16 ? bf2f(((const unsigned short*)deltaI)[ri])
                         : ((const float*)deltaI)[ri];
        float u = bf2f(u_[(size_t)(r0 + t) * DINNER + d]);
        float du = dl * u;
        sd += dl;
#pragma unroll
        for (int n = 0; n < DSTATE; ++n) {
            float a = __expf(dl * A[n]);
            h[n] = fmaf(a, h[n], du * sbc[t][n]);
        }
    }
    size_t sOff = (size_t)dir * NC * BATCHN * DINNER + (size_t)(c * BATCHN + b) * DINNER + d;
    sumdO[sOff] = sd;
    size_t qB = (size_t)dir * NC * BATCHN * DSTATE * DINNER +
                ((size_t)(c * BATCHN + b) * DSTATE) * DINNER + d;
#pragma unroll
    for (int n = 0; n < DSTATE; ++n) Q[qB + (size_t)n * DINNER] = h[n];
}

template <int NC>
__global__ __launch_bounds__(256) void scan_mid(
    const float* __restrict__ sumd, float* __restrict__ Q,
    const float* __restrict__ Alog0, const float* __restrict__ Alog1)
{
    int idx = blockIdx.x * 256 + threadIdx.x;   // 2*2*16*1536
    int d = idx % DINNER;
    int n = (idx / DINNER) % DSTATE;
    int b = (idx / (DINNER * DSTATE)) % BATCHN;
    int dir = idx / (DINNER * DSTATE * BATCHN);
    float A = -__expf((dir ? Alog1 : Alog0)[d * DSTATE + n]);
    size_t sBase = (size_t)dir * NC * BATCHN * DINNER;
    size_t qBase = (size_t)dir * NC * BATCHN * DSTATE * DINNER;
    float H = 0.f;
    for (int c = 0; c < NC; ++c) {
        size_t si = sBase + (size_t)(c * BATCHN + b) * DINNER + d;
        size_t qi = qBase + ((size_t)(c * BATCHN + b) * DSTATE + n) * DINNER + d;
        float p = __expf(sumd[si] * A);
        float q = Q[qi];
        Q[qi] = H;              // state entering chunk c
        H = fmaf(p, H, q);
    }
}

template <int NC, bool DBF16>
__global__ __launch_bounds__(256) void scan_pass2(
    const unsigned short* __restrict__ xc, const float* __restrict__ dbl,
    const unsigned short* __restrict__ xz, const void* __restrict__ deltaI,
    const float* __restrict__ Alog0, const float* __restrict__ Alog1,
    const float* __restrict__ Dp0, const float* __restrict__ Dp1,
    const float* __restrict__ Q,
    unsigned short* __restrict__ ymod)
{
    constexpr int CL = SEQ / NC;
    __shared__ float sbc[CL][32];
    int c = blockIdx.x;
    int d = blockIdx.y * 256 + threadIdx.x;
    int b = blockIdx.z & 1, dir = blockIdx.z >> 1;
    const float* Alog = dir ? Alog1 : Alog0;
    const unsigned short* u_ = xc + (size_t)dir * MROWS * DINNER;
    const unsigned short* z_ = xz + (size_t)dir * MROWS * 2 * DINNER;
    const float* dblz = dbl + (size_t)dir * MROWS * DBLW;
    size_t dOff = (size_t)dir * MROWS * DINNER;
    int r0 = b * SEQ + c * CL;
    for (int i = threadIdx.x; i < CL * 32; i += 256)
        sbc[i >> 5][i & 31] = dblz[(size_t)(r0 + (i >> 5)) * DBLW + DTRANK + (i & 31)];
    float Dd = (dir ? Dp1 : Dp0)[d];
    float A[DSTATE], h[DSTATE];
    size_t qB = (size_t)dir * NC * BATCHN * DSTATE * DINNER +
                ((size_t)(c * BATCHN + b) * DSTATE) * DINNER + d;
#pragma unroll
    for (int n = 0; n < DSTATE; ++n) {
        A[n] = -__expf(Alog[d * DSTATE + n]);
        h[n] = Q[qB + (size_t)n * DINNER];
    }
    __syncthreads();
    unsigned short* yo = ymod + (size_t)dir * MROWS * DINNER;
#pragma unroll 2
    for (int t = 0; t < CL; ++t) {
        size_t ri = dOff + (size_t)(r0 + t) * DINNER + d;
        float dl = DBF16 ? bf2f(((const unsigned short*)deltaI)[ri])
                         : ((const float*)deltaI)[ri];
        float u = bf2f(u_[(size_t)(r0 + t) * DINNER + d]);
        float du = dl * u;
        float y = 0.f;
#pragma unroll
        for (int n = 0; n < DSTATE; ++n) {
            float a = __expf(dl * A[n]);
            h[n] = fmaf(a, h[n], du * sbc[t][n]);
            y = fmaf(h[n], sbc[t][DSTATE + n], y);
        }
        float zz = bf2f(z_[(size_t)(r0 + t) * (2 * DINNER) + DINNER + d]);
        float sig = 1.f / (1.f + __expf(-zz));
        yo[(size_t)(r0 + t) * DINNER + d] = f2bf((y + u * Dd) * (zz * sig));
    }
}

// ---------------- launch ----------------
extern "C" void kernel_launch(void* const* d_in, const int* in_sizes, int n_in,
                              void* d_out, int out_size, void* d_ws, size_t ws_size,
                              hipStream_t stream)
{
    (void)in_sizes; (void)n_in; (void)out_size;
    const float* x    = (const float*)d_in[0];
    const float* ln_g = (const float*)d_in[1];
    const float* ln_b = (const float*)d_in[2];
    const float* W_in[2]   = {(const float*)d_in[3],  (const float*)d_in[12]};
    const float* conv_w[2] = {(const float*)d_in[4],  (const float*)d_in[13]};
    const float* conv_b[2] = {(const float*)d_in[5],  (const float*)d_in[14]};
    const float* W_x[2]    = {(const float*)d_in[6],  (const float*)d_in[15]};
    const float* W_dt[2]   = {(const float*)d_in[7],  (const float*)d_in[16]};
    const float* b_dt[2]   = {(const float*)d_in[8],  (const float*)d_in[17]};
    const float* A_log[2]  = {(const float*)d_in[9],  (const float*)d_in[18]};
    const float* Dp[2]     = {(const float*)d_in[10], (const float*)d_in[19]};
    const float* W_out[2]  = {(const float*)d_in[11], (const float*)d_in[20]};
    const float* W_c = (const float*)d_in[21];
    const float* b_c = (const float*)d_in[22];
    float* out = (float*)d_out;

    constexpr int NC = 64;
    // ---- workspace (floats first, then bf16 shorts) ----
    float* fp = (float*)d_ws;
    float* dbl  = fp; fp += (size_t)2 * MROWS * DBLW;
    float* part = fp; fp += (size_t)2 * XP_KSPLIT * MROWS * DBLW;
    float* sumd = fp; fp += (size_t)NC * BATCHN * 2 * DINNER;
    float* Q    = fp; fp += (size_t)NC * BATCHN * 2 * DSTATE * DINNER;

    size_t floatsBase = (size_t)2 * MROWS * DBLW + (size_t)2 * XP_KSPLIT * MROWS * DBLW +
                        (size_t)NC * BATCHN * 2 * DINNER +
                        (size_t)NC * BATCHN * 2 * DSTATE * DINNER;
    size_t shortsTot = (size_t)2 * MROWS * 2 * DINNER + (size_t)2 * MROWS * DINNER +
                       (size_t)2 * MROWS * DMODEL + (size_t)2 * MROWS * DINNER +
                       (size_t)2 * MROWS * DMODEL + (size_t)2 * (2 * DINNER) * DMODEL +
                       (size_t)2 * DMODEL * DINNER + (size_t)DMODEL * (2 * DMODEL);
    size_t deltaElems = (size_t)2 * MROWS * DINNER;
    // Tier A: fp32 delta appended to float region.
    bool tierA = ws_size >= (floatsBase + deltaElems) * 4 + shortsTot * 2;
    float* delta_f = nullptr;
    if (tierA) { delta_f = fp; fp += deltaElems; }

    unsigned short* us = (unsigned short*)fp;
    unsigned short* xz_bf   = us; us += (size_t)2 * MROWS * 2 * DINNER;
    unsigned short* xc_bf   = us; us += (size_t)2 * MROWS * DINNER;
    unsigned short* xn_bf   = us; us += (size_t)MROWS * DMODEL;
    unsigned short* xnr_bf  = us; us += (size_t)MROWS * DMODEL;
    unsigned short* ymod_bf = us; us += (size_t)2 * MROWS * DINNER;
    unsigned short* outf_bf = us; us += (size_t)MROWS * DMODEL;
    unsigned short* outb_bf = us; us += (size_t)MROWS * DMODEL;
    unsigned short* wt_in   = us; us += (size_t)2 * (2 * DINNER) * DMODEL;
    unsigned short* wt_out  = us; us += (size_t)2 * DMODEL * DINNER;
    unsigned short* wt_c    = us; us += (size_t)DMODEL * (2 * DMODEL);
    // Tier B: bf16 delta aliased over wt_in — dead after W_in GEMM;
    // wt_out rewritten only AFTER the scans.
    unsigned short* delta_h = wt_in;

    // 1. LN
    ln_kernel<<<MROWS, 256, 0, stream>>>(x, ln_g, ln_b, xn_bf, xnr_bf);
    // 2-3. weight transposes
    wt_transpose<<<dim3(DMODEL / 32, 2 * DMODEL / 32, 1), 256, 0, stream>>>(
        W_c, W_c, wt_c, 2 * DMODEL, DMODEL);
    wt_transpose<<<dim3(2 * DINNER / 32, DMODEL / 32, 2), 256, 0, stream>>>(
        W_in[0], W_in[1], wt_in, DMODEL, 2 * DINNER);
    // 4. W_in GEMM both dirs -> xz bf16
    gemm_bf16<128, false, true><<<dim3(2 * DINNER / 128, MROWS / 128, 2), 256, 0, stream>>>(
        xn_bf, xnr_bf, DMODEL, 0, DMODEL,
        wt_in, (size_t)(2 * DINNER) * DMODEL, 2 * DINNER,
        nullptr, xz_bf, xz_bf + (size_t)MROWS * 2 * DINNER, 0);
    // 5. conv+silu both dirs (sliding-window)
    conv_silu<<<dim3(2 * BATCHN * (SEQ / CV_RC), DINNER / 256), 256, 0, stream>>>(
        xz_bf, conv_w[0], conv_w[1], conv_b[0], conv_b[1], xc_bf);
    // 6-7. x-proj both dirs
    xproj_gemm<<<dim3(MROWS / XP_BM, XP_KSPLIT, 2), 256, 0, stream>>>(
        xc_bf, W_x[0], W_x[1], part);
    xproj_reduce<<<(2 * MROWS * DBLW) / 256, 256, 0, stream>>>(part, dbl);
    // 8. delta GEMM both dirs
    dim3 gdt(DINNER / DT_BN, MROWS / DT_BM, 2);
    if (tierA)
        dt_gemm<false><<<gdt, 256, 0, stream>>>(dbl, W_dt[0], W_dt[1], b_dt[0], b_dt[1], delta_f);
    else
        dt_gemm<true><<<gdt, 256, 0, stream>>>(dbl, W_dt[0], W_dt[1], b_dt[0], b_dt[1], delta_h);
    // 9-11. scan
    dim3 gsc(NC, DINNER / 256, BATCHN * 2);
    if (tierA) {
        scan_pass1<NC, false><<<gsc, 256, 0, stream>>>(
            xc_bf, dbl, delta_f, A_log[0], A_log[1], sumd, Q);
        scan_mid<NC><<<(2 * BATCHN * DSTATE * DINNER) / 256, 256, 0, stream>>>(
            sumd, Q, A_log[0], A_log[1]);
        scan_pass2<NC, false><<<gsc, 256, 0, stream>>>(
            xc_bf, dbl, xz_bf, delta_f, A_log[0], A_log[1], Dp[0], Dp[1], Q, ymod_bf);
    } else {
        scan_pass1<NC, true><<<gsc, 256, 0, stream>>>(
            xc_bf, dbl, delta_h, A_log[0], A_log[1], sumd, Q);
        scan_mid<NC><<<(2 * BATCHN * DSTATE * DINNER) / 256, 256, 0, stream>>>(
            sumd, Q, A_log[0], A_log[1]);
        scan_pass2<NC, true><<<gsc, 256, 0, stream>>>(
            xc_bf, dbl, xz_bf, delta_h, A_log[0], A_log[1], Dp[0], Dp[1], Q, ymod_bf);
    }
    // 12-13. W_out GEMM both dirs (bwd writes seq-reversed)
    wt_transpose<<<dim3(DMODEL / 32, DINNER / 32, 2), 256, 0, stream>>>(
        W_out[0], W_out[1], wt_out, DINNER, DMODEL);
    gemm_bf16<64, false, true><<<dim3(DMODEL / 128, MROWS / 64, 2), 256, 0, stream>>>(
        ymod_bf, ymod_bf, DINNER, (size_t)MROWS * DINNER, DINNER,
        wt_out, (size_t)DMODEL * DINNER, DMODEL,
        nullptr, outf_bf, outb_bf, SEQ - 1);
    // 14. final concat GEMM
    gemm_bf16<64, true, false><<<dim3(DMODEL / 128, MROWS / 64, 1), 256, 0, stream>>>(
        outf_bf, outb_bf, DMODEL, 0, 2 * DMODEL,
        wt_c, 0, DMODEL,
        b_c, out, nullptr, 0);
}